// Round 1
// baseline (1385.984 us; speedup 1.0000x reference)
//
#include <hip/hip_runtime.h>

#define NODES   32768
#define DIM     128
#define NCODES  4096
#define NGRAPHS 512

// output layout (flat f32, concatenated in reference return order)
#define OFF_LOGIT 0
#define OFF_CG    512
#define OFF_SG    66048
#define OFF_LC    131584
#define OFF_LS    131585
#define OFF_CN    131586
#define OFF_SN    4325890

// workspace layout (bytes)
#define WS_CNORM  0          // float[2][4096]
#define WS_SXX    32768      // float[2][32768]
#define WS_IDX    294912     // int[2][32768]
#define WS_STARTS 557056     // int[513]
#define WS_LOSS   559112     // double[2]

__device__ __forceinline__ float h_of(float x, float sc, int cb) {
    // reference: h_c = x*s + (0.5*x)*(1-s); h_s = x*(1-s) + (0.5*x)*s
    // explicit rounded ops to forbid fma contraction (mimic XLA elementwise)
    float omsc = __fsub_rn(1.0f, sc);
    float half_x = __fmul_rn(0.5f, x);
    if (cb == 0)
        return __fadd_rn(__fmul_rn(x, sc), __fmul_rn(half_x, omsc));
    else
        return __fadd_rn(__fmul_rn(x, omsc), __fmul_rn(half_x, sc));
}

// ---------------------------------------------------------------- prep ----
__global__ __launch_bounds__(256) void prep_kernel(
    const float* __restrict__ node_feat, const float* __restrict__ score,
    const float* __restrict__ cb_c, const float* __restrict__ cb_s,
    const int* __restrict__ batch,
    float* __restrict__ cnorm, float* __restrict__ sxx,
    int* __restrict__ starts, double* __restrict__ loss_acc)
{
    int gwave = (blockIdx.x * 256 + threadIdx.x) >> 6;
    int lane  = threadIdx.x & 63;

    if (gwave < 2 * NCODES) {                       // ||c||^2 per code
        int cb = gwave >> 12, code = gwave & (NCODES - 1);
        const float* cp = (cb ? cb_s : cb_c) + code * DIM;
        float a = cp[lane], b = cp[lane + 64];
        float p = __fadd_rn(__fmul_rn(a, a), __fmul_rn(b, b));
        #pragma unroll
        for (int off = 32; off; off >>= 1) p = __fadd_rn(p, __shfl_xor(p, off, 64));
        if (lane == 0) cnorm[cb * NCODES + code] = p;
    } else if (gwave < 2 * NCODES + 2 * NODES) {    // ||h||^2 per node,variant
        int w = gwave - 2 * NCODES;
        int cb = w >> 15, node = w & (NODES - 1);
        float sc = score[node];
        const float* xp = node_feat + node * DIM;
        float h1 = h_of(xp[lane], sc, cb);
        float h2 = h_of(xp[lane + 64], sc, cb);
        float p = __fadd_rn(__fmul_rn(h1, h1), __fmul_rn(h2, h2));
        #pragma unroll
        for (int off = 32; off; off >>= 1) p = __fadd_rn(p, __shfl_xor(p, off, 64));
        if (lane == 0) sxx[cb * NODES + node] = p;
    } else {                                        // graph boundaries + loss zero
        int w = gwave - (2 * NCODES + 2 * NODES);
        int g = w * 64 + lane;
        if (g <= NGRAPHS) {
            int lo = 0, hi = NODES;
            while (lo < hi) { int mid = (lo + hi) >> 1; if (batch[mid] < g) lo = mid + 1; else hi = mid; }
            starts[g] = lo;
        }
        if (w == 0 && lane < 2) loss_acc[lane] = 0.0;
    }
}

// ------------------------------------------------------------- vq argmin ----
// 64-node x 128-code tile, 256 threads, per-thread 4 nodes x 8 codes.
// LDS k-major transposed + XOR group swizzle -> conflict-free ds_read_b128.
__global__ __launch_bounds__(256) void vq_argmin_kernel(
    const float* __restrict__ node_feat, const float* __restrict__ score,
    const float* __restrict__ cb_c, const float* __restrict__ cb_s,
    const float* __restrict__ cnorm, const float* __restrict__ sxx,
    int* __restrict__ out_idx)
{
    __shared__ float aT[DIM][64];   // [k][node group-swizzled]  32 KB
    __shared__ float bT[32][DIM];   // [k%32][code group-swizzled] 16 KB

    const int cb = blockIdx.y;
    const float* cbp = cb ? cb_s : cb_c;
    const float* cnp = cnorm + cb * NCODES;
    const int nbase = blockIdx.x * 64;
    const int tid = threadIdx.x;
    const int tc = tid & 15;        // code group 0..15
    const int tn = tid >> 4;        // node group 0..15

    // fill aT: coalesced along k, write swizzled
    {
        int k = tid & 127, n0 = tid >> 7;
        for (int p = 0; p < 32; ++p) {
            int n = p * 2 + n0;
            float x = node_feat[(nbase + n) * DIM + k];
            float sc = score[nbase + n];
            int g = (n >> 2) ^ (k & 15);
            aT[k][g * 4 + (n & 3)] = h_of(x, sc, cb);
        }
    }

    float sxx_n[4];
    float best[4]; int bidx[4];
    #pragma unroll
    for (int i = 0; i < 4; ++i) {
        sxx_n[i] = sxx[cb * NODES + nbase + 4 * tn + i];
        best[i] = 3.4e38f; bidx[i] = 0;
    }

    for (int cbase = 0; cbase < NCODES; cbase += 128) {
        float acc[4][8];
        #pragma unroll
        for (int i = 0; i < 4; ++i)
            #pragma unroll
            for (int j = 0; j < 8; ++j) acc[i][j] = 0.0f;

        for (int kc = 0; kc < 4; ++kc) {
            __syncthreads();
            {   // fill bT chunk: coalesced along k, write swizzled
                int kk = tid & 31, c0 = tid >> 5;
                int kglob = kc * 32 + kk;
                #pragma unroll 4
                for (int p = 0; p < 16; ++p) {
                    int c = p * 8 + c0;
                    float v = cbp[(cbase + c) * DIM + kglob];
                    int g = (c >> 2) ^ kk;
                    bT[kk][g * 4 + (c & 3)] = v;
                }
            }
            __syncthreads();

            #pragma unroll 8
            for (int k = 0; k < 32; ++k) {
                int kg = kc * 32 + k;
                float4 av = *(const float4*)&aT[kg][(tn ^ (kg & 15)) << 2];
                float4 b0 = *(const float4*)&bT[k][(tc ^ k) << 2];
                float4 b1 = *(const float4*)&bT[k][((tc + 16) ^ k) << 2];
                float a_[4] = {av.x, av.y, av.z, av.w};
                float b_[8] = {b0.x, b0.y, b0.z, b0.w, b1.x, b1.y, b1.z, b1.w};
                #pragma unroll
                for (int i = 0; i < 4; ++i)
                    #pragma unroll
                    for (int j = 0; j < 8; ++j)
                        acc[i][j] = fmaf(a_[i], b_[j], acc[i][j]);
            }
        }

        // epilogue: d2 = (sxx - 2*dot) + cnorm, exactly as reference association
        #pragma unroll
        for (int i = 0; i < 4; ++i) {
            float sx = sxx_n[i];
            #pragma unroll
            for (int j = 0; j < 8; ++j) {
                int code = cbase + ((j < 4) ? (4 * tc + j) : (64 + 4 * tc + (j - 4)));
                float d2 = __fadd_rn(__fsub_rn(sx, 2.0f * acc[i][j]), cnp[code]);
                if (d2 < best[i]) { best[i] = d2; bidx[i] = code; }   // strict < : lowest idx wins ties
            }
        }
    }

    // reduce across the 16 code-group lanes (within-wave, lanes differ in bits 0..3)
    #pragma unroll
    for (int off = 1; off < 16; off <<= 1) {
        #pragma unroll
        for (int i = 0; i < 4; ++i) {
            float ob = __shfl_xor(best[i], off, 64);
            int   oi = __shfl_xor(bidx[i], off, 64);
            if (ob < best[i] || (ob == best[i] && oi < bidx[i])) { best[i] = ob; bidx[i] = oi; }
        }
    }
    if (tc == 0) {
        #pragma unroll
        for (int i = 0; i < 4; ++i)
            out_idx[cb * NODES + nbase + 4 * tn + i] = bidx[i];
    }
}

// --------------------------------------------------------------- gather ----
__global__ __launch_bounds__(256) void gather_kernel(
    const float* __restrict__ node_feat, const float* __restrict__ score,
    const float* __restrict__ cb_c, const float* __restrict__ cb_s,
    const int* __restrict__ idx_all, float* __restrict__ out,
    double* __restrict__ loss_acc)
{
    __shared__ float redc[4], reds[4];
    int wave = threadIdx.x >> 6, lane = threadIdx.x & 63;
    int node = blockIdx.x * 4 + wave;
    float sc = score[node];
    float2 x  = *(const float2*)&node_feat[node * DIM + 2 * lane];
    int ic = idx_all[node], is_ = idx_all[NODES + node];
    float2 qc = *(const float2*)&cb_c[ic * DIM + 2 * lane];
    float2 qs = *(const float2*)&cb_s[is_ * DIM + 2 * lane];

    float omsc = __fsub_rn(1.0f, sc);
    float2 cn, sn;
    cn.x = __fadd_rn(__fmul_rn(x.x, sc), qc.x);
    cn.y = __fadd_rn(__fmul_rn(x.y, sc), qc.y);
    sn.x = __fadd_rn(__fmul_rn(x.x, omsc), qs.x);
    sn.y = __fadd_rn(__fmul_rn(x.y, omsc), qs.y);
    *(float2*)&out[OFF_CN + node * DIM + 2 * lane] = cn;
    *(float2*)&out[OFF_SN + node * DIM + 2 * lane] = sn;

    float hc1 = h_of(x.x, sc, 0), hc2 = h_of(x.y, sc, 0);
    float hs1 = h_of(x.x, sc, 1), hs2 = h_of(x.y, sc, 1);
    float d1 = qc.x - hc1, d2 = qc.y - hc2;
    float e1 = qs.x - hs1, e2 = qs.y - hs2;
    float lc = d1 * d1 + d2 * d2;
    float ls = e1 * e1 + e2 * e2;
    #pragma unroll
    for (int off = 32; off; off >>= 1) {
        lc += __shfl_down(lc, off, 64);
        ls += __shfl_down(ls, off, 64);
    }
    if (lane == 0) { redc[wave] = lc; reds[wave] = ls; }
    __syncthreads();
    if (threadIdx.x == 0) {
        double tc = (double)redc[0] + redc[1] + redc[2] + redc[3];
        double ts = (double)reds[0] + reds[1] + reds[2] + reds[3];
        atomicAdd(loss_acc, tc);
        atomicAdd(loss_acc + 1, ts);
    }
}

// ----------------------------------------------------------------- pool ----
__global__ __launch_bounds__(256) void pool_kernel(
    const int* __restrict__ starts, float* __restrict__ out)
{
    int g = blockIdx.x;
    int half = threadIdx.x >> 7, d = threadIdx.x & 127;
    int s = starts[g], e = starts[g + 1];
    const float* src = out + (half ? OFF_SN : OFF_CN);
    float sum = 0.0f;
    for (int n = s; n < e; ++n) sum = __fadd_rn(sum, src[n * DIM + d]);
    float cnt = fmaxf((float)(e - s), 1.0f);
    out[(half ? OFF_SG : OFF_CG) + g * DIM + d] = __fdiv_rn(sum, cnt);
}

// ----------------------------------------------------------- classifier ----
__global__ __launch_bounds__(256) void classifier_kernel(
    const float* __restrict__ w1, const float* __restrict__ b1,
    const float* __restrict__ gamma, const float* __restrict__ beta,
    const float* __restrict__ rm, const float* __restrict__ rv,
    const float* __restrict__ w2, const float* __restrict__ b2,
    const double* __restrict__ loss_acc, float* __restrict__ out)
{
    __shared__ float row[DIM];
    __shared__ float red[4];
    int g = blockIdx.x, t = threadIdx.x;
    if (t < DIM) row[t] = out[OFF_CG + g * DIM + t];
    __syncthreads();
    float h = 0.0f;
    #pragma unroll 8
    for (int k = 0; k < DIM; ++k) h = fmaf(row[k], w1[k * 256 + t], h);
    h = __fadd_rn(h, b1[t]);
    float inv = __frsqrt_rn(__fadd_rn(rv[t], 1e-5f));
    h = __fadd_rn(__fmul_rn(__fmul_rn(__fsub_rn(h, rm[t]), inv), gamma[t]), beta[t]);
    h = fmaxf(h, 0.0f);
    float p = __fmul_rn(h, w2[t]);
    #pragma unroll
    for (int off = 32; off; off >>= 1) p += __shfl_down(p, off, 64);
    if ((t & 63) == 0) red[t >> 6] = p;
    __syncthreads();
    if (t == 0) {
        float total = __fadd_rn(__fadd_rn(red[0], red[1]), __fadd_rn(red[2], red[3]));
        out[OFF_LOGIT + g] = __fadd_rn(total, b2[0]);
        if (g == 0) {
            out[OFF_LC] = (float)(loss_acc[0] * (1.0 / 4194304.0));  // / 2^22 exact
            out[OFF_LS] = (float)(loss_acc[1] * (1.0 / 4194304.0));
        }
    }
}

extern "C" void kernel_launch(void* const* d_in, const int* in_sizes, int n_in,
                              void* d_out, int out_size, void* d_ws, size_t ws_size,
                              hipStream_t stream) {
    const float* node_feat = (const float*)d_in[0];
    const float* score     = (const float*)d_in[1];
    const int*   batch     = (const int*)d_in[2];
    const float* cb_c      = (const float*)d_in[3];
    const float* cb_s      = (const float*)d_in[4];
    const float* w1        = (const float*)d_in[5];
    const float* b1        = (const float*)d_in[6];
    const float* gamma     = (const float*)d_in[7];
    const float* beta      = (const float*)d_in[8];
    const float* rm        = (const float*)d_in[9];
    const float* rv        = (const float*)d_in[10];
    const float* w2        = (const float*)d_in[11];
    const float* b2        = (const float*)d_in[12];
    float* out = (float*)d_out;
    char*  ws  = (char*)d_ws;

    float*  cnorm    = (float*)(ws + WS_CNORM);
    float*  sxx      = (float*)(ws + WS_SXX);
    int*    idx      = (int*)(ws + WS_IDX);
    int*    starts   = (int*)(ws + WS_STARTS);
    double* loss_acc = (double*)(ws + WS_LOSS);

    // waves: 8192 (cnorm) + 65536 (sxx) + 9 (bounds) = 73737 -> 18435 blocks
    prep_kernel<<<18435, 256, 0, stream>>>(node_feat, score, cb_c, cb_s, batch,
                                           cnorm, sxx, starts, loss_acc);
    vq_argmin_kernel<<<dim3(512, 2), 256, 0, stream>>>(node_feat, score, cb_c, cb_s,
                                                       cnorm, sxx, idx);
    gather_kernel<<<8192, 256, 0, stream>>>(node_feat, score, cb_c, cb_s, idx, out, loss_acc);
    pool_kernel<<<512, 256, 0, stream>>>(starts, out);
    classifier_kernel<<<512, 256, 0, stream>>>(w1, b1, gamma, beta, rm, rv, w2, b2,
                                               loss_acc, out);
}

// Round 2
// 793.938 us; speedup vs baseline: 1.7457x; 1.7457x over previous
//
#include <hip/hip_runtime.h>
#include <hip/hip_bf16.h>

#define NODES   32768
#define DIM     128
#define NCODES  4096
#define NGRAPHS 512

// output layout (flat f32, concatenated in reference return order)
#define OFF_LOGIT 0
#define OFF_CG    512
#define OFF_SG    66048
#define OFF_LC    131584
#define OFF_LS    131585
#define OFF_CN    131586
#define OFF_SN    4325890

// bf16 split planes live inside d_out's CN region (rewritten by gather later).
// byte 527360 (16B aligned) = ushort index 263680. 4 planes x 1MB.
#define SPLIT_U16   263680
#define PLANE_U16   524288

// workspace layout (bytes) -- total 559124 <= round-1's proven 559128
#define WS_CNORM    0        // float[2][4096]        32768
#define WS_IDX      32768    // int[2][32768]         262144
#define WS_LOSS     294912   // double[2]             16
#define WS_FLAGCNT  294928   // int[2]                8
#define WS_STARTS   294936   // int[513]              2052
#define WS_FLAGLIST 296988   // int[2][32767]         262136
#define FLAG_CAP    32767

typedef __attribute__((ext_vector_type(8))) short bf16x8_t;
typedef __attribute__((ext_vector_type(4))) float f32x4_t;

__device__ __forceinline__ float h_of(float x, float sc, int cb) {
    float omsc = __fsub_rn(1.0f, sc);
    float half_x = __fmul_rn(0.5f, x);
    if (cb == 0)
        return __fadd_rn(__fmul_rn(x, sc), __fmul_rn(half_x, omsc));
    else
        return __fadd_rn(__fmul_rn(x, omsc), __fmul_rn(half_x, sc));
}

__device__ __forceinline__ unsigned short f2bf(float f) {
    __hip_bfloat16 b = __float2bfloat16(f);
    return *reinterpret_cast<unsigned short*>(&b);
}
__device__ __forceinline__ float bf2f(unsigned short u) {
    __hip_bfloat16 b = *reinterpret_cast<__hip_bfloat16*>(&u);
    return __bfloat162float(b);
}

__device__ __forceinline__ void gload_lds16(const void* g, void* l) {
    __builtin_amdgcn_global_load_lds(
        (const __attribute__((address_space(1))) int*)g,
        (__attribute__((address_space(3))) int*)l, 16, 0, 0);
}

// ---------------------------------------------------------------- prep ----
// cnorm + bf16 hi/lo codebook splits + graph boundaries + zero accumulators
__global__ __launch_bounds__(256) void prep_kernel(
    const float* __restrict__ cb_c, const float* __restrict__ cb_s,
    const int* __restrict__ batch,
    float* __restrict__ cnorm, unsigned short* __restrict__ splits,
    int* __restrict__ starts, double* __restrict__ loss_acc,
    int* __restrict__ flagcnt)
{
    int gwave = (blockIdx.x * 256 + threadIdx.x) >> 6;
    int lane  = threadIdx.x & 63;

    if (gwave < 2 * NCODES) {                  // one wave per (cb,row)
        int cb = gwave >> 12, row = gwave & (NCODES - 1);
        const float* cp = (cb ? cb_s : cb_c) + (size_t)row * DIM;
        float2 v = ((const float2*)cp)[lane];  // elems 2l, 2l+1
        // cnorm (exact-fp32-class)
        float p = __fadd_rn(__fmul_rn(v.x, v.x), __fmul_rn(v.y, v.y));
        #pragma unroll
        for (int off = 32; off; off >>= 1) p = __fadd_rn(p, __shfl_xor(p, off, 64));
        if (lane == 0) cnorm[cb * NCODES + row] = p;
        // hi/lo split planes
        unsigned short h0 = f2bf(v.x), h1 = f2bf(v.y);
        unsigned short l0 = f2bf(__fsub_rn(v.x, bf2f(h0)));
        unsigned short l1 = f2bf(__fsub_rn(v.y, bf2f(h1)));
        unsigned int* hp = (unsigned int*)(splits + (size_t)(cb * 2 + 0) * PLANE_U16);
        unsigned int* lp = (unsigned int*)(splits + (size_t)(cb * 2 + 1) * PLANE_U16);
        hp[row * 64 + lane] = (unsigned int)h0 | ((unsigned int)h1 << 16);
        lp[row * 64 + lane] = (unsigned int)l0 | ((unsigned int)l1 << 16);
    } else {
        int w1 = gwave - 2 * NCODES;
        int g = w1 * 64 + lane;
        if (g <= NGRAPHS) {
            int lo = 0, hi = NODES;
            while (lo < hi) { int mid = (lo + hi) >> 1; if (batch[mid] < g) lo = mid + 1; else hi = mid; }
            starts[g] = lo;
        }
        if (w1 == 0) {
            if (lane < 2) loss_acc[lane] = 0.0;
            if (lane >= 2 && lane < 4) flagcnt[lane - 2] = 0;
        }
    }
}

// ----------------------------------------------------------- vq main ----
// 128 nodes/block, 4 waves x 32 nodes; codes tiled by 64, double-buffered
// via global_load_lds (pre-swizzled source). dot = hh+hl+lh in MFMA.
__global__ __launch_bounds__(256, 2) void vq_main_kernel(
    const float* __restrict__ node_feat, const float* __restrict__ score,
    const unsigned short* __restrict__ splits, const float* __restrict__ cnorm,
    int* __restrict__ idx_ws, int* __restrict__ flagcnt, int* __restrict__ flaglist)
{
    __shared__ unsigned short lds[32768];   // 64 KB
    const int cb    = blockIdx.y;
    const int nbase = blockIdx.x * 128;
    const int tid = threadIdx.x;
    const int w   = tid >> 6;
    const int l15 = tid & 15;
    const int lg  = (tid & 63) >> 4;
    const int swz = (tid & 7) << 4;
    const float* cnp = cnorm + cb * NCODES;

    // ---- stage A (h values, hi/lo bf16) into LDS ----
    #pragma unroll
    for (int i = 0; i < 16; ++i) {
        int idx = i * 1024 + tid * 4;
        int row = idx >> 7, k = idx & 127;
        float4 x = *(const float4*)&node_feat[(size_t)(nbase + row) * DIM + k];
        float sc = score[nbase + row];
        float h0 = h_of(x.x, sc, cb), h1 = h_of(x.y, sc, cb);
        float h2 = h_of(x.z, sc, cb), h3 = h_of(x.w, sc, cb);
        unsigned short u0 = f2bf(h0), u1 = f2bf(h1), u2 = f2bf(h2), u3 = f2bf(h3);
        unsigned short v0 = f2bf(__fsub_rn(h0, bf2f(u0))), v1 = f2bf(__fsub_rn(h1, bf2f(u1)));
        unsigned short v2 = f2bf(__fsub_rn(h2, bf2f(u2))), v3 = f2bf(__fsub_rn(h3, bf2f(u3)));
        int abyte = row * 256 + ((2 * k) ^ ((row & 7) << 4));
        uint2 hw; hw.x = (unsigned)u0 | ((unsigned)u1 << 16); hw.y = (unsigned)u2 | ((unsigned)u3 << 16);
        uint2 lw; lw.x = (unsigned)v0 | ((unsigned)v1 << 16); lw.y = (unsigned)v2 | ((unsigned)v3 << 16);
        *(uint2*)((char*)lds + abyte) = hw;
        *(uint2*)((char*)lds + 32768 + abyte) = lw;
    }
    __syncthreads();

    // ---- A fragments to registers ----
    bf16x8_t ahi[2][4], alo[2][4];
    int colbyte[4];
    #pragma unroll
    for (int ch = 0; ch < 4; ++ch) colbyte[ch] = (ch * 64 + lg * 16) ^ swz;
    #pragma unroll
    for (int rs = 0; rs < 2; ++rs)
        #pragma unroll
        for (int ch = 0; ch < 4; ++ch) {
            int row = 32 * w + 16 * rs + l15;
            int off = row * 256 + colbyte[ch];
            ahi[rs][ch] = *(const bf16x8_t*)((const char*)lds + off);
            alo[rs][ch] = *(const bf16x8_t*)((const char*)lds + 32768 + off);
        }
    __syncthreads();   // all A reads done -> LDS reusable as B double-buffer

    // ---- B staging setup (pre-swizzled global source, linear LDS dest) ----
    const unsigned short* wplane = splits + (size_t)(cb * 2 + (w >> 1)) * PLANE_U16;
    int soff[8];
    #pragma unroll
    for (int i = 0; i < 8; ++i) {
        int row = ((w & 1) << 5) + i * 4 + lg;
        soff[i] = row * 256 + ((l15 * 16) ^ ((row & 7) << 4));
    }

    // issue tile 0 -> buf0
    {
        const char* tb = (const char*)wplane;
        #pragma unroll
        for (int i = 0; i < 8; ++i)
            gload_lds16(tb + soff[i], (char*)lds + w * 8192 + i * 1024);
    }
    float cnc[4], cnn[4];
    #pragma unroll
    for (int cs = 0; cs < 4; ++cs) cnc[cs] = cnp[cs * 16 + l15];
    __syncthreads();   // drains vmcnt -> tile0 ready

    const float NEG_INF = -3.4e38f;
    float b1v[2][4], b2v[2][4]; int b1i[2][4];
    #pragma unroll
    for (int rs = 0; rs < 2; ++rs)
        #pragma unroll
        for (int r = 0; r < 4; ++r) { b1v[rs][r] = NEG_INF; b2v[rs][r] = NEG_INF; b1i[rs][r] = 0; }

    for (int t = 0; t < 64; ++t) {
        int bs_cur = (t & 1) << 15;   // byte offset of current buffer
        if (t < 63) {
            int bs_nxt = ((t + 1) & 1) << 15;
            const char* tb = (const char*)wplane + (t + 1) * 16384;
            #pragma unroll
            for (int i = 0; i < 8; ++i)
                gload_lds16(tb + soff[i], (char*)lds + bs_nxt + w * 8192 + i * 1024);
            #pragma unroll
            for (int cs = 0; cs < 4; ++cs) cnn[cs] = cnp[(t + 1) * 64 + cs * 16 + l15];
        }

        // acc init folds cnorm: acc = -0.5*cn; final a = dot - 0.5*cn; d = -2a
        f32x4_t acc[2][4];
        #pragma unroll
        for (int cs = 0; cs < 4; ++cs) {
            float iv = -0.5f * cnc[cs];
            f32x4_t ini = {iv, iv, iv, iv};
            acc[0][cs] = ini; acc[1][cs] = ini;
        }

        #pragma unroll
        for (int ch = 0; ch < 4; ++ch) {
            #pragma unroll
            for (int cs = 0; cs < 4; ++cs) {
                const char* bp = (const char*)lds + bs_cur + (cs * 16 + l15) * 256 + colbyte[ch];
                bf16x8_t bhi = *(const bf16x8_t*)bp;
                bf16x8_t blo = *(const bf16x8_t*)(bp + 16384);
                #pragma unroll
                for (int rs = 0; rs < 2; ++rs) {
                    acc[rs][cs] = __builtin_amdgcn_mfma_f32_16x16x32_bf16(ahi[rs][ch], bhi, acc[rs][cs], 0, 0, 0);
                    acc[rs][cs] = __builtin_amdgcn_mfma_f32_16x16x32_bf16(alo[rs][ch], bhi, acc[rs][cs], 0, 0, 0);
                    acc[rs][cs] = __builtin_amdgcn_mfma_f32_16x16x32_bf16(ahi[rs][ch], blo, acc[rs][cs], 0, 0, 0);
                }
            }
        }

        // epilogue: track max(a) (== min distance), second max, index
        #pragma unroll
        for (int cs = 0; cs < 4; ++cs) {
            int code = t * 64 + cs * 16 + l15;
            #pragma unroll
            for (int rs = 0; rs < 2; ++rs)
                #pragma unroll
                for (int r = 0; r < 4; ++r) {
                    float a = acc[rs][cs][r];
                    bool gt = a > b1v[rs][r];
                    float nb2 = __builtin_amdgcn_fmed3f(a, b1v[rs][r], b2v[rs][r]);
                    if (gt) b1i[rs][r] = code;
                    b1v[rs][r] = fmaxf(a, b1v[rs][r]);
                    b2v[rs][r] = nb2;
                }
        }
        #pragma unroll
        for (int cs = 0; cs < 4; ++cs) cnc[cs] = cnn[cs];
        __syncthreads();   // drains gll vmcnt; protects buffer swap
    }

    // cross-lane merge over the 16 code-columns (lane bits 0..3)
    #pragma unroll
    for (int off = 1; off < 16; off <<= 1) {
        #pragma unroll
        for (int rs = 0; rs < 2; ++rs)
            #pragma unroll
            for (int r = 0; r < 4; ++r) {
                float ov1 = __shfl_xor(b1v[rs][r], off, 64);
                int   oi  = __shfl_xor(b1i[rs][r], off, 64);
                float ov2 = __shfl_xor(b2v[rs][r], off, 64);
                bool take = (ov1 > b1v[rs][r]) || (ov1 == b1v[rs][r] && oi < b1i[rs][r]);
                float loser = fminf(ov1, b1v[rs][r]);
                b1v[rs][r] = fmaxf(ov1, b1v[rs][r]);
                if (take) b1i[rs][r] = oi;
                b2v[rs][r] = fmaxf(loser, fmaxf(ov2, b2v[rs][r]));
            }
    }
    if (l15 == 0) {
        #pragma unroll
        for (int rs = 0; rs < 2; ++rs)
            #pragma unroll
            for (int r = 0; r < 4; ++r) {
                int node = nbase + 32 * w + 16 * rs + 4 * lg + r;
                idx_ws[cb * NODES + node] = b1i[rs][r];
                if (b1v[rs][r] - b2v[rs][r] < 0.04f) {     // d-space gap < 0.08
                    int p = atomicAdd(flagcnt + cb, 1);
                    if (p < FLAG_CAP) flaglist[cb * FLAG_CAP + p] = node;
                }
            }
    }
}

// --------------------------------------------------------- vq cleanup ----
// exact fp32 re-argmin for flagged (near-tie) nodes
__global__ __launch_bounds__(256) void vq_cleanup_kernel(
    const float* __restrict__ node_feat, const float* __restrict__ score,
    const float* __restrict__ cb_c, const float* __restrict__ cb_s,
    const float* __restrict__ cnorm, const int* __restrict__ flagcnt,
    const int* __restrict__ flaglist, int* __restrict__ idx_ws)
{
    __shared__ float cbT[128][65];
    __shared__ float hbuf[4][128];
    const int cb = blockIdx.y;
    const float* cbp = cb ? cb_s : cb_c;
    const float* cnp = cnorm + cb * NCODES;
    const int* list = flaglist + cb * FLAG_CAP;
    int cnt = flagcnt[cb]; if (cnt > FLAG_CAP) cnt = FLAG_CAP;
    const int tid = threadIdx.x, w = tid >> 6, l = tid & 63;

    for (int base = blockIdx.x * 4; base < cnt; base += 128 * 4) {
        int e = base + w;
        bool valid = e < cnt;
        int node = list[valid ? e : base];
        float sc = score[node];
        float x0 = node_feat[(size_t)node * DIM + l];
        float x1 = node_feat[(size_t)node * DIM + 64 + l];
        float h0 = h_of(x0, sc, cb), h1 = h_of(x1, sc, cb);
        hbuf[w][l] = h0; hbuf[w][64 + l] = h1;
        float sxx = __fadd_rn(__fmul_rn(h0, h0), __fmul_rn(h1, h1));
        #pragma unroll
        for (int off = 32; off; off >>= 1) sxx = __fadd_rn(sxx, __shfl_xor(sxx, off, 64));
        asm volatile("s_waitcnt lgkmcnt(0)" ::: "memory");

        float bestv = 3.4e38f; int besti = 0;
        for (int q = 0; q < 64; ++q) {
            __syncthreads();
            {   // stage 64-code chunk transposed
                int c = tid >> 2, ks = (tid & 3) * 32;
                const float* src = cbp + (size_t)(q * 64 + c) * DIM + ks;
                #pragma unroll
                for (int j = 0; j < 8; ++j) {
                    float4 v = *(const float4*)(src + j * 4);
                    cbT[ks + j * 4 + 0][c] = v.x;
                    cbT[ks + j * 4 + 1][c] = v.y;
                    cbT[ks + j * 4 + 2][c] = v.z;
                    cbT[ks + j * 4 + 3][c] = v.w;
                }
            }
            __syncthreads();
            int code = q * 64 + l;
            float p0 = 0.f, p1 = 0.f, p2 = 0.f, p3 = 0.f;
            #pragma unroll 8
            for (int m = 0; m < 32; ++m) {
                p0 = fmaf(hbuf[w][4 * m + 0], cbT[4 * m + 0][l], p0);
                p1 = fmaf(hbuf[w][4 * m + 1], cbT[4 * m + 1][l], p1);
                p2 = fmaf(hbuf[w][4 * m + 2], cbT[4 * m + 2][l], p2);
                p3 = fmaf(hbuf[w][4 * m + 3], cbT[4 * m + 3][l], p3);
            }
            float dot = __fadd_rn(__fadd_rn(p0, p1), __fadd_rn(p2, p3));
            float d2 = __fadd_rn(__fsub_rn(sxx, __fmul_rn(2.0f, dot)), cnp[code]);
            if (d2 < bestv) { bestv = d2; besti = code; }
        }
        #pragma unroll
        for (int off = 1; off < 64; off <<= 1) {
            float ov = __shfl_xor(bestv, off, 64);
            int   oi = __shfl_xor(besti, off, 64);
            if (ov < bestv || (ov == bestv && oi < besti)) { bestv = ov; besti = oi; }
        }
        if (valid && l == 0) idx_ws[cb * NODES + node] = besti;
    }
}

// --------------------------------------------------------------- gather ----
__global__ __launch_bounds__(256) void gather_kernel(
    const float* __restrict__ node_feat, const float* __restrict__ score,
    const float* __restrict__ cb_c, const float* __restrict__ cb_s,
    const int* __restrict__ idx_all, float* __restrict__ out,
    double* __restrict__ loss_acc)
{
    __shared__ float redc[4], reds[4];
    int wave = threadIdx.x >> 6, lane = threadIdx.x & 63;
    int node = blockIdx.x * 4 + wave;
    float sc = score[node];
    float2 x  = *(const float2*)&node_feat[(size_t)node * DIM + 2 * lane];
    int ic = idx_all[node], is_ = idx_all[NODES + node];
    float2 qc = *(const float2*)&cb_c[(size_t)ic * DIM + 2 * lane];
    float2 qs = *(const float2*)&cb_s[(size_t)is_ * DIM + 2 * lane];

    float omsc = __fsub_rn(1.0f, sc);
    float2 cn, sn;
    cn.x = __fadd_rn(__fmul_rn(x.x, sc), qc.x);
    cn.y = __fadd_rn(__fmul_rn(x.y, sc), qc.y);
    sn.x = __fadd_rn(__fmul_rn(x.x, omsc), qs.x);
    sn.y = __fadd_rn(__fmul_rn(x.y, omsc), qs.y);
    *(float2*)&out[OFF_CN + (size_t)node * DIM + 2 * lane] = cn;
    *(float2*)&out[OFF_SN + (size_t)node * DIM + 2 * lane] = sn;

    float hc1 = h_of(x.x, sc, 0), hc2 = h_of(x.y, sc, 0);
    float hs1 = h_of(x.x, sc, 1), hs2 = h_of(x.y, sc, 1);
    float d1 = qc.x - hc1, d2 = qc.y - hc2;
    float e1 = qs.x - hs1, e2 = qs.y - hs2;
    float lc = d1 * d1 + d2 * d2;
    float ls = e1 * e1 + e2 * e2;
    #pragma unroll
    for (int off = 32; off; off >>= 1) {
        lc += __shfl_down(lc, off, 64);
        ls += __shfl_down(ls, off, 64);
    }
    if (lane == 0) { redc[wave] = lc; reds[wave] = ls; }
    __syncthreads();
    if (threadIdx.x == 0) {
        double tc = (double)redc[0] + redc[1] + redc[2] + redc[3];
        double ts = (double)reds[0] + reds[1] + reds[2] + reds[3];
        atomicAdd(loss_acc, tc);
        atomicAdd(loss_acc + 1, ts);
    }
}

// ----------------------------------------------------------------- pool ----
__global__ __launch_bounds__(256) void pool_kernel(
    const int* __restrict__ starts, float* __restrict__ out)
{
    int g = blockIdx.x;
    int half = threadIdx.x >> 7, d = threadIdx.x & 127;
    int s = starts[g], e = starts[g + 1];
    const float* src = out + (half ? OFF_SN : OFF_CN);
    float sum = 0.0f;
    for (int n = s; n < e; ++n) sum = __fadd_rn(sum, src[(size_t)n * DIM + d]);
    float cnt = fmaxf((float)(e - s), 1.0f);
    out[(half ? OFF_SG : OFF_CG) + g * DIM + d] = __fdiv_rn(sum, cnt);
}

// ----------------------------------------------------------- classifier ----
__global__ __launch_bounds__(256) void classifier_kernel(
    const float* __restrict__ w1, const float* __restrict__ b1,
    const float* __restrict__ gamma, const float* __restrict__ beta,
    const float* __restrict__ rm, const float* __restrict__ rv,
    const float* __restrict__ w2, const float* __restrict__ b2,
    const double* __restrict__ loss_acc, float* __restrict__ out)
{
    __shared__ float row[DIM];
    __shared__ float red[4];
    int g = blockIdx.x, t = threadIdx.x;
    if (t < DIM) row[t] = out[OFF_CG + g * DIM + t];
    __syncthreads();
    float h = 0.0f;
    #pragma unroll 8
    for (int k = 0; k < DIM; ++k) h = fmaf(row[k], w1[k * 256 + t], h);
    h = __fadd_rn(h, b1[t]);
    float inv = __frsqrt_rn(__fadd_rn(rv[t], 1e-5f));
    h = __fadd_rn(__fmul_rn(__fmul_rn(__fsub_rn(h, rm[t]), inv), gamma[t]), beta[t]);
    h = fmaxf(h, 0.0f);
    float p = __fmul_rn(h, w2[t]);
    #pragma unroll
    for (int off = 32; off; off >>= 1) p += __shfl_down(p, off, 64);
    if ((t & 63) == 0) red[t >> 6] = p;
    __syncthreads();
    if (t == 0) {
        float total = __fadd_rn(__fadd_rn(red[0], red[1]), __fadd_rn(red[2], red[3]));
        out[OFF_LOGIT + g] = __fadd_rn(total, b2[0]);
        if (g == 0) {
            out[OFF_LC] = (float)(loss_acc[0] * (1.0 / 4194304.0));
            out[OFF_LS] = (float)(loss_acc[1] * (1.0 / 4194304.0));
        }
    }
}

extern "C" void kernel_launch(void* const* d_in, const int* in_sizes, int n_in,
                              void* d_out, int out_size, void* d_ws, size_t ws_size,
                              hipStream_t stream) {
    const float* node_feat = (const float*)d_in[0];
    const float* score     = (const float*)d_in[1];
    const int*   batch     = (const int*)d_in[2];
    const float* cb_c      = (const float*)d_in[3];
    const float* cb_s      = (const float*)d_in[4];
    const float* w1        = (const float*)d_in[5];
    const float* b1        = (const float*)d_in[6];
    const float* gamma     = (const float*)d_in[7];
    const float* beta      = (const float*)d_in[8];
    const float* rm        = (const float*)d_in[9];
    const float* rv        = (const float*)d_in[10];
    const float* w2        = (const float*)d_in[11];
    const float* b2        = (const float*)d_in[12];
    float* out = (float*)d_out;
    char*  ws  = (char*)d_ws;

    float*  cnorm    = (float*)(ws + WS_CNORM);
    int*    idx      = (int*)(ws + WS_IDX);
    double* loss_acc = (double*)(ws + WS_LOSS);
    int*    flagcnt  = (int*)(ws + WS_FLAGCNT);
    int*    starts   = (int*)(ws + WS_STARTS);
    int*    flaglist = (int*)(ws + WS_FLAGLIST);
    unsigned short* splits = (unsigned short*)d_out + SPLIT_U16;

    // waves: 8192 (cnorm+splits) + 9 (bounds/zero) = 8201 -> 2051 blocks
    prep_kernel<<<2051, 256, 0, stream>>>(cb_c, cb_s, batch, cnorm, splits,
                                          starts, loss_acc, flagcnt);
    vq_main_kernel<<<dim3(256, 2), 256, 0, stream>>>(node_feat, score, splits, cnorm,
                                                     idx, flagcnt, flaglist);
    vq_cleanup_kernel<<<dim3(128, 2), 256, 0, stream>>>(node_feat, score, cb_c, cb_s,
                                                        cnorm, flagcnt, flaglist, idx);
    gather_kernel<<<8192, 256, 0, stream>>>(node_feat, score, cb_c, cb_s, idx, out, loss_acc);
    pool_kernel<<<512, 256, 0, stream>>>(starts, out);
    classifier_kernel<<<512, 256, 0, stream>>>(w1, b1, gamma, beta, rm, rv, w2, b2,
                                               loss_acc, out);
}

// Round 3
// 566.455 us; speedup vs baseline: 2.4468x; 1.4016x over previous
//
#include <hip/hip_runtime.h>
#include <hip/hip_bf16.h>

#define NODES   32768
#define DIM     128
#define NCODES  4096
#define NGRAPHS 512

// output layout (flat f32, concatenated in reference return order)
#define OFF_LOGIT 0
#define OFF_CG    512
#define OFF_SG    66048
#define OFF_LC    131584
#define OFF_LS    131585
#define OFF_CN    131586
#define OFF_SN    4325890

// scratch regions inside d_out's CN region (rewritten by gather later):
//   split planes: ushort idx 263680 .. 2360832  (4 planes x 1 MB)
//   argmin slots: float idx 1180416 .. 1311488  (u64[2][32768], 8B-aligned)
#define SPLIT_U16   263680
#define PLANE_U16   524288
#define SLOT_F32    1180416

// workspace layout (bytes)
#define WS_CNORM    0        // float[2][4096]        32768
#define WS_IDX      32768    // int[2][32768]         262144
#define WS_LOSS     294912   // double[2]             16
#define WS_FLAGCNT  294928   // int[2]                8
#define WS_STARTS   294936   // int[513]              2052
#define WS_FLAGLIST 296988   // int[2][32767]         262136
#define FLAG_CAP    32767

typedef __attribute__((ext_vector_type(8))) short bf16x8_t;
typedef __attribute__((ext_vector_type(4))) float f32x4_t;

__device__ __forceinline__ float h_of(float x, float sc, int cb) {
    float omsc = __fsub_rn(1.0f, sc);
    float half_x = __fmul_rn(0.5f, x);
    if (cb == 0)
        return __fadd_rn(__fmul_rn(x, sc), __fmul_rn(half_x, omsc));
    else
        return __fadd_rn(__fmul_rn(x, omsc), __fmul_rn(half_x, sc));
}

__device__ __forceinline__ unsigned short f2bf(float f) {
    __hip_bfloat16 b = __float2bfloat16(f);
    return *reinterpret_cast<unsigned short*>(&b);
}
__device__ __forceinline__ float bf2f(unsigned short u) {
    __hip_bfloat16 b = *reinterpret_cast<__hip_bfloat16*>(&u);
    return __bfloat162float(b);
}

__device__ __forceinline__ void gload_lds16(const void* g, void* l) {
    __builtin_amdgcn_global_load_lds(
        (const __attribute__((address_space(1))) int*)g,
        (__attribute__((address_space(3))) int*)l, 16, 0, 0);
}

// ---------------------------------------------------------------- prep ----
__global__ __launch_bounds__(256) void prep_kernel(
    const float* __restrict__ cb_c, const float* __restrict__ cb_s,
    const int* __restrict__ batch,
    float* __restrict__ cnorm, unsigned short* __restrict__ splits,
    int* __restrict__ starts, double* __restrict__ loss_acc,
    int* __restrict__ flagcnt)
{
    int gwave = (blockIdx.x * 256 + threadIdx.x) >> 6;
    int lane  = threadIdx.x & 63;

    if (gwave < 2 * NCODES) {                  // one wave per (cb,row)
        int cb = gwave >> 12, row = gwave & (NCODES - 1);
        const float* cp = (cb ? cb_s : cb_c) + (size_t)row * DIM;
        float2 v = ((const float2*)cp)[lane];  // elems 2l, 2l+1
        float p = __fadd_rn(__fmul_rn(v.x, v.x), __fmul_rn(v.y, v.y));
        #pragma unroll
        for (int off = 32; off; off >>= 1) p = __fadd_rn(p, __shfl_xor(p, off, 64));
        if (lane == 0) cnorm[cb * NCODES + row] = p;
        unsigned short h0 = f2bf(v.x), h1 = f2bf(v.y);
        unsigned short l0 = f2bf(__fsub_rn(v.x, bf2f(h0)));
        unsigned short l1 = f2bf(__fsub_rn(v.y, bf2f(h1)));
        unsigned int* hp = (unsigned int*)(splits + (size_t)(cb * 2 + 0) * PLANE_U16);
        unsigned int* lp = (unsigned int*)(splits + (size_t)(cb * 2 + 1) * PLANE_U16);
        hp[row * 64 + lane] = (unsigned int)h0 | ((unsigned int)h1 << 16);
        lp[row * 64 + lane] = (unsigned int)l0 | ((unsigned int)l1 << 16);
    } else {
        int w1 = gwave - 2 * NCODES;
        int g = w1 * 64 + lane;
        if (g <= NGRAPHS) {
            int lo = 0, hi = NODES;
            while (lo < hi) { int mid = (lo + hi) >> 1; if (batch[mid] < g) lo = mid + 1; else hi = mid; }
            starts[g] = lo;
        }
        if (w1 == 0) {
            if (lane < 2) loss_acc[lane] = 0.0;
            if (lane >= 2 && lane < 4) flagcnt[lane - 2] = 0;
        }
    }
}

// ----------------------------------------------------------- vq main ----
__global__ __launch_bounds__(256, 2) void vq_main_kernel(
    const float* __restrict__ node_feat, const float* __restrict__ score,
    const unsigned short* __restrict__ splits, const float* __restrict__ cnorm,
    int* __restrict__ idx_ws, int* __restrict__ flagcnt, int* __restrict__ flaglist,
    unsigned long long* __restrict__ slots)
{
    __shared__ unsigned short lds[32768];   // 64 KB
    const int cb    = blockIdx.y;
    const int nbase = blockIdx.x * 128;
    const int tid = threadIdx.x;
    const int w   = tid >> 6;
    const int l15 = tid & 15;
    const int lg  = (tid & 63) >> 4;
    const int swz = (tid & 7) << 4;
    const float* cnp = cnorm + cb * NCODES;

    // init argmin slots for this block's nodes (consumed by cleanup's atomicMin)
    if (tid < 128) slots[(size_t)cb * NODES + nbase + tid] = ~0ull;

    // ---- stage A (h values, hi/lo bf16) into LDS ----
    #pragma unroll
    for (int i = 0; i < 16; ++i) {
        int idx = i * 1024 + tid * 4;
        int row = idx >> 7, k = idx & 127;
        float4 x = *(const float4*)&node_feat[(size_t)(nbase + row) * DIM + k];
        float sc = score[nbase + row];
        float h0 = h_of(x.x, sc, cb), h1 = h_of(x.y, sc, cb);
        float h2 = h_of(x.z, sc, cb), h3 = h_of(x.w, sc, cb);
        unsigned short u0 = f2bf(h0), u1 = f2bf(h1), u2 = f2bf(h2), u3 = f2bf(h3);
        unsigned short v0 = f2bf(__fsub_rn(h0, bf2f(u0))), v1 = f2bf(__fsub_rn(h1, bf2f(u1)));
        unsigned short v2 = f2bf(__fsub_rn(h2, bf2f(u2))), v3 = f2bf(__fsub_rn(h3, bf2f(u3)));
        int abyte = row * 256 + ((2 * k) ^ ((row & 7) << 4));
        uint2 hw; hw.x = (unsigned)u0 | ((unsigned)u1 << 16); hw.y = (unsigned)u2 | ((unsigned)u3 << 16);
        uint2 lw; lw.x = (unsigned)v0 | ((unsigned)v1 << 16); lw.y = (unsigned)v2 | ((unsigned)v3 << 16);
        *(uint2*)((char*)lds + abyte) = hw;
        *(uint2*)((char*)lds + 32768 + abyte) = lw;
    }
    __syncthreads();

    // ---- A fragments to registers ----
    bf16x8_t ahi[2][4], alo[2][4];
    int colbyte[4];
    #pragma unroll
    for (int ch = 0; ch < 4; ++ch) colbyte[ch] = (ch * 64 + lg * 16) ^ swz;
    #pragma unroll
    for (int rs = 0; rs < 2; ++rs)
        #pragma unroll
        for (int ch = 0; ch < 4; ++ch) {
            int row = 32 * w + 16 * rs + l15;
            int off = row * 256 + colbyte[ch];
            ahi[rs][ch] = *(const bf16x8_t*)((const char*)lds + off);
            alo[rs][ch] = *(const bf16x8_t*)((const char*)lds + 32768 + off);
        }
    __syncthreads();   // all A reads done -> LDS reusable as B double-buffer

    // ---- B staging setup (pre-swizzled global source, linear LDS dest) ----
    const unsigned short* wplane = splits + (size_t)(cb * 2 + (w >> 1)) * PLANE_U16;
    int soff[8];
    #pragma unroll
    for (int i = 0; i < 8; ++i) {
        int row = ((w & 1) << 5) + i * 4 + lg;
        soff[i] = row * 256 + ((l15 * 16) ^ ((row & 7) << 4));
    }

    {
        const char* tb = (const char*)wplane;
        #pragma unroll
        for (int i = 0; i < 8; ++i)
            gload_lds16(tb + soff[i], (char*)lds + w * 8192 + i * 1024);
    }
    float cnc[4], cnn[4];
    #pragma unroll
    for (int cs = 0; cs < 4; ++cs) cnc[cs] = cnp[cs * 16 + l15];
    __syncthreads();   // drains vmcnt -> tile0 ready

    const float NEG_INF = -3.4e38f;
    float b1v[2][4], b2v[2][4]; int b1i[2][4];
    #pragma unroll
    for (int rs = 0; rs < 2; ++rs)
        #pragma unroll
        for (int r = 0; r < 4; ++r) { b1v[rs][r] = NEG_INF; b2v[rs][r] = NEG_INF; b1i[rs][r] = 0; }

    for (int t = 0; t < 64; ++t) {
        int bs_cur = (t & 1) << 15;
        if (t < 63) {
            int bs_nxt = ((t + 1) & 1) << 15;
            const char* tb = (const char*)wplane + (t + 1) * 16384;
            #pragma unroll
            for (int i = 0; i < 8; ++i)
                gload_lds16(tb + soff[i], (char*)lds + bs_nxt + w * 8192 + i * 1024);
            #pragma unroll
            for (int cs = 0; cs < 4; ++cs) cnn[cs] = cnp[(t + 1) * 64 + cs * 16 + l15];
        }

        f32x4_t acc[2][4];
        #pragma unroll
        for (int cs = 0; cs < 4; ++cs) {
            float iv = -0.5f * cnc[cs];
            f32x4_t ini = {iv, iv, iv, iv};
            acc[0][cs] = ini; acc[1][cs] = ini;
        }

        #pragma unroll
        for (int ch = 0; ch < 4; ++ch) {
            #pragma unroll
            for (int cs = 0; cs < 4; ++cs) {
                const char* bp = (const char*)lds + bs_cur + (cs * 16 + l15) * 256 + colbyte[ch];
                bf16x8_t bhi = *(const bf16x8_t*)bp;
                bf16x8_t blo = *(const bf16x8_t*)(bp + 16384);
                #pragma unroll
                for (int rs = 0; rs < 2; ++rs) {
                    acc[rs][cs] = __builtin_amdgcn_mfma_f32_16x16x32_bf16(ahi[rs][ch], bhi, acc[rs][cs], 0, 0, 0);
                    acc[rs][cs] = __builtin_amdgcn_mfma_f32_16x16x32_bf16(alo[rs][ch], bhi, acc[rs][cs], 0, 0, 0);
                    acc[rs][cs] = __builtin_amdgcn_mfma_f32_16x16x32_bf16(ahi[rs][ch], blo, acc[rs][cs], 0, 0, 0);
                }
            }
        }

        #pragma unroll
        for (int cs = 0; cs < 4; ++cs) {
            int code = t * 64 + cs * 16 + l15;
            #pragma unroll
            for (int rs = 0; rs < 2; ++rs)
                #pragma unroll
                for (int r = 0; r < 4; ++r) {
                    float a = acc[rs][cs][r];
                    bool gt = a > b1v[rs][r];
                    float nb2 = __builtin_amdgcn_fmed3f(a, b1v[rs][r], b2v[rs][r]);
                    if (gt) b1i[rs][r] = code;
                    b1v[rs][r] = fmaxf(a, b1v[rs][r]);
                    b2v[rs][r] = nb2;
                }
        }
        #pragma unroll
        for (int cs = 0; cs < 4; ++cs) cnc[cs] = cnn[cs];
        __syncthreads();
    }

    #pragma unroll
    for (int off = 1; off < 16; off <<= 1) {
        #pragma unroll
        for (int rs = 0; rs < 2; ++rs)
            #pragma unroll
            for (int r = 0; r < 4; ++r) {
                float ov1 = __shfl_xor(b1v[rs][r], off, 64);
                int   oi  = __shfl_xor(b1i[rs][r], off, 64);
                float ov2 = __shfl_xor(b2v[rs][r], off, 64);
                bool take = (ov1 > b1v[rs][r]) || (ov1 == b1v[rs][r] && oi < b1i[rs][r]);
                float loser = fminf(ov1, b1v[rs][r]);
                b1v[rs][r] = fmaxf(ov1, b1v[rs][r]);
                if (take) b1i[rs][r] = oi;
                b2v[rs][r] = fmaxf(loser, fmaxf(ov2, b2v[rs][r]));
            }
    }
    if (l15 == 0) {
        #pragma unroll
        for (int rs = 0; rs < 2; ++rs)
            #pragma unroll
            for (int r = 0; r < 4; ++r) {
                int node = nbase + 32 * w + 16 * rs + 4 * lg + r;
                idx_ws[cb * NODES + node] = b1i[rs][r];
                if (b1v[rs][r] - b2v[rs][r] < 0.04f) {     // d-space gap < 0.08
                    int p = atomicAdd(flagcnt + cb, 1);
                    if (p < FLAG_CAP) flaglist[cb * FLAG_CAP + p] = node;
                }
            }
    }
}

// --------------------------------------------------------- vq cleanup ----
// (node-group x 64-code-segment)-parallel exact fp32 rescore; merge via
// atomicMin on packed (flipped-d2 || code) u64 -> exact lowest-idx tiebreak.
__global__ __launch_bounds__(256) void vq_cleanup_kernel(
    const float* __restrict__ node_feat, const float* __restrict__ score,
    const float* __restrict__ cb_c, const float* __restrict__ cb_s,
    const float* __restrict__ cnorm, const int* __restrict__ flagcnt,
    const int* __restrict__ flaglist, unsigned long long* __restrict__ slots)
{
    __shared__ float cbT[128][65];
    __shared__ float hbuf[4][128];
    const int cb  = blockIdx.y;
    const int seg = blockIdx.x & 63;    // 64-code segment
    const int ng  = blockIdx.x >> 6;    // node-group 0..7
    const float* cbp = cb ? cb_s : cb_c;
    const int* list = flaglist + cb * FLAG_CAP;
    int cnt = flagcnt[cb]; if (cnt > FLAG_CAP) cnt = FLAG_CAP;
    const int tid = threadIdx.x, w = tid >> 6, l = tid & 63;

    {   // stage this segment's 64 codes transposed, once
        int c = tid >> 2, ks = (tid & 3) * 32;
        const float* src = cbp + (size_t)(seg * 64 + c) * DIM + ks;
        #pragma unroll
        for (int j = 0; j < 8; ++j) {
            float4 v = *(const float4*)(src + j * 4);
            cbT[ks + j * 4 + 0][c] = v.x;
            cbT[ks + j * 4 + 1][c] = v.y;
            cbT[ks + j * 4 + 2][c] = v.z;
            cbT[ks + j * 4 + 3][c] = v.w;
        }
    }
    const int mycode = seg * 64 + l;
    const float cn = cnorm[cb * NCODES + mycode];
    __syncthreads();

    for (int base = ng * 4; base < cnt; base += 32) {
        int e = base + w;
        bool valid = e < cnt;
        int node = list[valid ? e : 0];
        float sc = score[node];
        float x0 = node_feat[(size_t)node * DIM + l];
        float x1 = node_feat[(size_t)node * DIM + 64 + l];
        float h0 = h_of(x0, sc, cb), h1 = h_of(x1, sc, cb);
        hbuf[w][l] = h0; hbuf[w][64 + l] = h1;
        float sxx = __fadd_rn(__fmul_rn(h0, h0), __fmul_rn(h1, h1));
        #pragma unroll
        for (int off = 32; off; off >>= 1) sxx = __fadd_rn(sxx, __shfl_xor(sxx, off, 64));
        asm volatile("s_waitcnt lgkmcnt(0)" ::: "memory");

        float p0 = 0.f, p1 = 0.f, p2 = 0.f, p3 = 0.f;
        #pragma unroll 8
        for (int m = 0; m < 32; ++m) {
            p0 = fmaf(hbuf[w][4 * m + 0], cbT[4 * m + 0][l], p0);
            p1 = fmaf(hbuf[w][4 * m + 1], cbT[4 * m + 1][l], p1);
            p2 = fmaf(hbuf[w][4 * m + 2], cbT[4 * m + 2][l], p2);
            p3 = fmaf(hbuf[w][4 * m + 3], cbT[4 * m + 3][l], p3);
        }
        float dot = __fadd_rn(__fadd_rn(p0, p1), __fadd_rn(p2, p3));
        float d2 = __fadd_rn(__fsub_rn(sxx, __fmul_rn(2.0f, dot)), cn);

        unsigned b = __float_as_uint(d2);
        unsigned key = (b & 0x80000000u) ? ~b : (b | 0x80000000u);
        unsigned long long pk = ((unsigned long long)key << 32) | (unsigned)mycode;
        #pragma unroll
        for (int off = 1; off < 64; off <<= 1) {
            unsigned long long o = __shfl_xor(pk, off, 64);
            pk = (o < pk) ? o : pk;
        }
        if (valid && l == 0)
            atomicMin(&slots[(size_t)cb * NODES + node], pk);
        asm volatile("s_waitcnt lgkmcnt(0)" ::: "memory");
    }
}

// ------------------------------------------------------- flag writeback ----
__global__ __launch_bounds__(256) void flag_writeback_kernel(
    const int* __restrict__ flagcnt, const int* __restrict__ flaglist,
    const unsigned long long* __restrict__ slots, int* __restrict__ idx_ws)
{
    int gt = blockIdx.x * 256 + threadIdx.x;
    int c0 = flagcnt[0]; if (c0 > FLAG_CAP) c0 = FLAG_CAP;
    int c1 = flagcnt[1]; if (c1 > FLAG_CAP) c1 = FLAG_CAP;
    for (int e = gt; e < 2 * FLAG_CAP; e += 256 * 256) {
        int cb = (e >= FLAG_CAP) ? 1 : 0;
        int i = e - cb * FLAG_CAP;
        int cnt = cb ? c1 : c0;
        if (i < cnt) {
            int node = flaglist[cb * FLAG_CAP + i];
            idx_ws[cb * NODES + node] =
                (int)(slots[(size_t)cb * NODES + node] & 0xFFFFFFFFull);
        }
    }
}

// --------------------------------------------------------------- gather ----
__global__ __launch_bounds__(256) void gather_kernel(
    const float* __restrict__ node_feat, const float* __restrict__ score,
    const float* __restrict__ cb_c, const float* __restrict__ cb_s,
    const int* __restrict__ idx_all, float* __restrict__ out,
    double* __restrict__ loss_acc)
{
    __shared__ float redc[4], reds[4];
    int wave = threadIdx.x >> 6, lane = threadIdx.x & 63;
    int node = blockIdx.x * 4 + wave;
    float sc = score[node];
    float2 x  = *(const float2*)&node_feat[(size_t)node * DIM + 2 * lane];
    int ic = idx_all[node], is_ = idx_all[NODES + node];
    float2 qc = *(const float2*)&cb_c[(size_t)ic * DIM + 2 * lane];
    float2 qs = *(const float2*)&cb_s[(size_t)is_ * DIM + 2 * lane];

    float omsc = __fsub_rn(1.0f, sc);
    float2 cn, sn;
    cn.x = __fadd_rn(__fmul_rn(x.x, sc), qc.x);
    cn.y = __fadd_rn(__fmul_rn(x.y, sc), qc.y);
    sn.x = __fadd_rn(__fmul_rn(x.x, omsc), qs.x);
    sn.y = __fadd_rn(__fmul_rn(x.y, omsc), qs.y);
    *(float2*)&out[OFF_CN + (size_t)node * DIM + 2 * lane] = cn;
    *(float2*)&out[OFF_SN + (size_t)node * DIM + 2 * lane] = sn;

    float hc1 = h_of(x.x, sc, 0), hc2 = h_of(x.y, sc, 0);
    float hs1 = h_of(x.x, sc, 1), hs2 = h_of(x.y, sc, 1);
    float d1 = qc.x - hc1, d2 = qc.y - hc2;
    float e1 = qs.x - hs1, e2 = qs.y - hs2;
    float lc = d1 * d1 + d2 * d2;
    float ls = e1 * e1 + e2 * e2;
    #pragma unroll
    for (int off = 32; off; off >>= 1) {
        lc += __shfl_down(lc, off, 64);
        ls += __shfl_down(ls, off, 64);
    }
    if (lane == 0) { redc[wave] = lc; reds[wave] = ls; }
    __syncthreads();
    if (threadIdx.x == 0) {
        double tc = (double)redc[0] + redc[1] + redc[2] + redc[3];
        double ts = (double)reds[0] + reds[1] + reds[2] + reds[3];
        atomicAdd(loss_acc, tc);
        atomicAdd(loss_acc + 1, ts);
    }
}

// ----------------------------------------------------------------- pool ----
__global__ __launch_bounds__(256) void pool_kernel(
    const int* __restrict__ starts, float* __restrict__ out)
{
    int g = blockIdx.x;
    int half = threadIdx.x >> 7, d = threadIdx.x & 127;
    int s = starts[g], e = starts[g + 1];
    const float* src = out + (half ? OFF_SN : OFF_CN);
    float sum = 0.0f;
    for (int n = s; n < e; ++n) sum = __fadd_rn(sum, src[(size_t)n * DIM + d]);
    float cnt = fmaxf((float)(e - s), 1.0f);
    out[(half ? OFF_SG : OFF_CG) + g * DIM + d] = __fdiv_rn(sum, cnt);
}

// ----------------------------------------------------------- classifier ----
__global__ __launch_bounds__(256) void classifier_kernel(
    const float* __restrict__ w1, const float* __restrict__ b1,
    const float* __restrict__ gamma, const float* __restrict__ beta,
    const float* __restrict__ rm, const float* __restrict__ rv,
    const float* __restrict__ w2, const float* __restrict__ b2,
    const double* __restrict__ loss_acc, float* __restrict__ out)
{
    __shared__ float row[DIM];
    __shared__ float red[4];
    int g = blockIdx.x, t = threadIdx.x;
    if (t < DIM) row[t] = out[OFF_CG + g * DIM + t];
    __syncthreads();
    float h = 0.0f;
    #pragma unroll 8
    for (int k = 0; k < DIM; ++k) h = fmaf(row[k], w1[k * 256 + t], h);
    h = __fadd_rn(h, b1[t]);
    float inv = __frsqrt_rn(__fadd_rn(rv[t], 1e-5f));
    h = __fadd_rn(__fmul_rn(__fmul_rn(__fsub_rn(h, rm[t]), inv), gamma[t]), beta[t]);
    h = fmaxf(h, 0.0f);
    float p = __fmul_rn(h, w2[t]);
    #pragma unroll
    for (int off = 32; off; off >>= 1) p += __shfl_down(p, off, 64);
    if ((t & 63) == 0) red[t >> 6] = p;
    __syncthreads();
    if (t == 0) {
        float total = __fadd_rn(__fadd_rn(red[0], red[1]), __fadd_rn(red[2], red[3]));
        out[OFF_LOGIT + g] = __fadd_rn(total, b2[0]);
        if (g == 0) {
            out[OFF_LC] = (float)(loss_acc[0] * (1.0 / 4194304.0));
            out[OFF_LS] = (float)(loss_acc[1] * (1.0 / 4194304.0));
        }
    }
}

extern "C" void kernel_launch(void* const* d_in, const int* in_sizes, int n_in,
                              void* d_out, int out_size, void* d_ws, size_t ws_size,
                              hipStream_t stream) {
    const float* node_feat = (const float*)d_in[0];
    const float* score     = (const float*)d_in[1];
    const int*   batch     = (const int*)d_in[2];
    const float* cb_c      = (const float*)d_in[3];
    const float* cb_s      = (const float*)d_in[4];
    const float* w1        = (const float*)d_in[5];
    const float* b1        = (const float*)d_in[6];
    const float* gamma     = (const float*)d_in[7];
    const float* beta      = (const float*)d_in[8];
    const float* rm        = (const float*)d_in[9];
    const float* rv        = (const float*)d_in[10];
    const float* w2        = (const float*)d_in[11];
    const float* b2        = (const float*)d_in[12];
    float* out = (float*)d_out;
    char*  ws  = (char*)d_ws;

    float*  cnorm    = (float*)(ws + WS_CNORM);
    int*    idx      = (int*)(ws + WS_IDX);
    double* loss_acc = (double*)(ws + WS_LOSS);
    int*    flagcnt  = (int*)(ws + WS_FLAGCNT);
    int*    starts   = (int*)(ws + WS_STARTS);
    int*    flaglist = (int*)(ws + WS_FLAGLIST);
    unsigned short* splits = (unsigned short*)d_out + SPLIT_U16;
    unsigned long long* slots = (unsigned long long*)(out + SLOT_F32);

    prep_kernel<<<2051, 256, 0, stream>>>(cb_c, cb_s, batch, cnorm, splits,
                                          starts, loss_acc, flagcnt);
    vq_main_kernel<<<dim3(256, 2), 256, 0, stream>>>(node_feat, score, splits, cnorm,
                                                     idx, flagcnt, flaglist, slots);
    vq_cleanup_kernel<<<dim3(512, 2), 256, 0, stream>>>(node_feat, score, cb_c, cb_s,
                                                        cnorm, flagcnt, flaglist, slots);
    flag_writeback_kernel<<<256, 256, 0, stream>>>(flagcnt, flaglist, slots, idx);
    gather_kernel<<<8192, 256, 0, stream>>>(node_feat, score, cb_c, cb_s, idx, out, loss_acc);
    pool_kernel<<<512, 256, 0, stream>>>(starts, out);
    classifier_kernel<<<512, 256, 0, stream>>>(w1, b1, gamma, beta, rm, rv, w2, b2,
                                               loss_acc, out);
}

// Round 4
// 384.271 us; speedup vs baseline: 3.6068x; 1.4741x over previous
//
#include <hip/hip_runtime.h>
#include <hip/hip_bf16.h>

#define NODES   32768
#define DIM     128
#define NCODES  4096
#define NGRAPHS 512

// output layout (flat f32, concatenated in reference return order)
#define OFF_LOGIT 0
#define OFF_CG    512
#define OFF_SG    66048
#define OFF_LC    131584
#define OFF_LS    131585
#define OFF_CN    131586
#define OFF_SN    4325890

// scratch regions inside d_out (overwritten by later kernels in stream order):
//   split planes: ushort idx 263680.. (4 planes x 1 MB)    [CN region; used pre-gather]
//   argmin slots: f32 idx 1180416..1311488 (u64[2][32768]) [CN region; used pre-gather]
//   loss partials: f32 idx 512..33280 (double[2][8192])    [CG region; gather->loss_reduce,
//                                                           then pool overwrites CG]
#define SPLIT_U16   263680
#define PLANE_U16   524288
#define SLOT_F32    1180416

// workspace layout (bytes)
#define WS_CNORM    0        // float[2][4096]        32768
#define WS_IDX      32768    // int[2][32768]         262144
#define WS_LOSS     294912   // double[2]             16 (unused now)
#define WS_FLAGCNT  294928   // int[2]                8
#define WS_STARTS   294936   // int[513]              2052
#define WS_FLAGLIST 296988   // int[2][32767]         262136
#define FLAG_CAP    32767

typedef __attribute__((ext_vector_type(8))) short bf16x8_t;
typedef __attribute__((ext_vector_type(4))) float f32x4_t;

__device__ __forceinline__ float h_of(float x, float sc, int cb) {
    float omsc = __fsub_rn(1.0f, sc);
    float half_x = __fmul_rn(0.5f, x);
    if (cb == 0)
        return __fadd_rn(__fmul_rn(x, sc), __fmul_rn(half_x, omsc));
    else
        return __fadd_rn(__fmul_rn(x, omsc), __fmul_rn(half_x, sc));
}

__device__ __forceinline__ unsigned short f2bf(float f) {
    __hip_bfloat16 b = __float2bfloat16(f);
    return *reinterpret_cast<unsigned short*>(&b);
}
__device__ __forceinline__ float bf2f(unsigned short u) {
    __hip_bfloat16 b = *reinterpret_cast<__hip_bfloat16*>(&u);
    return __bfloat162float(b);
}

__device__ __forceinline__ void gload_lds16(const void* g, void* l) {
    __builtin_amdgcn_global_load_lds(
        (const __attribute__((address_space(1))) int*)g,
        (__attribute__((address_space(3))) int*)l, 16, 0, 0);
}

// ---------------------------------------------------------------- prep ----
__global__ __launch_bounds__(256) void prep_kernel(
    const float* __restrict__ cb_c, const float* __restrict__ cb_s,
    const int* __restrict__ batch,
    float* __restrict__ cnorm, unsigned short* __restrict__ splits,
    int* __restrict__ starts, int* __restrict__ flagcnt)
{
    int gwave = (blockIdx.x * 256 + threadIdx.x) >> 6;
    int lane  = threadIdx.x & 63;

    if (gwave < 2 * NCODES) {                  // one wave per (cb,row)
        int cb = gwave >> 12, row = gwave & (NCODES - 1);
        const float* cp = (cb ? cb_s : cb_c) + (size_t)row * DIM;
        float2 v = ((const float2*)cp)[lane];  // elems 2l, 2l+1
        float p = __fadd_rn(__fmul_rn(v.x, v.x), __fmul_rn(v.y, v.y));
        #pragma unroll
        for (int off = 32; off; off >>= 1) p = __fadd_rn(p, __shfl_xor(p, off, 64));
        if (lane == 0) cnorm[cb * NCODES + row] = p;
        unsigned short h0 = f2bf(v.x), h1 = f2bf(v.y);
        unsigned short l0 = f2bf(__fsub_rn(v.x, bf2f(h0)));
        unsigned short l1 = f2bf(__fsub_rn(v.y, bf2f(h1)));
        unsigned int* hp = (unsigned int*)(splits + (size_t)(cb * 2 + 0) * PLANE_U16);
        unsigned int* lp = (unsigned int*)(splits + (size_t)(cb * 2 + 1) * PLANE_U16);
        hp[row * 64 + lane] = (unsigned int)h0 | ((unsigned int)h1 << 16);
        lp[row * 64 + lane] = (unsigned int)l0 | ((unsigned int)l1 << 16);
    } else {
        int w1 = gwave - 2 * NCODES;
        int g = w1 * 64 + lane;
        if (g <= NGRAPHS) {
            int lo = 0, hi = NODES;
            while (lo < hi) { int mid = (lo + hi) >> 1; if (batch[mid] < g) lo = mid + 1; else hi = mid; }
            starts[g] = lo;
        }
        if (w1 == 0 && lane < 2) flagcnt[lane] = 0;
    }
}

// ----------------------------------------------------------- vq main ----
__global__ __launch_bounds__(256, 2) void vq_main_kernel(
    const float* __restrict__ node_feat, const float* __restrict__ score,
    const unsigned short* __restrict__ splits, const float* __restrict__ cnorm,
    int* __restrict__ idx_ws, int* __restrict__ flagcnt, int* __restrict__ flaglist,
    unsigned long long* __restrict__ slots)
{
    __shared__ unsigned short lds[32768];   // 64 KB
    const int cb    = blockIdx.y;
    const int nbase = blockIdx.x * 128;
    const int tid = threadIdx.x;
    const int w   = tid >> 6;
    const int l15 = tid & 15;
    const int lg  = (tid & 63) >> 4;
    const int swz = (tid & 7) << 4;
    const float* cnp = cnorm + cb * NCODES;

    // init argmin slots for this block's nodes (consumed by cleanup's atomicMin)
    if (tid < 128) slots[(size_t)cb * NODES + nbase + tid] = ~0ull;

    // ---- stage A (h values, hi/lo bf16) into LDS ----
    #pragma unroll
    for (int i = 0; i < 16; ++i) {
        int idx = i * 1024 + tid * 4;
        int row = idx >> 7, k = idx & 127;
        float4 x = *(const float4*)&node_feat[(size_t)(nbase + row) * DIM + k];
        float sc = score[nbase + row];
        float h0 = h_of(x.x, sc, cb), h1 = h_of(x.y, sc, cb);
        float h2 = h_of(x.z, sc, cb), h3 = h_of(x.w, sc, cb);
        unsigned short u0 = f2bf(h0), u1 = f2bf(h1), u2 = f2bf(h2), u3 = f2bf(h3);
        unsigned short v0 = f2bf(__fsub_rn(h0, bf2f(u0))), v1 = f2bf(__fsub_rn(h1, bf2f(u1)));
        unsigned short v2 = f2bf(__fsub_rn(h2, bf2f(u2))), v3 = f2bf(__fsub_rn(h3, bf2f(u3)));
        int abyte = row * 256 + ((2 * k) ^ ((row & 7) << 4));
        uint2 hw; hw.x = (unsigned)u0 | ((unsigned)u1 << 16); hw.y = (unsigned)u2 | ((unsigned)u3 << 16);
        uint2 lw; lw.x = (unsigned)v0 | ((unsigned)v1 << 16); lw.y = (unsigned)v2 | ((unsigned)v3 << 16);
        *(uint2*)((char*)lds + abyte) = hw;
        *(uint2*)((char*)lds + 32768 + abyte) = lw;
    }
    __syncthreads();

    // ---- A fragments to registers ----
    bf16x8_t ahi[2][4], alo[2][4];
    int colbyte[4];
    #pragma unroll
    for (int ch = 0; ch < 4; ++ch) colbyte[ch] = (ch * 64 + lg * 16) ^ swz;
    #pragma unroll
    for (int rs = 0; rs < 2; ++rs)
        #pragma unroll
        for (int ch = 0; ch < 4; ++ch) {
            int row = 32 * w + 16 * rs + l15;
            int off = row * 256 + colbyte[ch];
            ahi[rs][ch] = *(const bf16x8_t*)((const char*)lds + off);
            alo[rs][ch] = *(const bf16x8_t*)((const char*)lds + 32768 + off);
        }
    __syncthreads();   // all A reads done -> LDS reusable as B double-buffer

    // ---- B staging setup (pre-swizzled global source, linear LDS dest) ----
    const unsigned short* wplane = splits + (size_t)(cb * 2 + (w >> 1)) * PLANE_U16;
    int soff[8];
    #pragma unroll
    for (int i = 0; i < 8; ++i) {
        int row = ((w & 1) << 5) + i * 4 + lg;
        soff[i] = row * 256 + ((l15 * 16) ^ ((row & 7) << 4));
    }

    {
        const char* tb = (const char*)wplane;
        #pragma unroll
        for (int i = 0; i < 8; ++i)
            gload_lds16(tb + soff[i], (char*)lds + w * 8192 + i * 1024);
    }
    float cnc[4], cnn[4];
    #pragma unroll
    for (int cs = 0; cs < 4; ++cs) cnc[cs] = cnp[cs * 16 + l15];
    __syncthreads();   // drains vmcnt -> tile0 ready

    const float NEG_INF = -3.4e38f;
    float b1v[2][4], b2v[2][4]; int b1i[2][4];
    #pragma unroll
    for (int rs = 0; rs < 2; ++rs)
        #pragma unroll
        for (int r = 0; r < 4; ++r) { b1v[rs][r] = NEG_INF; b2v[rs][r] = NEG_INF; b1i[rs][r] = 0; }

    for (int t = 0; t < 64; ++t) {
        int bs_cur = (t & 1) << 15;
        if (t < 63) {
            int bs_nxt = ((t + 1) & 1) << 15;
            const char* tb = (const char*)wplane + (t + 1) * 16384;
            #pragma unroll
            for (int i = 0; i < 8; ++i)
                gload_lds16(tb + soff[i], (char*)lds + bs_nxt + w * 8192 + i * 1024);
            #pragma unroll
            for (int cs = 0; cs < 4; ++cs) cnn[cs] = cnp[(t + 1) * 64 + cs * 16 + l15];
        }

        f32x4_t acc[2][4];
        #pragma unroll
        for (int cs = 0; cs < 4; ++cs) {
            float iv = -0.5f * cnc[cs];
            f32x4_t ini = {iv, iv, iv, iv};
            acc[0][cs] = ini; acc[1][cs] = ini;
        }

        #pragma unroll
        for (int ch = 0; ch < 4; ++ch) {
            #pragma unroll
            for (int cs = 0; cs < 4; ++cs) {
                const char* bp = (const char*)lds + bs_cur + (cs * 16 + l15) * 256 + colbyte[ch];
                bf16x8_t bhi = *(const bf16x8_t*)bp;
                bf16x8_t blo = *(const bf16x8_t*)(bp + 16384);
                #pragma unroll
                for (int rs = 0; rs < 2; ++rs) {
                    acc[rs][cs] = __builtin_amdgcn_mfma_f32_16x16x32_bf16(ahi[rs][ch], bhi, acc[rs][cs], 0, 0, 0);
                    acc[rs][cs] = __builtin_amdgcn_mfma_f32_16x16x32_bf16(alo[rs][ch], bhi, acc[rs][cs], 0, 0, 0);
                    acc[rs][cs] = __builtin_amdgcn_mfma_f32_16x16x32_bf16(ahi[rs][ch], blo, acc[rs][cs], 0, 0, 0);
                }
            }
        }

        #pragma unroll
        for (int cs = 0; cs < 4; ++cs) {
            int code = t * 64 + cs * 16 + l15;
            #pragma unroll
            for (int rs = 0; rs < 2; ++rs)
                #pragma unroll
                for (int r = 0; r < 4; ++r) {
                    float a = acc[rs][cs][r];
                    bool gt = a > b1v[rs][r];
                    float nb2 = __builtin_amdgcn_fmed3f(a, b1v[rs][r], b2v[rs][r]);
                    if (gt) b1i[rs][r] = code;
                    b1v[rs][r] = fmaxf(a, b1v[rs][r]);
                    b2v[rs][r] = nb2;
                }
        }
        #pragma unroll
        for (int cs = 0; cs < 4; ++cs) cnc[cs] = cnn[cs];
        __syncthreads();
    }

    #pragma unroll
    for (int off = 1; off < 16; off <<= 1) {
        #pragma unroll
        for (int rs = 0; rs < 2; ++rs)
            #pragma unroll
            for (int r = 0; r < 4; ++r) {
                float ov1 = __shfl_xor(b1v[rs][r], off, 64);
                int   oi  = __shfl_xor(b1i[rs][r], off, 64);
                float ov2 = __shfl_xor(b2v[rs][r], off, 64);
                bool take = (ov1 > b1v[rs][r]) || (ov1 == b1v[rs][r] && oi < b1i[rs][r]);
                float loser = fminf(ov1, b1v[rs][r]);
                b1v[rs][r] = fmaxf(ov1, b1v[rs][r]);
                if (take) b1i[rs][r] = oi;
                b2v[rs][r] = fmaxf(loser, fmaxf(ov2, b2v[rs][r]));
            }
    }
    if (l15 == 0) {
        #pragma unroll
        for (int rs = 0; rs < 2; ++rs)
            #pragma unroll
            for (int r = 0; r < 4; ++r) {
                int node = nbase + 32 * w + 16 * rs + 4 * lg + r;
                idx_ws[cb * NODES + node] = b1i[rs][r];
                if (b1v[rs][r] - b2v[rs][r] < 0.04f) {     // d-space gap < 0.08
                    int p = atomicAdd(flagcnt + cb, 1);
                    if (p < FLAG_CAP) flaglist[cb * FLAG_CAP + p] = node;
                }
            }
    }
}

// --------------------------------------------------------- vq cleanup ----
__global__ __launch_bounds__(256) void vq_cleanup_kernel(
    const float* __restrict__ node_feat, const float* __restrict__ score,
    const float* __restrict__ cb_c, const float* __restrict__ cb_s,
    const float* __restrict__ cnorm, const int* __restrict__ flagcnt,
    const int* __restrict__ flaglist, unsigned long long* __restrict__ slots)
{
    __shared__ float cbT[128][65];
    __shared__ float hbuf[4][128];
    const int cb  = blockIdx.y;
    const int seg = blockIdx.x & 63;    // 64-code segment
    const int ng  = blockIdx.x >> 6;    // node-group 0..7
    const float* cbp = cb ? cb_s : cb_c;
    const int* list = flaglist + cb * FLAG_CAP;
    int cnt = flagcnt[cb]; if (cnt > FLAG_CAP) cnt = FLAG_CAP;
    const int tid = threadIdx.x, w = tid >> 6, l = tid & 63;

    {   // stage this segment's 64 codes transposed, once
        int c = tid >> 2, ks = (tid & 3) * 32;
        const float* src = cbp + (size_t)(seg * 64 + c) * DIM + ks;
        #pragma unroll
        for (int j = 0; j < 8; ++j) {
            float4 v = *(const float4*)(src + j * 4);
            cbT[ks + j * 4 + 0][c] = v.x;
            cbT[ks + j * 4 + 1][c] = v.y;
            cbT[ks + j * 4 + 2][c] = v.z;
            cbT[ks + j * 4 + 3][c] = v.w;
        }
    }
    const int mycode = seg * 64 + l;
    const float cn = cnorm[cb * NCODES + mycode];
    __syncthreads();

    for (int base = ng * 4; base < cnt; base += 32) {
        int e = base + w;
        bool valid = e < cnt;
        int node = list[valid ? e : 0];
        float sc = score[node];
        float x0 = node_feat[(size_t)node * DIM + l];
        float x1 = node_feat[(size_t)node * DIM + 64 + l];
        float h0 = h_of(x0, sc, cb), h1 = h_of(x1, sc, cb);
        hbuf[w][l] = h0; hbuf[w][64 + l] = h1;
        float sxx = __fadd_rn(__fmul_rn(h0, h0), __fmul_rn(h1, h1));
        #pragma unroll
        for (int off = 32; off; off >>= 1) sxx = __fadd_rn(sxx, __shfl_xor(sxx, off, 64));
        asm volatile("s_waitcnt lgkmcnt(0)" ::: "memory");

        float p0 = 0.f, p1 = 0.f, p2 = 0.f, p3 = 0.f;
        #pragma unroll 8
        for (int m = 0; m < 32; ++m) {
            p0 = fmaf(hbuf[w][4 * m + 0], cbT[4 * m + 0][l], p0);
            p1 = fmaf(hbuf[w][4 * m + 1], cbT[4 * m + 1][l], p1);
            p2 = fmaf(hbuf[w][4 * m + 2], cbT[4 * m + 2][l], p2);
            p3 = fmaf(hbuf[w][4 * m + 3], cbT[4 * m + 3][l], p3);
        }
        float dot = __fadd_rn(__fadd_rn(p0, p1), __fadd_rn(p2, p3));
        float d2 = __fadd_rn(__fsub_rn(sxx, __fmul_rn(2.0f, dot)), cn);

        unsigned b = __float_as_uint(d2);
        unsigned key = (b & 0x80000000u) ? ~b : (b | 0x80000000u);
        unsigned long long pk = ((unsigned long long)key << 32) | (unsigned)mycode;
        #pragma unroll
        for (int off = 1; off < 64; off <<= 1) {
            unsigned long long o = __shfl_xor(pk, off, 64);
            pk = (o < pk) ? o : pk;
        }
        if (valid && l == 0)
            atomicMin(&slots[(size_t)cb * NODES + node], pk);
        asm volatile("s_waitcnt lgkmcnt(0)" ::: "memory");
    }
}

// ------------------------------------------------------- flag writeback ----
__global__ __launch_bounds__(256) void flag_writeback_kernel(
    const int* __restrict__ flagcnt, const int* __restrict__ flaglist,
    const unsigned long long* __restrict__ slots, int* __restrict__ idx_ws)
{
    int gt = blockIdx.x * 256 + threadIdx.x;
    int c0 = flagcnt[0]; if (c0 > FLAG_CAP) c0 = FLAG_CAP;
    int c1 = flagcnt[1]; if (c1 > FLAG_CAP) c1 = FLAG_CAP;
    for (int e = gt; e < 2 * FLAG_CAP; e += 256 * 256) {
        int cb = (e >= FLAG_CAP) ? 1 : 0;
        int i = e - cb * FLAG_CAP;
        int cnt = cb ? c1 : c0;
        if (i < cnt) {
            int node = flaglist[cb * FLAG_CAP + i];
            idx_ws[cb * NODES + node] =
                (int)(slots[(size_t)cb * NODES + node] & 0xFFFFFFFFull);
        }
    }
}

// --------------------------------------------------------------- gather ----
// per-block loss partials (no atomics): partials[blk] = loss_c, [8192+blk] = loss_s
__global__ __launch_bounds__(256) void gather_kernel(
    const float* __restrict__ node_feat, const float* __restrict__ score,
    const float* __restrict__ cb_c, const float* __restrict__ cb_s,
    const int* __restrict__ idx_all, float* __restrict__ out,
    double* __restrict__ partials)
{
    __shared__ float redc[4], reds[4];
    int wave = threadIdx.x >> 6, lane = threadIdx.x & 63;
    int node = blockIdx.x * 4 + wave;
    float sc = score[node];
    float2 x  = *(const float2*)&node_feat[(size_t)node * DIM + 2 * lane];
    int ic = idx_all[node], is_ = idx_all[NODES + node];
    float2 qc = *(const float2*)&cb_c[(size_t)ic * DIM + 2 * lane];
    float2 qs = *(const float2*)&cb_s[(size_t)is_ * DIM + 2 * lane];

    float omsc = __fsub_rn(1.0f, sc);
    float2 cn, sn;
    cn.x = __fadd_rn(__fmul_rn(x.x, sc), qc.x);
    cn.y = __fadd_rn(__fmul_rn(x.y, sc), qc.y);
    sn.x = __fadd_rn(__fmul_rn(x.x, omsc), qs.x);
    sn.y = __fadd_rn(__fmul_rn(x.y, omsc), qs.y);
    *(float2*)&out[OFF_CN + (size_t)node * DIM + 2 * lane] = cn;
    *(float2*)&out[OFF_SN + (size_t)node * DIM + 2 * lane] = sn;

    float hc1 = h_of(x.x, sc, 0), hc2 = h_of(x.y, sc, 0);
    float hs1 = h_of(x.x, sc, 1), hs2 = h_of(x.y, sc, 1);
    float d1 = qc.x - hc1, d2 = qc.y - hc2;
    float e1 = qs.x - hs1, e2 = qs.y - hs2;
    float lc = d1 * d1 + d2 * d2;
    float ls = e1 * e1 + e2 * e2;
    #pragma unroll
    for (int off = 32; off; off >>= 1) {
        lc += __shfl_down(lc, off, 64);
        ls += __shfl_down(ls, off, 64);
    }
    if (lane == 0) { redc[wave] = lc; reds[wave] = ls; }
    __syncthreads();
    if (threadIdx.x == 0) {
        double tc = (double)redc[0] + redc[1] + redc[2] + redc[3];
        double ts = (double)reds[0] + reds[1] + reds[2] + reds[3];
        partials[blockIdx.x] = tc;
        partials[8192 + blockIdx.x] = ts;
    }
}

// ---------------------------------------------------------- loss reduce ----
// block b sums partials[b*8192 .. +8192) and writes out[OFF_LC + b]
__global__ __launch_bounds__(256) void loss_reduce_kernel(
    const double* __restrict__ partials, float* __restrict__ out)
{
    __shared__ double red[4];
    int b = blockIdx.x, t = threadIdx.x, w = t >> 6, l = t & 63;
    const double* p = partials + b * 8192;
    double s = 0.0;
    #pragma unroll 4
    for (int i = t; i < 8192; i += 256) s += p[i];
    #pragma unroll
    for (int off = 32; off; off >>= 1) s += __shfl_down(s, off, 64);
    if (l == 0) red[w] = s;
    __syncthreads();
    if (t == 0) {
        double tot = (red[0] + red[1]) + (red[2] + red[3]);
        out[OFF_LC + b] = (float)(tot * (1.0 / 4194304.0));   // / 2^22 exact
    }
}

// ----------------------------------------------------------------- pool ----
__global__ __launch_bounds__(256) void pool_kernel(
    const int* __restrict__ starts, float* __restrict__ out)
{
    int g = blockIdx.x;
    int half = threadIdx.x >> 7, d = threadIdx.x & 127;
    int s = starts[g], e = starts[g + 1];
    const float* src = out + (half ? OFF_SN : OFF_CN);
    float sum = 0.0f;
    for (int n = s; n < e; ++n) sum = __fadd_rn(sum, src[(size_t)n * DIM + d]);
    float cnt = fmaxf((float)(e - s), 1.0f);
    out[(half ? OFF_SG : OFF_CG) + g * DIM + d] = __fdiv_rn(sum, cnt);
}

// ----------------------------------------------------------- classifier ----
__global__ __launch_bounds__(256) void classifier_kernel(
    const float* __restrict__ w1, const float* __restrict__ b1,
    const float* __restrict__ gamma, const float* __restrict__ beta,
    const float* __restrict__ rm, const float* __restrict__ rv,
    const float* __restrict__ w2, const float* __restrict__ b2,
    float* __restrict__ out)
{
    __shared__ float row[DIM];
    __shared__ float red[4];
    int g = blockIdx.x, t = threadIdx.x;
    if (t < DIM) row[t] = out[OFF_CG + g * DIM + t];
    __syncthreads();
    float h = 0.0f;
    #pragma unroll 8
    for (int k = 0; k < DIM; ++k) h = fmaf(row[k], w1[k * 256 + t], h);
    h = __fadd_rn(h, b1[t]);
    float inv = __frsqrt_rn(__fadd_rn(rv[t], 1e-5f));
    h = __fadd_rn(__fmul_rn(__fmul_rn(__fsub_rn(h, rm[t]), inv), gamma[t]), beta[t]);
    h = fmaxf(h, 0.0f);
    float p = __fmul_rn(h, w2[t]);
    #pragma unroll
    for (int off = 32; off; off >>= 1) p += __shfl_down(p, off, 64);
    if ((t & 63) == 0) red[t >> 6] = p;
    __syncthreads();
    if (t == 0) {
        float total = __fadd_rn(__fadd_rn(red[0], red[1]), __fadd_rn(red[2], red[3]));
        out[OFF_LOGIT + g] = __fadd_rn(total, b2[0]);
    }
}

extern "C" void kernel_launch(void* const* d_in, const int* in_sizes, int n_in,
                              void* d_out, int out_size, void* d_ws, size_t ws_size,
                              hipStream_t stream) {
    const float* node_feat = (const float*)d_in[0];
    const float* score     = (const float*)d_in[1];
    const int*   batch     = (const int*)d_in[2];
    const float* cb_c      = (const float*)d_in[3];
    const float* cb_s      = (const float*)d_in[4];
    const float* w1        = (const float*)d_in[5];
    const float* b1        = (const float*)d_in[6];
    const float* gamma     = (const float*)d_in[7];
    const float* beta      = (const float*)d_in[8];
    const float* rm        = (const float*)d_in[9];
    const float* rv        = (const float*)d_in[10];
    const float* w2        = (const float*)d_in[11];
    const float* b2        = (const float*)d_in[12];
    float* out = (float*)d_out;
    char*  ws  = (char*)d_ws;

    float*  cnorm    = (float*)(ws + WS_CNORM);
    int*    idx      = (int*)(ws + WS_IDX);
    int*    flagcnt  = (int*)(ws + WS_FLAGCNT);
    int*    starts   = (int*)(ws + WS_STARTS);
    int*    flaglist = (int*)(ws + WS_FLAGLIST);
    unsigned short* splits = (unsigned short*)d_out + SPLIT_U16;
    unsigned long long* slots = (unsigned long long*)(out + SLOT_F32);
    double* partials = (double*)(out + OFF_CG);   // CG region scratch, pre-pool

    prep_kernel<<<2051, 256, 0, stream>>>(cb_c, cb_s, batch, cnorm, splits,
                                          starts, flagcnt);
    vq_main_kernel<<<dim3(256, 2), 256, 0, stream>>>(node_feat, score, splits, cnorm,
                                                     idx, flagcnt, flaglist, slots);
    vq_cleanup_kernel<<<dim3(512, 2), 256, 0, stream>>>(node_feat, score, cb_c, cb_s,
                                                        cnorm, flagcnt, flaglist, slots);
    flag_writeback_kernel<<<256, 256, 0, stream>>>(flagcnt, flaglist, slots, idx);
    gather_kernel<<<8192, 256, 0, stream>>>(node_feat, score, cb_c, cb_s, idx, out, partials);
    loss_reduce_kernel<<<2, 256, 0, stream>>>(partials, out);
    pool_kernel<<<512, 256, 0, stream>>>(starts, out);
    classifier_kernel<<<512, 256, 0, stream>>>(w1, b1, gamma, beta, rm, rv, w2, b2, out);
}

// Round 5
// 350.348 us; speedup vs baseline: 3.9560x; 1.0968x over previous
//
#include <hip/hip_runtime.h>
#include <hip/hip_bf16.h>

#define NODES   32768
#define DIM     128
#define NCODES  4096
#define NGRAPHS 512
#define THR     0.0625f

// output layout (flat f32, concatenated in reference return order)
#define OFF_LOGIT 0
#define OFF_CG    512
#define OFF_SG    66048
#define OFF_LC    131584
#define OFF_LS    131585
#define OFF_CN    131586
#define OFF_SN    4325890

// scratch inside d_out (all rewritten by gather/pool later, in stream order):
//   fp16 codebook planes: u16 idx 263680.. (2 x 1 MB)       [CN region]
//   half-results:  f32 idx 1180416.. u64[2][2][32768] 1 MB  [CN region]
//   cleanup slots: f32 idx 1442560.. u64[2][32768] 512 KB   [CN region]
//   loss partials: f32 idx 512..  double[2][8192]           [CG region]
#define SPLIT_U16   263680
#define PLANE_U16   524288
#define HALF_F32    1180416
#define CSLOT_F32   1442560

// workspace layout (bytes)
#define WS_CNORM    0        // float[2][4096]
#define WS_IDX      32768    // int[2][32768]
#define WS_FLAGCNT  294928   // int[2]
#define WS_STARTS   294936   // int[513]
#define WS_FLAGLIST 296988   // int[2][32767]
#define FLAG_CAP    32767

typedef __attribute__((ext_vector_type(8))) _Float16 f16x8_t;
typedef __attribute__((ext_vector_type(4))) float f32x4_t;

__device__ __forceinline__ float h_of(float x, float sc, int cb) {
    float omsc = __fsub_rn(1.0f, sc);
    float half_x = __fmul_rn(0.5f, x);
    if (cb == 0)
        return __fadd_rn(__fmul_rn(x, sc), __fmul_rn(half_x, omsc));
    else
        return __fadd_rn(__fmul_rn(x, omsc), __fmul_rn(half_x, sc));
}

__device__ __forceinline__ unsigned short f2h(float f) {
    return __builtin_bit_cast(unsigned short, (_Float16)f);
}

__device__ __forceinline__ void gload_lds16(const void* g, void* l) {
    __builtin_amdgcn_global_load_lds(
        (const __attribute__((address_space(1))) int*)g,
        (__attribute__((address_space(3))) int*)l, 16, 0, 0);
}

__device__ __forceinline__ unsigned sortkey(float f) {
    unsigned b = __float_as_uint(f);
    return (b & 0x80000000u) ? ~b : (b | 0x80000000u);
}
__device__ __forceinline__ float keyinv(unsigned k) {
    unsigned b = (k & 0x80000000u) ? (k & 0x7FFFFFFFu) : ~k;
    return __uint_as_float(b);
}

// ---------------------------------------------------------------- prep ----
// cnorm + fp16 codebook plane + graph boundaries + zero flag counters
__global__ __launch_bounds__(256) void prep_kernel(
    const float* __restrict__ cb_c, const float* __restrict__ cb_s,
    const int* __restrict__ batch,
    float* __restrict__ cnorm, unsigned short* __restrict__ splits,
    int* __restrict__ starts, int* __restrict__ flagcnt)
{
    int gwave = (blockIdx.x * 256 + threadIdx.x) >> 6;
    int lane  = threadIdx.x & 63;

    if (gwave < 2 * NCODES) {                  // one wave per (cb,row)
        int cb = gwave >> 12, row = gwave & (NCODES - 1);
        const float* cp = (cb ? cb_s : cb_c) + (size_t)row * DIM;
        float2 v = ((const float2*)cp)[lane];  // elems 2l, 2l+1
        float p = __fadd_rn(__fmul_rn(v.x, v.x), __fmul_rn(v.y, v.y));
        #pragma unroll
        for (int off = 32; off; off >>= 1) p = __fadd_rn(p, __shfl_xor(p, off, 64));
        if (lane == 0) cnorm[cb * NCODES + row] = p;
        unsigned int* hp = (unsigned int*)(splits + (size_t)cb * PLANE_U16);
        hp[row * 64 + lane] = (unsigned)f2h(v.x) | ((unsigned)f2h(v.y) << 16);
    } else {
        int w1 = gwave - 2 * NCODES;
        int g = w1 * 64 + lane;
        if (g <= NGRAPHS) {
            int lo = 0, hi = NODES;
            while (lo < hi) { int mid = (lo + hi) >> 1; if (batch[mid] < g) lo = mid + 1; else hi = mid; }
            starts[g] = lo;
        }
        if (w1 == 0 && lane < 2) flagcnt[lane] = 0;
    }
}

// ----------------------------------------------------------- vq main ----
// 128 nodes x 2048 codes per block (code-half split), fp16 single-plane.
// 4 waves x 32 nodes; 32 t-iters of 64 codes, double-buffered gll staging.
__global__ __launch_bounds__(256, 4) void vq_main_kernel(
    const float* __restrict__ node_feat, const float* __restrict__ score,
    const unsigned short* __restrict__ splits, const float* __restrict__ cnorm,
    unsigned long long* __restrict__ halfres)
{
    __shared__ unsigned short lds[16384];   // 32 KB
    const int nb    = blockIdx.x & 255;
    const int half  = blockIdx.x >> 8;
    const int cb    = blockIdx.y;
    const int nbase = nb * 128;
    const int tid = threadIdx.x;
    const int w   = tid >> 6;
    const int l15 = tid & 15;
    const int lg  = (tid & 63) >> 4;
    const int swz = (tid & 7) << 4;
    const float* cnp = cnorm + cb * NCODES + half * 2048;

    // ---- stage A (h values, fp16) into LDS, swizzled ----
    #pragma unroll
    for (int i = 0; i < 16; ++i) {
        int idx = i * 1024 + tid * 4;
        int row = idx >> 7, k = idx & 127;
        float4 x = *(const float4*)&node_feat[(size_t)(nbase + row) * DIM + k];
        float sc = score[nbase + row];
        unsigned u0 = f2h(h_of(x.x, sc, cb)), u1 = f2h(h_of(x.y, sc, cb));
        unsigned u2 = f2h(h_of(x.z, sc, cb)), u3 = f2h(h_of(x.w, sc, cb));
        int abyte = row * 256 + ((2 * k) ^ ((row & 7) << 4));
        uint2 hw; hw.x = u0 | (u1 << 16); hw.y = u2 | (u3 << 16);
        *(uint2*)((char*)lds + abyte) = hw;
    }
    __syncthreads();

    // ---- A fragments to registers ----
    f16x8_t ahi[2][4];
    int colbyte[4];
    #pragma unroll
    for (int ch = 0; ch < 4; ++ch) colbyte[ch] = (ch * 64 + lg * 16) ^ swz;
    #pragma unroll
    for (int rs = 0; rs < 2; ++rs)
        #pragma unroll
        for (int ch = 0; ch < 4; ++ch) {
            int row = 32 * w + 16 * rs + l15;
            ahi[rs][ch] = *(const f16x8_t*)((const char*)lds + row * 256 + colbyte[ch]);
        }
    __syncthreads();   // A reads done -> LDS reused as B double-buffer (2 x 16KB)

    // ---- B staging setup (pre-swizzled global source, linear LDS dest) ----
    const unsigned short* wplane = splits + (size_t)cb * PLANE_U16 + half * 262144;
    int soff[4];
    #pragma unroll
    for (int i = 0; i < 4; ++i) {
        int row = w * 16 + i * 4 + lg;
        soff[i] = row * 256 + ((l15 * 16) ^ ((row & 7) << 4));
    }

    {   // tile 0 -> buf0
        const char* tb = (const char*)wplane;
        #pragma unroll
        for (int i = 0; i < 4; ++i)
            gload_lds16(tb + soff[i], (char*)lds + w * 4096 + i * 1024);
    }
    __syncthreads();   // drains vmcnt -> tile0 ready

    const float NEG_INF = -3.4e38f;
    float b1v[2][4], b2v[2][4]; int b1i[2][4];
    #pragma unroll
    for (int rs = 0; rs < 2; ++rs)
        #pragma unroll
        for (int r = 0; r < 4; ++r) { b1v[rs][r] = NEG_INF; b2v[rs][r] = NEG_INF; b1i[rs][r] = 0; }

    for (int t = 0; t < 32; ++t) {
        int bs_cur = (t & 1) << 14;   // byte offset of current 16KB buffer
        float cnc[4];
        #pragma unroll
        for (int cs = 0; cs < 4; ++cs) cnc[cs] = cnp[t * 64 + cs * 16 + l15];
        if (t < 31) {
            int bs_nxt = ((t + 1) & 1) << 14;
            const char* tb = (const char*)wplane + (t + 1) * 16384;
            #pragma unroll
            for (int i = 0; i < 4; ++i)
                gload_lds16(tb + soff[i], (char*)lds + bs_nxt + w * 4096 + i * 1024);
        }

        #pragma unroll
        for (int cp = 0; cp < 2; ++cp) {        // cs pairs: keeps acc live-range small
            f32x4_t acc[2][2];
            #pragma unroll
            for (int rs = 0; rs < 2; ++rs)
                #pragma unroll
                for (int c2 = 0; c2 < 2; ++c2) acc[rs][c2] = (f32x4_t){0.f, 0.f, 0.f, 0.f};

            #pragma unroll
            for (int ch = 0; ch < 4; ++ch)
                #pragma unroll
                for (int c2 = 0; c2 < 2; ++c2) {
                    int cs = cp * 2 + c2;
                    f16x8_t bh = *(const f16x8_t*)((const char*)lds + bs_cur +
                                                   (cs * 16 + l15) * 256 + colbyte[ch]);
                    acc[0][c2] = __builtin_amdgcn_mfma_f32_16x16x32_f16(ahi[0][ch], bh, acc[0][c2], 0, 0, 0);
                    acc[1][c2] = __builtin_amdgcn_mfma_f32_16x16x32_f16(ahi[1][ch], bh, acc[1][c2], 0, 0, 0);
                }

            #pragma unroll
            for (int c2 = 0; c2 < 2; ++c2) {
                int cs = cp * 2 + c2;
                int code = half * 2048 + t * 64 + cs * 16 + l15;
                #pragma unroll
                for (int rs = 0; rs < 2; ++rs)
                    #pragma unroll
                    for (int r = 0; r < 4; ++r) {
                        float a = __fmaf_rn(-0.5f, cnc[cs], acc[rs][c2][r]);
                        bool gt = a > b1v[rs][r];
                        float nb2 = __builtin_amdgcn_fmed3f(a, b1v[rs][r], b2v[rs][r]);
                        if (gt) b1i[rs][r] = code;
                        b1v[rs][r] = fmaxf(a, b1v[rs][r]);
                        b2v[rs][r] = nb2;
                    }
            }
        }
        __syncthreads();   // drains gll vmcnt; protects buffer swap
    }

    // cross-lane merge over the 16 code-columns (lane bits 0..3)
    #pragma unroll
    for (int off = 1; off < 16; off <<= 1) {
        #pragma unroll
        for (int rs = 0; rs < 2; ++rs)
            #pragma unroll
            for (int r = 0; r < 4; ++r) {
                float ov1 = __shfl_xor(b1v[rs][r], off, 64);
                int   oi  = __shfl_xor(b1i[rs][r], off, 64);
                float ov2 = __shfl_xor(b2v[rs][r], off, 64);
                bool take = (ov1 > b1v[rs][r]) || (ov1 == b1v[rs][r] && oi < b1i[rs][r]);
                float loser = fminf(ov1, b1v[rs][r]);
                b1v[rs][r] = fmaxf(ov1, b1v[rs][r]);
                if (take) b1i[rs][r] = oi;
                b2v[rs][r] = fmaxf(loser, fmaxf(ov2, b2v[rs][r]));
            }
    }
    if (l15 == 0) {
        #pragma unroll
        for (int rs = 0; rs < 2; ++rs)
            #pragma unroll
            for (int r = 0; r < 4; ++r) {
                int node = nbase + 32 * w + 16 * rs + 4 * lg + r;
                unsigned key = sortkey(b1v[rs][r]);
                unsigned pay = (unsigned)b1i[rs][r] |
                               ((b1v[rs][r] - b2v[rs][r] < THR) ? 0x1000u : 0u);
                halfres[((size_t)(cb * 2 + half)) * NODES + node] =
                    ((unsigned long long)key << 32) | pay;
            }
    }
}

// -------------------------------------------------------------- resolve ----
// merge the two code-half results; wave-aggregated flaglist append
__global__ __launch_bounds__(256) void resolve_kernel(
    const unsigned long long* __restrict__ hr, unsigned long long* __restrict__ cslot,
    int* __restrict__ idx_ws, int* __restrict__ flagcnt, int* __restrict__ flaglist)
{
    int cb = blockIdx.y;
    int node = blockIdx.x * 256 + threadIdx.x;
    unsigned long long A = hr[((size_t)(cb * 2 + 0)) * NODES + node];
    unsigned long long B = hr[((size_t)(cb * 2 + 1)) * NODES + node];
    unsigned ka = (unsigned)(A >> 32), kb = (unsigned)(B >> 32);
    bool awin = ka >= kb;
    unsigned long long W = awin ? A : B;
    float aw = keyinv(awin ? ka : kb);
    float al = keyinv(awin ? kb : ka);
    bool flag = ((W >> 12) & 1ull) || (__fsub_rn(aw, al) < THR);
    idx_ws[cb * NODES + node] = (int)(W & 0xFFFu);
    if (flag) cslot[(size_t)cb * NODES + node] = ~0ull;

    unsigned long long mask = __ballot(flag);
    if (mask) {
        int lane = threadIdx.x & 63;
        int leader = __ffsll((long long)mask) - 1;
        int base = 0;
        if (lane == leader) base = atomicAdd(flagcnt + cb, (int)__popcll(mask));
        base = __shfl(base, leader, 64);
        if (flag) {
            int pos = base + (int)__popcll(mask & ((1ull << lane) - 1ull));
            if (pos < FLAG_CAP) flaglist[cb * FLAG_CAP + pos] = node;
        }
    }
}

// --------------------------------------------------------- vq cleanup ----
// exact fp32 rescore of flagged nodes; atomicMin merge on packed u64
__global__ __launch_bounds__(256) void vq_cleanup_kernel(
    const float* __restrict__ node_feat, const float* __restrict__ score,
    const float* __restrict__ cb_c, const float* __restrict__ cb_s,
    const float* __restrict__ cnorm, const int* __restrict__ flagcnt,
    const int* __restrict__ flaglist, unsigned long long* __restrict__ slots)
{
    __shared__ float cbT[128][65];
    __shared__ float hbuf[4][128];
    const int cb  = blockIdx.y;
    const int seg = blockIdx.x & 63;    // 64-code segment
    const int ng  = blockIdx.x >> 6;    // node-group 0..15
    const float* cbp = cb ? cb_s : cb_c;
    const int* list = flaglist + cb * FLAG_CAP;
    int cnt = flagcnt[cb]; if (cnt > FLAG_CAP) cnt = FLAG_CAP;
    const int tid = threadIdx.x, w = tid >> 6, l = tid & 63;

    {   // stage this segment's 64 codes transposed, once
        int c = tid >> 2, ks = (tid & 3) * 32;
        const float* src = cbp + (size_t)(seg * 64 + c) * DIM + ks;
        #pragma unroll
        for (int j = 0; j < 8; ++j) {
            float4 v = *(const float4*)(src + j * 4);
            cbT[ks + j * 4 + 0][c] = v.x;
            cbT[ks + j * 4 + 1][c] = v.y;
            cbT[ks + j * 4 + 2][c] = v.z;
            cbT[ks + j * 4 + 3][c] = v.w;
        }
    }
    const int mycode = seg * 64 + l;
    const float cn = cnorm[cb * NCODES + mycode];
    __syncthreads();

    for (int base = ng * 4; base < cnt; base += 64) {
        int e = base + w;
        bool valid = e < cnt;
        int node = list[valid ? e : 0];
        float sc = score[node];
        float x0 = node_feat[(size_t)node * DIM + l];
        float x1 = node_feat[(size_t)node * DIM + 64 + l];
        float h0 = h_of(x0, sc, cb), h1 = h_of(x1, sc, cb);
        hbuf[w][l] = h0; hbuf[w][64 + l] = h1;
        float sxx = __fadd_rn(__fmul_rn(h0, h0), __fmul_rn(h1, h1));
        #pragma unroll
        for (int off = 32; off; off >>= 1) sxx = __fadd_rn(sxx, __shfl_xor(sxx, off, 64));
        asm volatile("s_waitcnt lgkmcnt(0)" ::: "memory");

        float p0 = 0.f, p1 = 0.f, p2 = 0.f, p3 = 0.f;
        #pragma unroll 8
        for (int m = 0; m < 32; ++m) {
            p0 = fmaf(hbuf[w][4 * m + 0], cbT[4 * m + 0][l], p0);
            p1 = fmaf(hbuf[w][4 * m + 1], cbT[4 * m + 1][l], p1);
            p2 = fmaf(hbuf[w][4 * m + 2], cbT[4 * m + 2][l], p2);
            p3 = fmaf(hbuf[w][4 * m + 3], cbT[4 * m + 3][l], p3);
        }
        float dot = __fadd_rn(__fadd_rn(p0, p1), __fadd_rn(p2, p3));
        float d2 = __fadd_rn(__fsub_rn(sxx, __fmul_rn(2.0f, dot)), cn);

        unsigned b = __float_as_uint(d2);
        unsigned key = (b & 0x80000000u) ? ~b : (b | 0x80000000u);
        unsigned long long pk = ((unsigned long long)key << 32) | (unsigned)mycode;
        #pragma unroll
        for (int off = 1; off < 64; off <<= 1) {
            unsigned long long o = __shfl_xor(pk, off, 64);
            pk = (o < pk) ? o : pk;
        }
        if (valid && l == 0)
            atomicMin(&slots[(size_t)cb * NODES + node], pk);
        asm volatile("s_waitcnt lgkmcnt(0)" ::: "memory");
    }
}

// ------------------------------------------------------- flag writeback ----
__global__ __launch_bounds__(256) void flag_writeback_kernel(
    const int* __restrict__ flagcnt, const int* __restrict__ flaglist,
    const unsigned long long* __restrict__ slots, int* __restrict__ idx_ws)
{
    int gt = blockIdx.x * 256 + threadIdx.x;
    int c0 = flagcnt[0]; if (c0 > FLAG_CAP) c0 = FLAG_CAP;
    int c1 = flagcnt[1]; if (c1 > FLAG_CAP) c1 = FLAG_CAP;
    for (int e = gt; e < 2 * FLAG_CAP; e += 256 * 256) {
        int cb = (e >= FLAG_CAP) ? 1 : 0;
        int i = e - cb * FLAG_CAP;
        int cnt = cb ? c1 : c0;
        if (i < cnt) {
            int node = flaglist[cb * FLAG_CAP + i];
            idx_ws[cb * NODES + node] =
                (int)(slots[(size_t)cb * NODES + node] & 0xFFFFFFFFull);
        }
    }
}

// --------------------------------------------------------------- gather ----
__global__ __launch_bounds__(256) void gather_kernel(
    const float* __restrict__ node_feat, const float* __restrict__ score,
    const float* __restrict__ cb_c, const float* __restrict__ cb_s,
    const int* __restrict__ idx_all, float* __restrict__ out,
    double* __restrict__ partials)
{
    __shared__ float redc[4], reds[4];
    int wave = threadIdx.x >> 6, lane = threadIdx.x & 63;
    int node = blockIdx.x * 4 + wave;
    float sc = score[node];
    float2 x  = *(const float2*)&node_feat[(size_t)node * DIM + 2 * lane];
    int ic = idx_all[node], is_ = idx_all[NODES + node];
    float2 qc = *(const float2*)&cb_c[(size_t)ic * DIM + 2 * lane];
    float2 qs = *(const float2*)&cb_s[(size_t)is_ * DIM + 2 * lane];

    float omsc = __fsub_rn(1.0f, sc);
    float2 cn, sn;
    cn.x = __fadd_rn(__fmul_rn(x.x, sc), qc.x);
    cn.y = __fadd_rn(__fmul_rn(x.y, sc), qc.y);
    sn.x = __fadd_rn(__fmul_rn(x.x, omsc), qs.x);
    sn.y = __fadd_rn(__fmul_rn(x.y, omsc), qs.y);
    *(float2*)&out[OFF_CN + (size_t)node * DIM + 2 * lane] = cn;
    *(float2*)&out[OFF_SN + (size_t)node * DIM + 2 * lane] = sn;

    float hc1 = h_of(x.x, sc, 0), hc2 = h_of(x.y, sc, 0);
    float hs1 = h_of(x.x, sc, 1), hs2 = h_of(x.y, sc, 1);
    float d1 = qc.x - hc1, d2 = qc.y - hc2;
    float e1 = qs.x - hs1, e2 = qs.y - hs2;
    float lc = d1 * d1 + d2 * d2;
    float ls = e1 * e1 + e2 * e2;
    #pragma unroll
    for (int off = 32; off; off >>= 1) {
        lc += __shfl_down(lc, off, 64);
        ls += __shfl_down(ls, off, 64);
    }
    if (lane == 0) { redc[wave] = lc; reds[wave] = ls; }
    __syncthreads();
    if (threadIdx.x == 0) {
        partials[blockIdx.x]        = (double)redc[0] + redc[1] + redc[2] + redc[3];
        partials[8192 + blockIdx.x] = (double)reds[0] + reds[1] + reds[2] + reds[3];
    }
}

// ---------------------------------------------------------- loss reduce ----
__global__ __launch_bounds__(256) void loss_reduce_kernel(
    const double* __restrict__ partials, float* __restrict__ out)
{
    __shared__ double red[4];
    int b = blockIdx.x, t = threadIdx.x, w = t >> 6, l = t & 63;
    const double* p = partials + b * 8192;
    double s = 0.0;
    #pragma unroll 4
    for (int i = t; i < 8192; i += 256) s += p[i];
    #pragma unroll
    for (int off = 32; off; off >>= 1) s += __shfl_down(s, off, 64);
    if (l == 0) red[w] = s;
    __syncthreads();
    if (t == 0) {
        double tot = (red[0] + red[1]) + (red[2] + red[3]);
        out[OFF_LC + b] = (float)(tot * (1.0 / 4194304.0));   // / 2^22 exact
    }
}

// ----------------------------------------------------------------- pool ----
__global__ __launch_bounds__(256) void pool_kernel(
    const int* __restrict__ starts, float* __restrict__ out)
{
    int g = blockIdx.x;
    int half = threadIdx.x >> 7, d = threadIdx.x & 127;
    int s = starts[g], e = starts[g + 1];
    const float* src = out + (half ? OFF_SN : OFF_CN);
    float sum = 0.0f;
    for (int n = s; n < e; ++n) sum = __fadd_rn(sum, src[(size_t)n * DIM + d]);
    float cnt = fmaxf((float)(e - s), 1.0f);
    out[(half ? OFF_SG : OFF_CG) + g * DIM + d] = __fdiv_rn(sum, cnt);
}

// ----------------------------------------------------------- classifier ----
__global__ __launch_bounds__(256) void classifier_kernel(
    const float* __restrict__ w1, const float* __restrict__ b1,
    const float* __restrict__ gamma, const float* __restrict__ beta,
    const float* __restrict__ rm, const float* __restrict__ rv,
    const float* __restrict__ w2, const float* __restrict__ b2,
    float* __restrict__ out)
{
    __shared__ float row[DIM];
    __shared__ float red[4];
    int g = blockIdx.x, t = threadIdx.x;
    if (t < DIM) row[t] = out[OFF_CG + g * DIM + t];
    __syncthreads();
    float h = 0.0f;
    #pragma unroll 8
    for (int k = 0; k < DIM; ++k) h = fmaf(row[k], w1[k * 256 + t], h);
    h = __fadd_rn(h, b1[t]);
    float inv = __frsqrt_rn(__fadd_rn(rv[t], 1e-5f));
    h = __fadd_rn(__fmul_rn(__fmul_rn(__fsub_rn(h, rm[t]), inv), gamma[t]), beta[t]);
    h = fmaxf(h, 0.0f);
    float p = __fmul_rn(h, w2[t]);
    #pragma unroll
    for (int off = 32; off; off >>= 1) p += __shfl_down(p, off, 64);
    if ((t & 63) == 0) red[t >> 6] = p;
    __syncthreads();
    if (t == 0) {
        float total = __fadd_rn(__fadd_rn(red[0], red[1]), __fadd_rn(red[2], red[3]));
        out[OFF_LOGIT + g] = __fadd_rn(total, b2[0]);
    }
}

extern "C" void kernel_launch(void* const* d_in, const int* in_sizes, int n_in,
                              void* d_out, int out_size, void* d_ws, size_t ws_size,
                              hipStream_t stream) {
    const float* node_feat = (const float*)d_in[0];
    const float* score     = (const float*)d_in[1];
    const int*   batch     = (const int*)d_in[2];
    const float* cb_c      = (const float*)d_in[3];
    const float* cb_s      = (const float*)d_in[4];
    const float* w1        = (const float*)d_in[5];
    const float* b1        = (const float*)d_in[6];
    const float* gamma     = (const float*)d_in[7];
    const float* beta      = (const float*)d_in[8];
    const float* rm        = (const float*)d_in[9];
    const float* rv        = (const float*)d_in[10];
    const float* w2        = (const float*)d_in[11];
    const float* b2        = (const float*)d_in[12];
    float* out = (float*)d_out;
    char*  ws  = (char*)d_ws;

    float*  cnorm    = (float*)(ws + WS_CNORM);
    int*    idx      = (int*)(ws + WS_IDX);
    int*    flagcnt  = (int*)(ws + WS_FLAGCNT);
    int*    starts   = (int*)(ws + WS_STARTS);
    int*    flaglist = (int*)(ws + WS_FLAGLIST);
    unsigned short* splits = (unsigned short*)d_out + SPLIT_U16;
    unsigned long long* halfres = (unsigned long long*)(out + HALF_F32);
    unsigned long long* cslot   = (unsigned long long*)(out + CSLOT_F32);
    double* partials = (double*)(out + OFF_CG);   // CG region scratch, pre-pool

    prep_kernel<<<2051, 256, 0, stream>>>(cb_c, cb_s, batch, cnorm, splits,
                                          starts, flagcnt);
    vq_main_kernel<<<dim3(512, 2), 256, 0, stream>>>(node_feat, score, splits, cnorm,
                                                     halfres);
    resolve_kernel<<<dim3(128, 2), 256, 0, stream>>>(halfres, cslot, idx,
                                                     flagcnt, flaglist);
    vq_cleanup_kernel<<<dim3(1024, 2), 256, 0, stream>>>(node_feat, score, cb_c, cb_s,
                                                         cnorm, flagcnt, flaglist, cslot);
    flag_writeback_kernel<<<256, 256, 0, stream>>>(flagcnt, flaglist, cslot, idx);
    gather_kernel<<<8192, 256, 0, stream>>>(node_feat, score, cb_c, cb_s, idx, out, partials);
    loss_reduce_kernel<<<2, 256, 0, stream>>>(partials, out);
    pool_kernel<<<512, 256, 0, stream>>>(starts, out);
    classifier_kernel<<<512, 256, 0, stream>>>(w1, b1, gamma, beta, rm, rv, w2, b2, out);
}

// Round 6
// 338.732 us; speedup vs baseline: 4.0917x; 1.0343x over previous
//
#include <hip/hip_runtime.h>
#include <hip/hip_bf16.h>

#define NODES   32768
#define DIM     128
#define NCODES  4096
#define NGRAPHS 512
#define THR     0.0625f

// output layout (flat f32, concatenated in reference return order)
#define OFF_LOGIT 0
#define OFF_CG    512
#define OFF_SG    66048
#define OFF_LC    131584
#define OFF_LS    131585
#define OFF_CN    131586
#define OFF_SN    4325890

// scratch inside d_out (all rewritten by gather/pool later, in stream order):
//   fp16 codebook planes: u16 idx 263680.. (2 x 1 MB)       [CN region]
//   half-results:  f32 idx 1180416.. u64[2][2][32768] 1 MB  [CN region]
//   cleanup slots: f32 idx 1442560.. u64[2][32768] 512 KB   [CN region]
//   loss partials: f32 idx 512..  double[2][8192]           [CG region]
#define SPLIT_U16   263680
#define PLANE_U16   524288
#define HALF_F32    1180416
#define CSLOT_F32   1442560

// workspace layout (bytes)
#define WS_CNORM    0        // float[2][4096]
#define WS_IDX      32768    // int[2][32768]
#define WS_FLAGCNT  294928   // int[2]
#define WS_STARTS   294936   // int[513]
#define WS_FLAGLIST 296988   // int[2][32767]
#define FLAG_CAP    32767

typedef __attribute__((ext_vector_type(8))) _Float16 f16x8_t;
typedef __attribute__((ext_vector_type(4))) float f32x4_t;

__device__ __forceinline__ float h_of(float x, float sc, int cb) {
    float omsc = __fsub_rn(1.0f, sc);
    float half_x = __fmul_rn(0.5f, x);
    if (cb == 0)
        return __fadd_rn(__fmul_rn(x, sc), __fmul_rn(half_x, omsc));
    else
        return __fadd_rn(__fmul_rn(x, omsc), __fmul_rn(half_x, sc));
}

__device__ __forceinline__ unsigned short f2h(float f) {
    return __builtin_bit_cast(unsigned short, (_Float16)f);
}

__device__ __forceinline__ void gload_lds16(const void* g, void* l) {
    __builtin_amdgcn_global_load_lds(
        (const __attribute__((address_space(1))) int*)g,
        (__attribute__((address_space(3))) int*)l, 16, 0, 0);
}

__device__ __forceinline__ unsigned sortkey(float f) {
    unsigned b = __float_as_uint(f);
    return (b & 0x80000000u) ? ~b : (b | 0x80000000u);
}
__device__ __forceinline__ float keyinv(unsigned k) {
    unsigned b = (k & 0x80000000u) ? (k & 0x7FFFFFFFu) : ~k;
    return __uint_as_float(b);
}

// ---------------------------------------------------------------- prep ----
// cnorm + fp16 codebook plane + graph boundaries + zero flag counters
__global__ __launch_bounds__(256) void prep_kernel(
    const float* __restrict__ cb_c, const float* __restrict__ cb_s,
    const int* __restrict__ batch,
    float* __restrict__ cnorm, unsigned short* __restrict__ splits,
    int* __restrict__ starts, int* __restrict__ flagcnt)
{
    int gwave = (blockIdx.x * 256 + threadIdx.x) >> 6;
    int lane  = threadIdx.x & 63;

    if (gwave < 2 * NCODES) {                  // one wave per (cb,row)
        int cb = gwave >> 12, row = gwave & (NCODES - 1);
        const float* cp = (cb ? cb_s : cb_c) + (size_t)row * DIM;
        float2 v = ((const float2*)cp)[lane];  // elems 2l, 2l+1
        float p = __fadd_rn(__fmul_rn(v.x, v.x), __fmul_rn(v.y, v.y));
        #pragma unroll
        for (int off = 32; off; off >>= 1) p = __fadd_rn(p, __shfl_xor(p, off, 64));
        if (lane == 0) cnorm[cb * NCODES + row] = p;
        unsigned int* hp = (unsigned int*)(splits + (size_t)cb * PLANE_U16);
        hp[row * 64 + lane] = (unsigned)f2h(v.x) | ((unsigned)f2h(v.y) << 16);
    } else {
        int w1 = gwave - 2 * NCODES;
        int g = w1 * 64 + lane;
        if (g <= NGRAPHS) {
            int lo = 0, hi = NODES;
            while (lo < hi) { int mid = (lo + hi) >> 1; if (batch[mid] < g) lo = mid + 1; else hi = mid; }
            starts[g] = lo;
        }
        if (w1 == 0 && lane < 2) flagcnt[lane] = 0;
    }
}

// ----------------------------------------------------------- vq main ----
// 128 nodes x 2048 codes per block (code-half split), fp16 single-plane.
// 4 waves x 32 nodes; 32 t-iters of 64 codes, double-buffered gll staging.
__global__ __launch_bounds__(256, 4) void vq_main_kernel(
    const float* __restrict__ node_feat, const float* __restrict__ score,
    const unsigned short* __restrict__ splits, const float* __restrict__ cnorm,
    unsigned long long* __restrict__ halfres)
{
    __shared__ unsigned short lds[16384];   // 32 KB
    const int nb    = blockIdx.x & 255;
    const int half  = blockIdx.x >> 8;
    const int cb    = blockIdx.y;
    const int nbase = nb * 128;
    const int tid = threadIdx.x;
    const int w   = tid >> 6;
    const int l15 = tid & 15;
    const int lg  = (tid & 63) >> 4;
    const int swz = (tid & 7) << 4;
    const float* cnp = cnorm + cb * NCODES + half * 2048;

    // ---- stage A (h values, fp16) into LDS, swizzled ----
    #pragma unroll
    for (int i = 0; i < 16; ++i) {
        int idx = i * 1024 + tid * 4;
        int row = idx >> 7, k = idx & 127;
        float4 x = *(const float4*)&node_feat[(size_t)(nbase + row) * DIM + k];
        float sc = score[nbase + row];
        unsigned u0 = f2h(h_of(x.x, sc, cb)), u1 = f2h(h_of(x.y, sc, cb));
        unsigned u2 = f2h(h_of(x.z, sc, cb)), u3 = f2h(h_of(x.w, sc, cb));
        int abyte = row * 256 + ((2 * k) ^ ((row & 7) << 4));
        uint2 hw; hw.x = u0 | (u1 << 16); hw.y = u2 | (u3 << 16);
        *(uint2*)((char*)lds + abyte) = hw;
    }
    __syncthreads();

    // ---- A fragments to registers ----
    f16x8_t ahi[2][4];
    int colbyte[4];
    #pragma unroll
    for (int ch = 0; ch < 4; ++ch) colbyte[ch] = (ch * 64 + lg * 16) ^ swz;
    #pragma unroll
    for (int rs = 0; rs < 2; ++rs)
        #pragma unroll
        for (int ch = 0; ch < 4; ++ch) {
            int row = 32 * w + 16 * rs + l15;
            ahi[rs][ch] = *(const f16x8_t*)((const char*)lds + row * 256 + colbyte[ch]);
        }
    __syncthreads();   // A reads done -> LDS reused as B double-buffer (2 x 16KB)

    // ---- B staging setup (pre-swizzled global source, linear LDS dest) ----
    const unsigned short* wplane = splits + (size_t)cb * PLANE_U16 + half * 262144;
    int soff[4];
    #pragma unroll
    for (int i = 0; i < 4; ++i) {
        int row = w * 16 + i * 4 + lg;
        soff[i] = row * 256 + ((l15 * 16) ^ ((row & 7) << 4));
    }

    {   // tile 0 -> buf0
        const char* tb = (const char*)wplane;
        #pragma unroll
        for (int i = 0; i < 4; ++i)
            gload_lds16(tb + soff[i], (char*)lds + w * 4096 + i * 1024);
    }
    __syncthreads();   // drains vmcnt -> tile0 ready

    const float NEG_INF = -3.4e38f;
    float b1v[2][4], b2v[2][4]; int b1i[2][4];
    #pragma unroll
    for (int rs = 0; rs < 2; ++rs)
        #pragma unroll
        for (int r = 0; r < 4; ++r) { b1v[rs][r] = NEG_INF; b2v[rs][r] = NEG_INF; b1i[rs][r] = 0; }

    for (int t = 0; t < 32; ++t) {
        int bs_cur = (t & 1) << 14;   // byte offset of current 16KB buffer
        float cnc[4];
        #pragma unroll
        for (int cs = 0; cs < 4; ++cs) cnc[cs] = __fmul_rn(-0.5f, cnp[t * 64 + cs * 16 + l15]);
        if (t < 31) {
            int bs_nxt = ((t + 1) & 1) << 14;
            const char* tb = (const char*)wplane + (t + 1) * 16384;
            #pragma unroll
            for (int i = 0; i < 4; ++i)
                gload_lds16(tb + soff[i], (char*)lds + bs_nxt + w * 4096 + i * 1024);
        }

        #pragma unroll
        for (int cp = 0; cp < 2; ++cp) {        // cs pairs: keeps acc live-range small
            f32x4_t acc[2][2];
            #pragma unroll
            for (int rs = 0; rs < 2; ++rs)
                #pragma unroll
                for (int c2 = 0; c2 < 2; ++c2) {
                    float iv = cnc[cp * 2 + c2];
                    acc[rs][c2] = (f32x4_t){iv, iv, iv, iv};   // folds -0.5*cn into MFMA C
                }

            #pragma unroll
            for (int ch = 0; ch < 4; ++ch)
                #pragma unroll
                for (int c2 = 0; c2 < 2; ++c2) {
                    int cs = cp * 2 + c2;
                    f16x8_t bh = *(const f16x8_t*)((const char*)lds + bs_cur +
                                                   (cs * 16 + l15) * 256 + colbyte[ch]);
                    acc[0][c2] = __builtin_amdgcn_mfma_f32_16x16x32_f16(ahi[0][ch], bh, acc[0][c2], 0, 0, 0);
                    acc[1][c2] = __builtin_amdgcn_mfma_f32_16x16x32_f16(ahi[1][ch], bh, acc[1][c2], 0, 0, 0);
                }

            #pragma unroll
            for (int c2 = 0; c2 < 2; ++c2) {
                int cs = cp * 2 + c2;
                int code = half * 2048 + t * 64 + cs * 16 + l15;
                #pragma unroll
                for (int rs = 0; rs < 2; ++rs)
                    #pragma unroll
                    for (int r = 0; r < 4; ++r) {
                        float a = acc[rs][c2][r];
                        bool gt = a > b1v[rs][r];
                        float nb2 = __builtin_amdgcn_fmed3f(a, b1v[rs][r], b2v[rs][r]);
                        if (gt) b1i[rs][r] = code;
                        b1v[rs][r] = fmaxf(a, b1v[rs][r]);
                        b2v[rs][r] = nb2;
                    }
            }
        }
        __syncthreads();   // drains gll vmcnt; protects buffer swap
    }

    // cross-lane merge over the 16 code-columns (lane bits 0..3)
    #pragma unroll
    for (int off = 1; off < 16; off <<= 1) {
        #pragma unroll
        for (int rs = 0; rs < 2; ++rs)
            #pragma unroll
            for (int r = 0; r < 4; ++r) {
                float ov1 = __shfl_xor(b1v[rs][r], off, 64);
                int   oi  = __shfl_xor(b1i[rs][r], off, 64);
                float ov2 = __shfl_xor(b2v[rs][r], off, 64);
                bool take = (ov1 > b1v[rs][r]) || (ov1 == b1v[rs][r] && oi < b1i[rs][r]);
                float loser = fminf(ov1, b1v[rs][r]);
                b1v[rs][r] = fmaxf(ov1, b1v[rs][r]);
                if (take) b1i[rs][r] = oi;
                b2v[rs][r] = fmaxf(loser, fmaxf(ov2, b2v[rs][r]));
            }
    }
    if (l15 == 0) {
        #pragma unroll
        for (int rs = 0; rs < 2; ++rs)
            #pragma unroll
            for (int r = 0; r < 4; ++r) {
                int node = nbase + 32 * w + 16 * rs + 4 * lg + r;
                unsigned key = sortkey(b1v[rs][r]);
                unsigned pay = (unsigned)b1i[rs][r] |
                               ((b1v[rs][r] - b2v[rs][r] < THR) ? 0x1000u : 0u);
                halfres[((size_t)(cb * 2 + half)) * NODES + node] =
                    ((unsigned long long)key << 32) | pay;
            }
    }
}

// -------------------------------------------------------------- resolve ----
// merge the two code-half results; wave-aggregated flaglist append
__global__ __launch_bounds__(256) void resolve_kernel(
    const unsigned long long* __restrict__ hr, unsigned long long* __restrict__ cslot,
    int* __restrict__ idx_ws, int* __restrict__ flagcnt, int* __restrict__ flaglist)
{
    int cb = blockIdx.y;
    int node = blockIdx.x * 256 + threadIdx.x;
    unsigned long long A = hr[((size_t)(cb * 2 + 0)) * NODES + node];
    unsigned long long B = hr[((size_t)(cb * 2 + 1)) * NODES + node];
    unsigned ka = (unsigned)(A >> 32), kb = (unsigned)(B >> 32);
    bool awin = ka >= kb;
    unsigned long long W = awin ? A : B;
    float aw = keyinv(awin ? ka : kb);
    float al = keyinv(awin ? kb : ka);
    bool flag = ((W >> 12) & 1ull) || (__fsub_rn(aw, al) < THR);
    idx_ws[cb * NODES + node] = (int)(W & 0xFFFu);
    if (flag) cslot[(size_t)cb * NODES + node] = ~0ull;

    unsigned long long mask = __ballot(flag);
    if (mask) {
        int lane = threadIdx.x & 63;
        int leader = __ffsll((long long)mask) - 1;
        int base = 0;
        if (lane == leader) base = atomicAdd(flagcnt + cb, (int)__popcll(mask));
        base = __shfl(base, leader, 64);
        if (flag) {
            int pos = base + (int)__popcll(mask & ((1ull << lane) - 1ull));
            if (pos < FLAG_CAP) flaglist[cb * FLAG_CAP + pos] = node;
        }
    }
}

// --------------------------------------------------------- vq cleanup ----
// exact fp32 rescore of flagged nodes. Segment codebook staged once as
// [64][128] f32 with 16B XOR swizzle -> conflict-free ds_read_b128 (lane=code).
// 2 nodes per wave share each codebook read. Same fp32 math/order as before.
__global__ __launch_bounds__(256) void vq_cleanup_kernel(
    const float* __restrict__ node_feat, const float* __restrict__ score,
    const float* __restrict__ cb_c, const float* __restrict__ cb_s,
    const float* __restrict__ cnorm, const int* __restrict__ flagcnt,
    const int* __restrict__ flaglist, unsigned long long* __restrict__ slots)
{
    __shared__ char cbS[32768];      // 64 codes x 512 B, XOR-swizzled 16B units
    __shared__ float hbuf[8][128];   // 8 nodes' h rows (2 per wave)
    const int cb  = blockIdx.y;
    const int seg = blockIdx.x & 63;    // 64-code segment
    const int ng  = blockIdx.x >> 6;    // node-group 0..15
    const float* cbp = cb ? cb_s : cb_c;
    const int* list = flaglist + cb * FLAG_CAP;
    int cnt = flagcnt[cb]; if (cnt > FLAG_CAP) cnt = FLAG_CAP;
    const int tid = threadIdx.x, w = tid >> 6, l = tid & 63;

    {   // stage this segment's 64 codes, swizzled, once
        int c = tid >> 2, ks = (tid & 3) * 32;
        const float* src = cbp + (size_t)(seg * 64 + c) * DIM + ks;
        char* dst = cbS + c * 512;
        int sw = (c & 7) << 4;
        #pragma unroll
        for (int j = 0; j < 8; ++j) {
            float4 v = *(const float4*)(src + j * 4);
            *(float4*)(dst + ((ks * 4 + j * 16) ^ sw)) = v;
        }
    }
    const int mycode = seg * 64 + l;
    const float cn = cnorm[cb * NCODES + mycode];
    const int swl = (l & 7) << 4;
    const char* crow = cbS + l * 512;
    __syncthreads();

    for (int base = ng * 8; base < cnt; base += 128) {
        int eA = base + 2 * w, eB = eA + 1;
        bool vA = eA < cnt, vB = eB < cnt;
        int nA = list[vA ? eA : 0], nB = list[vB ? eB : 0];
        float scA = score[nA], scB = score[nB];
        float a0 = h_of(node_feat[(size_t)nA * DIM + l],      scA, cb);
        float a1 = h_of(node_feat[(size_t)nA * DIM + 64 + l], scA, cb);
        float b0 = h_of(node_feat[(size_t)nB * DIM + l],      scB, cb);
        float b1 = h_of(node_feat[(size_t)nB * DIM + 64 + l], scB, cb);
        hbuf[2 * w][l] = a0;     hbuf[2 * w][64 + l] = a1;
        hbuf[2 * w + 1][l] = b0; hbuf[2 * w + 1][64 + l] = b1;
        float sxA = __fadd_rn(__fmul_rn(a0, a0), __fmul_rn(a1, a1));
        float sxB = __fadd_rn(__fmul_rn(b0, b0), __fmul_rn(b1, b1));
        #pragma unroll
        for (int off = 32; off; off >>= 1) {
            sxA = __fadd_rn(sxA, __shfl_xor(sxA, off, 64));
            sxB = __fadd_rn(sxB, __shfl_xor(sxB, off, 64));
        }
        asm volatile("s_waitcnt lgkmcnt(0)" ::: "memory");

        float pA0 = 0.f, pA1 = 0.f, pA2 = 0.f, pA3 = 0.f;
        float pB0 = 0.f, pB1 = 0.f, pB2 = 0.f, pB3 = 0.f;
        const float4* hA = (const float4*)hbuf[2 * w];
        const float4* hB = (const float4*)hbuf[2 * w + 1];
        #pragma unroll 8
        for (int m = 0; m < 32; ++m) {
            float4 c4 = *(const float4*)(crow + ((m * 16) ^ swl));
            float4 ha = hA[m], hb = hB[m];
            pA0 = fmaf(ha.x, c4.x, pA0); pA1 = fmaf(ha.y, c4.y, pA1);
            pA2 = fmaf(ha.z, c4.z, pA2); pA3 = fmaf(ha.w, c4.w, pA3);
            pB0 = fmaf(hb.x, c4.x, pB0); pB1 = fmaf(hb.y, c4.y, pB1);
            pB2 = fmaf(hb.z, c4.z, pB2); pB3 = fmaf(hb.w, c4.w, pB3);
        }
        float dotA = __fadd_rn(__fadd_rn(pA0, pA1), __fadd_rn(pA2, pA3));
        float dotB = __fadd_rn(__fadd_rn(pB0, pB1), __fadd_rn(pB2, pB3));
        float dA = __fadd_rn(__fsub_rn(sxA, __fmul_rn(2.0f, dotA)), cn);
        float dB = __fadd_rn(__fsub_rn(sxB, __fmul_rn(2.0f, dotB)), cn);

        unsigned long long pkA = ((unsigned long long)sortkey(dA) << 32) | (unsigned)mycode;
        unsigned long long pkB = ((unsigned long long)sortkey(dB) << 32) | (unsigned)mycode;
        #pragma unroll
        for (int off = 1; off < 64; off <<= 1) {
            unsigned long long oA = __shfl_xor(pkA, off, 64);
            unsigned long long oB = __shfl_xor(pkB, off, 64);
            pkA = (oA < pkA) ? oA : pkA;
            pkB = (oB < pkB) ? oB : pkB;
        }
        if (l == 0 && vA) atomicMin(&slots[(size_t)cb * NODES + nA], pkA);
        if (l == 0 && vB) atomicMin(&slots[(size_t)cb * NODES + nB], pkB);
        asm volatile("s_waitcnt lgkmcnt(0)" ::: "memory");
    }
}

// ------------------------------------------------------- flag writeback ----
__global__ __launch_bounds__(256) void flag_writeback_kernel(
    const int* __restrict__ flagcnt, const int* __restrict__ flaglist,
    const unsigned long long* __restrict__ slots, int* __restrict__ idx_ws)
{
    int gt = blockIdx.x * 256 + threadIdx.x;
    int c0 = flagcnt[0]; if (c0 > FLAG_CAP) c0 = FLAG_CAP;
    int c1 = flagcnt[1]; if (c1 > FLAG_CAP) c1 = FLAG_CAP;
    for (int e = gt; e < 2 * FLAG_CAP; e += 256 * 256) {
        int cb = (e >= FLAG_CAP) ? 1 : 0;
        int i = e - cb * FLAG_CAP;
        int cnt = cb ? c1 : c0;
        if (i < cnt) {
            int node = flaglist[cb * FLAG_CAP + i];
            idx_ws[cb * NODES + node] =
                (int)(slots[(size_t)cb * NODES + node] & 0xFFFFFFFFull);
        }
    }
}

// --------------------------------------------------------------- gather ----
__global__ __launch_bounds__(256) void gather_kernel(
    const float* __restrict__ node_feat, const float* __restrict__ score,
    const float* __restrict__ cb_c, const float* __restrict__ cb_s,
    const int* __restrict__ idx_all, float* __restrict__ out,
    double* __restrict__ partials)
{
    __shared__ float redc[4], reds[4];
    int wave = threadIdx.x >> 6, lane = threadIdx.x & 63;
    int node = blockIdx.x * 4 + wave;
    float sc = score[node];
    float2 x  = *(const float2*)&node_feat[(size_t)node * DIM + 2 * lane];
    int ic = idx_all[node], is_ = idx_all[NODES + node];
    float2 qc = *(const float2*)&cb_c[(size_t)ic * DIM + 2 * lane];
    float2 qs = *(const float2*)&cb_s[(size_t)is_ * DIM + 2 * lane];

    float omsc = __fsub_rn(1.0f, sc);
    float2 cn, sn;
    cn.x = __fadd_rn(__fmul_rn(x.x, sc), qc.x);
    cn.y = __fadd_rn(__fmul_rn(x.y, sc), qc.y);
    sn.x = __fadd_rn(__fmul_rn(x.x, omsc), qs.x);
    sn.y = __fadd_rn(__fmul_rn(x.y, omsc), qs.y);
    *(float2*)&out[OFF_CN + (size_t)node * DIM + 2 * lane] = cn;
    *(float2*)&out[OFF_SN + (size_t)node * DIM + 2 * lane] = sn;

    float hc1 = h_of(x.x, sc, 0), hc2 = h_of(x.y, sc, 0);
    float hs1 = h_of(x.x, sc, 1), hs2 = h_of(x.y, sc, 1);
    float d1 = qc.x - hc1, d2 = qc.y - hc2;
    float e1 = qs.x - hs1, e2 = qs.y - hs2;
    float lc = d1 * d1 + d2 * d2;
    float ls = e1 * e1 + e2 * e2;
    #pragma unroll
    for (int off = 32; off; off >>= 1) {
        lc += __shfl_down(lc, off, 64);
        ls += __shfl_down(ls, off, 64);
    }
    if (lane == 0) { redc[wave] = lc; reds[wave] = ls; }
    __syncthreads();
    if (threadIdx.x == 0) {
        partials[blockIdx.x]        = (double)redc[0] + redc[1] + redc[2] + redc[3];
        partials[8192 + blockIdx.x] = (double)reds[0] + reds[1] + reds[2] + reds[3];
    }
}

// ---------------------------------------------------------- loss reduce ----
__global__ __launch_bounds__(256) void loss_reduce_kernel(
    const double* __restrict__ partials, float* __restrict__ out)
{
    __shared__ double red[4];
    int b = blockIdx.x, t = threadIdx.x, w = t >> 6, l = t & 63;
    const double* p = partials + b * 8192;
    double s = 0.0;
    #pragma unroll 4
    for (int i = t; i < 8192; i += 256) s += p[i];
    #pragma unroll
    for (int off = 32; off; off >>= 1) s += __shfl_down(s, off, 64);
    if (l == 0) red[w] = s;
    __syncthreads();
    if (t == 0) {
        double tot = (red[0] + red[1]) + (red[2] + red[3]);
        out[OFF_LC + b] = (float)(tot * (1.0 / 4194304.0));   // / 2^22 exact
    }
}

// ----------------------------------------------------------------- pool ----
__global__ __launch_bounds__(256) void pool_kernel(
    const int* __restrict__ starts, float* __restrict__ out)
{
    int g = blockIdx.x;
    int half = threadIdx.x >> 7, d = threadIdx.x & 127;
    int s = starts[g], e = starts[g + 1];
    const float* src = out + (half ? OFF_SN : OFF_CN);
    float sum = 0.0f;
    for (int n = s; n < e; ++n) sum = __fadd_rn(sum, src[(size_t)n * DIM + d]);
    float cnt = fmaxf((float)(e - s), 1.0f);
    out[(half ? OFF_SG : OFF_CG) + g * DIM + d] = __fdiv_rn(sum, cnt);
}

// ----------------------------------------------------------- classifier ----
__global__ __launch_bounds__(256) void classifier_kernel(
    const float* __restrict__ w1, const float* __restrict__ b1,
    const float* __restrict__ gamma, const float* __restrict__ beta,
    const float* __restrict__ rm, const float* __restrict__ rv,
    const float* __restrict__ w2, const float* __restrict__ b2,
    float* __restrict__ out)
{
    __shared__ float row[DIM];
    __shared__ float red[4];
    int g = blockIdx.x, t = threadIdx.x;
    if (t < DIM) row[t] = out[OFF_CG + g * DIM + t];
    __syncthreads();
    float h = 0.0f;
    #pragma unroll 8
    for (int k = 0; k < DIM; ++k) h = fmaf(row[k], w1[k * 256 + t], h);
    h = __fadd_rn(h, b1[t]);
    float inv = __frsqrt_rn(__fadd_rn(rv[t], 1e-5f));
    h = __fadd_rn(__fmul_rn(__fmul_rn(__fsub_rn(h, rm[t]), inv), gamma[t]), beta[t]);
    h = fmaxf(h, 0.0f);
    float p = __fmul_rn(h, w2[t]);
    #pragma unroll
    for (int off = 32; off; off >>= 1) p += __shfl_down(p, off, 64);
    if ((t & 63) == 0) red[t >> 6] = p;
    __syncthreads();
    if (t == 0) {
        float total = __fadd_rn(__fadd_rn(red[0], red[1]), __fadd_rn(red[2], red[3]));
        out[OFF_LOGIT + g] = __fadd_rn(total, b2[0]);
    }
}

extern "C" void kernel_launch(void* const* d_in, const int* in_sizes, int n_in,
                              void* d_out, int out_size, void* d_ws, size_t ws_size,
                              hipStream_t stream) {
    const float* node_feat = (const float*)d_in[0];
    const float* score     = (const float*)d_in[1];
    const int*   batch     = (const int*)d_in[2];
    const float* cb_c      = (const float*)d_in[3];
    const float* cb_s      = (const float*)d_in[4];
    const float* w1        = (const float*)d_in[5];
    const float* b1        = (const float*)d_in[6];
    const float* gamma     = (const float*)d_in[7];
    const float* beta      = (const float*)d_in[8];
    const float* rm        = (const float*)d_in[9];
    const float* rv        = (const float*)d_in[10];
    const float* w2        = (const float*)d_in[11];
    const float* b2        = (const float*)d_in[12];
    float* out = (float*)d_out;
    char*  ws  = (char*)d_ws;

    float*  cnorm    = (float*)(ws + WS_CNORM);
    int*    idx      = (int*)(ws + WS_IDX);
    int*    flagcnt  = (int*)(ws + WS_FLAGCNT);
    int*    starts   = (int*)(ws + WS_STARTS);
    int*    flaglist = (int*)(ws + WS_FLAGLIST);
    unsigned short* splits = (unsigned short*)d_out + SPLIT_U16;
    unsigned long long* halfres = (unsigned long long*)(out + HALF_F32);
    unsigned long long* cslot   = (unsigned long long*)(out + CSLOT_F32);
    double* partials = (double*)(out + OFF_CG);   // CG region scratch, pre-pool

    prep_kernel<<<2051, 256, 0, stream>>>(cb_c, cb_s, batch, cnorm, splits,
                                          starts, flagcnt);
    vq_main_kernel<<<dim3(512, 2), 256, 0, stream>>>(node_feat, score, splits, cnorm,
                                                     halfres);
    resolve_kernel<<<dim3(128, 2), 256, 0, stream>>>(halfres, cslot, idx,
                                                     flagcnt, flaglist);
    vq_cleanup_kernel<<<dim3(1024, 2), 256, 0, stream>>>(node_feat, score, cb_c, cb_s,
                                                         cnorm, flagcnt, flaglist, cslot);
    flag_writeback_kernel<<<256, 256, 0, stream>>>(flagcnt, flaglist, cslot, idx);
    gather_kernel<<<8192, 256, 0, stream>>>(node_feat, score, cb_c, cb_s, idx, out, partials);
    loss_reduce_kernel<<<2, 256, 0, stream>>>(partials, out);
    pool_kernel<<<512, 256, 0, stream>>>(starts, out);
    classifier_kernel<<<512, 256, 0, stream>>>(w1, b1, gamma, beta, rm, rv, w2, b2, out);
}

// Round 7
// 323.829 us; speedup vs baseline: 4.2800x; 1.0460x over previous
//
#include <hip/hip_runtime.h>
#include <hip/hip_bf16.h>

#define NODES   32768
#define DIM     128
#define NCODES  4096
#define NGRAPHS 512
#define THR     0.0625f

// output layout (flat f32, concatenated in reference return order)
#define OFF_LOGIT 0
#define OFF_CG    512
#define OFF_SG    66048
#define OFF_LC    131584
#define OFF_LS    131585
#define OFF_CN    131586
#define OFF_SN    4325890

// scratch inside d_out (all rewritten by gather/pool later, in stream order):
//   fp16 codebook planes: u16 idx 263680.. (2 x 1 MB)       [CN region]
//   half-results:  f32 idx 1180416.. u64[2][2][32768] 1 MB  [CN region]
//   cleanup slots: f32 idx 1442560.. u64[2][32768] 512 KB   [CN region]
//   loss partials: f32 idx 512..  double[2][8192]           [CG region]
#define SPLIT_U16   263680
#define PLANE_U16   524288
#define HALF_F32    1180416
#define CSLOT_F32   1442560

// workspace layout (bytes)
#define WS_CNORM    0        // float[2][4096]
#define WS_IDX      32768    // int[2][32768]
#define WS_FLAGCNT  294928   // int[2]
#define WS_STARTS   294936   // int[513]
#define WS_FLAGLIST 296988   // int[2][32767]
#define FLAG_CAP    32767

typedef __attribute__((ext_vector_type(8))) _Float16 f16x8_t;
typedef __attribute__((ext_vector_type(4))) float f32x4_t;

__device__ __forceinline__ float h_of(float x, float sc, int cb) {
    float omsc = __fsub_rn(1.0f, sc);
    float half_x = __fmul_rn(0.5f, x);
    if (cb == 0)
        return __fadd_rn(__fmul_rn(x, sc), __fmul_rn(half_x, omsc));
    else
        return __fadd_rn(__fmul_rn(x, omsc), __fmul_rn(half_x, sc));
}

__device__ __forceinline__ unsigned short f2h(float f) {
    return __builtin_bit_cast(unsigned short, (_Float16)f);
}

__device__ __forceinline__ void gload_lds16(const void* g, void* l) {
    __builtin_amdgcn_global_load_lds(
        (const __attribute__((address_space(1))) int*)g,
        (__attribute__((address_space(3))) int*)l, 16, 0, 0);
}

__device__ __forceinline__ unsigned sortkey(float f) {
    unsigned b = __float_as_uint(f);
    return (b & 0x80000000u) ? ~b : (b | 0x80000000u);
}
__device__ __forceinline__ float keyinv(unsigned k) {
    unsigned b = (k & 0x80000000u) ? (k & 0x7FFFFFFFu) : ~k;
    return __uint_as_float(b);
}

// ---------------------------------------------------------------- prep ----
__global__ __launch_bounds__(256) void prep_kernel(
    const float* __restrict__ cb_c, const float* __restrict__ cb_s,
    const int* __restrict__ batch,
    float* __restrict__ cnorm, unsigned short* __restrict__ splits,
    int* __restrict__ starts, int* __restrict__ flagcnt)
{
    int gwave = (blockIdx.x * 256 + threadIdx.x) >> 6;
    int lane  = threadIdx.x & 63;

    if (gwave < 2 * NCODES) {                  // one wave per (cb,row)
        int cb = gwave >> 12, row = gwave & (NCODES - 1);
        const float* cp = (cb ? cb_s : cb_c) + (size_t)row * DIM;
        float2 v = ((const float2*)cp)[lane];  // elems 2l, 2l+1
        float p = __fadd_rn(__fmul_rn(v.x, v.x), __fmul_rn(v.y, v.y));
        #pragma unroll
        for (int off = 32; off; off >>= 1) p = __fadd_rn(p, __shfl_xor(p, off, 64));
        if (lane == 0) cnorm[cb * NCODES + row] = p;
        unsigned int* hp = (unsigned int*)(splits + (size_t)cb * PLANE_U16);
        hp[row * 64 + lane] = (unsigned)f2h(v.x) | ((unsigned)f2h(v.y) << 16);
    } else {
        int w1 = gwave - 2 * NCODES;
        int g = w1 * 64 + lane;
        if (g <= NGRAPHS) {
            int lo = 0, hi = NODES;
            while (lo < hi) { int mid = (lo + hi) >> 1; if (batch[mid] < g) lo = mid + 1; else hi = mid; }
            starts[g] = lo;
        }
        if (w1 == 0 && lane < 2) flagcnt[lane] = 0;
    }
}

// ----------------------------------------------------------- vq main ----
// 256 nodes x 2048 codes per block. 4 waves x 64 nodes; 32 t-iters of 64
// codes, double-buffered gll staging into the (reused) A-stage LDS region.
__global__ __launch_bounds__(256, 2) void vq_main_kernel(
    const float* __restrict__ node_feat, const float* __restrict__ score,
    const unsigned short* __restrict__ splits, const float* __restrict__ cnorm,
    unsigned long long* __restrict__ halfres)
{
    __shared__ __align__(16) char lds[65536];   // 64 KB: A stage, then 2x16KB B dbuf
    const int nb    = blockIdx.x & 127;
    const int half  = blockIdx.x >> 7;
    const int cb    = blockIdx.y;
    const int nbase = nb * 256;
    const int tid = threadIdx.x;
    const int w   = tid >> 6;
    const int l15 = tid & 15;
    const int lg  = (tid & 63) >> 4;
    const int swz = (tid & 7) << 4;
    const float* cnp = cnorm + cb * NCODES + half * 2048;

    // ---- stage A (h values, fp16) into LDS, swizzled: 256 rows x 256 B ----
    #pragma unroll
    for (int i = 0; i < 32; ++i) {
        int idx = i * 1024 + tid * 4;
        int row = idx >> 7, k = idx & 127;
        float4 x = *(const float4*)&node_feat[(size_t)(nbase + row) * DIM + k];
        float sc = score[nbase + row];
        unsigned u0 = f2h(h_of(x.x, sc, cb)), u1 = f2h(h_of(x.y, sc, cb));
        unsigned u2 = f2h(h_of(x.z, sc, cb)), u3 = f2h(h_of(x.w, sc, cb));
        int abyte = row * 256 + ((2 * k) ^ ((row & 7) << 4));
        uint2 hw; hw.x = u0 | (u1 << 16); hw.y = u2 | (u3 << 16);
        *(uint2*)(lds + abyte) = hw;
    }
    __syncthreads();

    // ---- A fragments to registers: 4 rs x 4 ch ----
    f16x8_t ahi[4][4];
    int colbyte[4];
    #pragma unroll
    for (int ch = 0; ch < 4; ++ch) colbyte[ch] = (ch * 64 + lg * 16) ^ swz;
    #pragma unroll
    for (int rs = 0; rs < 4; ++rs)
        #pragma unroll
        for (int ch = 0; ch < 4; ++ch) {
            int row = 64 * w + 16 * rs + l15;
            ahi[rs][ch] = *(const f16x8_t*)(lds + row * 256 + colbyte[ch]);
        }
    __syncthreads();   // A reads done -> LDS reused as B double-buffer (2 x 16KB)

    // ---- B staging setup (pre-swizzled global source, linear LDS dest) ----
    const unsigned short* wplane = splits + (size_t)cb * PLANE_U16 + half * 262144;
    int soff[4];
    #pragma unroll
    for (int i = 0; i < 4; ++i) {
        int row = w * 16 + i * 4 + lg;
        soff[i] = row * 256 + ((l15 * 16) ^ ((row & 7) << 4));
    }

    {   // tile 0 -> buf0
        const char* tb = (const char*)wplane;
        #pragma unroll
        for (int i = 0; i < 4; ++i)
            gload_lds16(tb + soff[i], lds + w * 4096 + i * 1024);
    }
    __syncthreads();   // drains vmcnt -> tile0 ready

    const float NEG_INF = -3.4e38f;
    float b1v[4][4], b2v[4][4]; int b1i[4][4];
    #pragma unroll
    for (int rs = 0; rs < 4; ++rs)
        #pragma unroll
        for (int r = 0; r < 4; ++r) { b1v[rs][r] = NEG_INF; b2v[rs][r] = NEG_INF; b1i[rs][r] = 0; }

    for (int t = 0; t < 32; ++t) {
        int bs_cur = (t & 1) << 14;   // byte offset of current 16KB buffer
        float cnc[4];
        #pragma unroll
        for (int cs = 0; cs < 4; ++cs) cnc[cs] = __fmul_rn(-0.5f, cnp[t * 64 + cs * 16 + l15]);
        if (t < 31) {
            int bs_nxt = ((t + 1) & 1) << 14;
            const char* tb = (const char*)wplane + (t + 1) * 16384;
            #pragma unroll
            for (int i = 0; i < 4; ++i)
                gload_lds16(tb + soff[i], lds + bs_nxt + w * 4096 + i * 1024);
        }

        #pragma unroll
        for (int cp = 0; cp < 2; ++cp) {        // cs pairs
            f32x4_t acc[4][2];
            #pragma unroll
            for (int rs = 0; rs < 4; ++rs)
                #pragma unroll
                for (int c2 = 0; c2 < 2; ++c2) {
                    float iv = cnc[cp * 2 + c2];
                    acc[rs][c2] = (f32x4_t){iv, iv, iv, iv};   // folds -0.5*cn into MFMA C
                }

            #pragma unroll
            for (int ch = 0; ch < 4; ++ch)
                #pragma unroll
                for (int c2 = 0; c2 < 2; ++c2) {
                    int cs = cp * 2 + c2;
                    f16x8_t bh = *(const f16x8_t*)(lds + bs_cur +
                                                   (cs * 16 + l15) * 256 + colbyte[ch]);
                    #pragma unroll
                    for (int rs = 0; rs < 4; ++rs)
                        acc[rs][c2] = __builtin_amdgcn_mfma_f32_16x16x32_f16(ahi[rs][ch], bh, acc[rs][c2], 0, 0, 0);
                }

            #pragma unroll
            for (int c2 = 0; c2 < 2; ++c2) {
                int cs = cp * 2 + c2;
                int code = half * 2048 + t * 64 + cs * 16 + l15;
                #pragma unroll
                for (int rs = 0; rs < 4; ++rs)
                    #pragma unroll
                    for (int r = 0; r < 4; ++r) {
                        float a = acc[rs][c2][r];
                        bool gt = a > b1v[rs][r];
                        float nb2 = __builtin_amdgcn_fmed3f(a, b1v[rs][r], b2v[rs][r]);
                        if (gt) b1i[rs][r] = code;
                        b1v[rs][r] = fmaxf(a, b1v[rs][r]);
                        b2v[rs][r] = nb2;
                    }
            }
        }
        __syncthreads();   // drains gll vmcnt; protects buffer swap
    }

    // cross-lane merge over the 16 code-columns (lane bits 0..3)
    #pragma unroll
    for (int off = 1; off < 16; off <<= 1) {
        #pragma unroll
        for (int rs = 0; rs < 4; ++rs)
            #pragma unroll
            for (int r = 0; r < 4; ++r) {
                float ov1 = __shfl_xor(b1v[rs][r], off, 64);
                int   oi  = __shfl_xor(b1i[rs][r], off, 64);
                float ov2 = __shfl_xor(b2v[rs][r], off, 64);
                bool take = (ov1 > b1v[rs][r]) || (ov1 == b1v[rs][r] && oi < b1i[rs][r]);
                float loser = fminf(ov1, b1v[rs][r]);
                b1v[rs][r] = fmaxf(ov1, b1v[rs][r]);
                if (take) b1i[rs][r] = oi;
                b2v[rs][r] = fmaxf(loser, fmaxf(ov2, b2v[rs][r]));
            }
    }
    if (l15 == 0) {
        #pragma unroll
        for (int rs = 0; rs < 4; ++rs)
            #pragma unroll
            for (int r = 0; r < 4; ++r) {
                int node = nbase + 64 * w + 16 * rs + 4 * lg + r;
                unsigned key = sortkey(b1v[rs][r]);
                unsigned pay = (unsigned)b1i[rs][r] |
                               ((b1v[rs][r] - b2v[rs][r] < THR) ? 0x1000u : 0u);
                halfres[((size_t)(cb * 2 + half)) * NODES + node] =
                    ((unsigned long long)key << 32) | pay;
            }
    }
}

// -------------------------------------------------------------- resolve ----
__global__ __launch_bounds__(256) void resolve_kernel(
    const unsigned long long* __restrict__ hr, unsigned long long* __restrict__ cslot,
    int* __restrict__ idx_ws, int* __restrict__ flagcnt, int* __restrict__ flaglist)
{
    int cb = blockIdx.y;
    int node = blockIdx.x * 256 + threadIdx.x;
    unsigned long long A = hr[((size_t)(cb * 2 + 0)) * NODES + node];
    unsigned long long B = hr[((size_t)(cb * 2 + 1)) * NODES + node];
    unsigned ka = (unsigned)(A >> 32), kb = (unsigned)(B >> 32);
    bool awin = ka >= kb;
    unsigned long long W = awin ? A : B;
    float aw = keyinv(awin ? ka : kb);
    float al = keyinv(awin ? kb : ka);
    bool flag = ((W >> 12) & 1ull) || (__fsub_rn(aw, al) < THR);
    idx_ws[cb * NODES + node] = (int)(W & 0xFFFu);
    if (flag) cslot[(size_t)cb * NODES + node] = ~0ull;

    unsigned long long mask = __ballot(flag);
    if (mask) {
        int lane = threadIdx.x & 63;
        int leader = __ffsll((long long)mask) - 1;
        int base = 0;
        if (lane == leader) base = atomicAdd(flagcnt + cb, (int)__popcll(mask));
        base = __shfl(base, leader, 64);
        if (flag) {
            int pos = base + (int)__popcll(mask & ((1ull << lane) - 1ull));
            if (pos < FLAG_CAP) flaglist[cb * FLAG_CAP + pos] = node;
        }
    }
}

// --------------------------------------------------------- vq cleanup ----
// exact fp32 rescore of flagged nodes; 64 segs x 64 node-groups.
__global__ __launch_bounds__(256) void vq_cleanup_kernel(
    const float* __restrict__ node_feat, const float* __restrict__ score,
    const float* __restrict__ cb_c, const float* __restrict__ cb_s,
    const float* __restrict__ cnorm, const int* __restrict__ flagcnt,
    const int* __restrict__ flaglist, unsigned long long* __restrict__ slots)
{
    __shared__ char cbS[32768];      // 64 codes x 512 B, XOR-swizzled 16B units
    __shared__ float hbuf[8][128];   // 8 nodes' h rows (2 per wave)
    const int cb  = blockIdx.y;
    const int seg = blockIdx.x & 63;    // 64-code segment
    const int ng  = blockIdx.x >> 6;    // node-group 0..63
    const float* cbp = cb ? cb_s : cb_c;
    const int* list = flaglist + cb * FLAG_CAP;
    int cnt = flagcnt[cb]; if (cnt > FLAG_CAP) cnt = FLAG_CAP;
    const int tid = threadIdx.x, w = tid >> 6, l = tid & 63;

    {   // stage this segment's 64 codes, swizzled, once
        int c = tid >> 2, ks = (tid & 3) * 32;
        const float* src = cbp + (size_t)(seg * 64 + c) * DIM + ks;
        char* dst = cbS + c * 512;
        int sw = (c & 7) << 4;
        #pragma unroll
        for (int j = 0; j < 8; ++j) {
            float4 v = *(const float4*)(src + j * 4);
            *(float4*)(dst + ((ks * 4 + j * 16) ^ sw)) = v;
        }
    }
    const int mycode = seg * 64 + l;
    const float cn = cnorm[cb * NCODES + mycode];
    const int swl = (l & 7) << 4;
    const char* crow = cbS + l * 512;
    __syncthreads();

    for (int base = ng * 8; base < cnt; base += 512) {
        int eA = base + 2 * w, eB = eA + 1;
        bool vA = eA < cnt, vB = eB < cnt;
        int nA = list[vA ? eA : 0], nB = list[vB ? eB : 0];
        float scA = score[nA], scB = score[nB];
        float a0 = h_of(node_feat[(size_t)nA * DIM + l],      scA, cb);
        float a1 = h_of(node_feat[(size_t)nA * DIM + 64 + l], scA, cb);
        float b0 = h_of(node_feat[(size_t)nB * DIM + l],      scB, cb);
        float b1 = h_of(node_feat[(size_t)nB * DIM + 64 + l], scB, cb);
        hbuf[2 * w][l] = a0;     hbuf[2 * w][64 + l] = a1;
        hbuf[2 * w + 1][l] = b0; hbuf[2 * w + 1][64 + l] = b1;
        float sxA = __fadd_rn(__fmul_rn(a0, a0), __fmul_rn(a1, a1));
        float sxB = __fadd_rn(__fmul_rn(b0, b0), __fmul_rn(b1, b1));
        #pragma unroll
        for (int off = 32; off; off >>= 1) {
            sxA = __fadd_rn(sxA, __shfl_xor(sxA, off, 64));
            sxB = __fadd_rn(sxB, __shfl_xor(sxB, off, 64));
        }
        asm volatile("s_waitcnt lgkmcnt(0)" ::: "memory");

        float pA0 = 0.f, pA1 = 0.f, pA2 = 0.f, pA3 = 0.f;
        float pB0 = 0.f, pB1 = 0.f, pB2 = 0.f, pB3 = 0.f;
        const float4* hA = (const float4*)hbuf[2 * w];
        const float4* hB = (const float4*)hbuf[2 * w + 1];
        #pragma unroll 8
        for (int m = 0; m < 32; ++m) {
            float4 c4 = *(const float4*)(crow + ((m * 16) ^ swl));
            float4 ha = hA[m], hb = hB[m];
            pA0 = fmaf(ha.x, c4.x, pA0); pA1 = fmaf(ha.y, c4.y, pA1);
            pA2 = fmaf(ha.z, c4.z, pA2); pA3 = fmaf(ha.w, c4.w, pA3);
            pB0 = fmaf(hb.x, c4.x, pB0); pB1 = fmaf(hb.y, c4.y, pB1);
            pB2 = fmaf(hb.z, c4.z, pB2); pB3 = fmaf(hb.w, c4.w, pB3);
        }
        float dotA = __fadd_rn(__fadd_rn(pA0, pA1), __fadd_rn(pA2, pA3));
        float dotB = __fadd_rn(__fadd_rn(pB0, pB1), __fadd_rn(pB2, pB3));
        float dA = __fadd_rn(__fsub_rn(sxA, __fmul_rn(2.0f, dotA)), cn);
        float dB = __fadd_rn(__fsub_rn(sxB, __fmul_rn(2.0f, dotB)), cn);

        unsigned long long pkA = ((unsigned long long)sortkey(dA) << 32) | (unsigned)mycode;
        unsigned long long pkB = ((unsigned long long)sortkey(dB) << 32) | (unsigned)mycode;
        #pragma unroll
        for (int off = 1; off < 64; off <<= 1) {
            unsigned long long oA = __shfl_xor(pkA, off, 64);
            unsigned long long oB = __shfl_xor(pkB, off, 64);
            pkA = (oA < pkA) ? oA : pkA;
            pkB = (oB < pkB) ? oB : pkB;
        }
        if (l == 0 && vA) atomicMin(&slots[(size_t)cb * NODES + nA], pkA);
        if (l == 0 && vB) atomicMin(&slots[(size_t)cb * NODES + nB], pkB);
        asm volatile("s_waitcnt lgkmcnt(0)" ::: "memory");
    }
}

// ------------------------------------------------------- flag writeback ----
__global__ __launch_bounds__(256) void flag_writeback_kernel(
    const int* __restrict__ flagcnt, const int* __restrict__ flaglist,
    const unsigned long long* __restrict__ slots, int* __restrict__ idx_ws)
{
    int gt = blockIdx.x * 256 + threadIdx.x;
    int c0 = flagcnt[0]; if (c0 > FLAG_CAP) c0 = FLAG_CAP;
    int c1 = flagcnt[1]; if (c1 > FLAG_CAP) c1 = FLAG_CAP;
    for (int e = gt; e < 2 * FLAG_CAP; e += 256 * 256) {
        int cb = (e >= FLAG_CAP) ? 1 : 0;
        int i = e - cb * FLAG_CAP;
        int cnt = cb ? c1 : c0;
        if (i < cnt) {
            int node = flaglist[cb * FLAG_CAP + i];
            idx_ws[cb * NODES + node] =
                (int)(slots[(size_t)cb * NODES + node] & 0xFFFFFFFFull);
        }
    }
}

// --------------------------------------------------------------- gather ----
__global__ __launch_bounds__(256) void gather_kernel(
    const float* __restrict__ node_feat, const float* __restrict__ score,
    const float* __restrict__ cb_c, const float* __restrict__ cb_s,
    const int* __restrict__ idx_all, float* __restrict__ out,
    double* __restrict__ partials)
{
    __shared__ float redc[4], reds[4];
    int wave = threadIdx.x >> 6, lane = threadIdx.x & 63;
    int node = blockIdx.x * 4 + wave;
    float sc = score[node];
    float2 x  = *(const float2*)&node_feat[(size_t)node * DIM + 2 * lane];
    int ic = idx_all[node], is_ = idx_all[NODES + node];
    float2 qc = *(const float2*)&cb_c[(size_t)ic * DIM + 2 * lane];
    float2 qs = *(const float2*)&cb_s[(size_t)is_ * DIM + 2 * lane];

    float omsc = __fsub_rn(1.0f, sc);
    float2 cn, sn;
    cn.x = __fadd_rn(__fmul_rn(x.x, sc), qc.x);
    cn.y = __fadd_rn(__fmul_rn(x.y, sc), qc.y);
    sn.x = __fadd_rn(__fmul_rn(x.x, omsc), qs.x);
    sn.y = __fadd_rn(__fmul_rn(x.y, omsc), qs.y);
    *(float2*)&out[OFF_CN + (size_t)node * DIM + 2 * lane] = cn;
    *(float2*)&out[OFF_SN + (size_t)node * DIM + 2 * lane] = sn;

    float hc1 = h_of(x.x, sc, 0), hc2 = h_of(x.y, sc, 0);
    float hs1 = h_of(x.x, sc, 1), hs2 = h_of(x.y, sc, 1);
    float d1 = qc.x - hc1, d2 = qc.y - hc2;
    float e1 = qs.x - hs1, e2 = qs.y - hs2;
    float lc = d1 * d1 + d2 * d2;
    float ls = e1 * e1 + e2 * e2;
    #pragma unroll
    for (int off = 32; off; off >>= 1) {
        lc += __shfl_down(lc, off, 64);
        ls += __shfl_down(ls, off, 64);
    }
    if (lane == 0) { redc[wave] = lc; reds[wave] = ls; }
    __syncthreads();
    if (threadIdx.x == 0) {
        partials[blockIdx.x]        = (double)redc[0] + redc[1] + redc[2] + redc[3];
        partials[8192 + blockIdx.x] = (double)reds[0] + reds[1] + reds[2] + reds[3];
    }
}

// ---------------------------------------------------------- loss reduce ----
__global__ __launch_bounds__(256) void loss_reduce_kernel(
    const double* __restrict__ partials, float* __restrict__ out)
{
    __shared__ double red[4];
    int b = blockIdx.x, t = threadIdx.x, w = t >> 6, l = t & 63;
    const double* p = partials + b * 8192;
    double s = 0.0;
    #pragma unroll 4
    for (int i = t; i < 8192; i += 256) s += p[i];
    #pragma unroll
    for (int off = 32; off; off >>= 1) s += __shfl_down(s, off, 64);
    if (l == 0) red[w] = s;
    __syncthreads();
    if (t == 0) {
        double tot = (red[0] + red[1]) + (red[2] + red[3]);
        out[OFF_LC + b] = (float)(tot * (1.0 / 4194304.0));   // / 2^22 exact
    }
}

// ----------------------------------------------------------------- pool ----
// grid (512 graphs, 2 halves), 512 threads = 4 node-lanes x 128 dims
__global__ __launch_bounds__(512) void pool_kernel(
    const int* __restrict__ starts, float* __restrict__ out)
{
    __shared__ float part[4][128];
    int g = blockIdx.x, half = blockIdx.y;
    int d = threadIdx.x & 127, nl = threadIdx.x >> 7;
    int s = starts[g], e = starts[g + 1];
    const float* src = out + (half ? OFF_SN : OFF_CN);
    float sum = 0.0f;
    for (int n = s + nl; n < e; n += 4) sum = __fadd_rn(sum, src[(size_t)n * DIM + d]);
    part[nl][d] = sum;
    __syncthreads();
    if (nl == 0) {
        float tot = __fadd_rn(__fadd_rn(part[0][d], part[1][d]),
                              __fadd_rn(part[2][d], part[3][d]));
        float cnt = fmaxf((float)(e - s), 1.0f);
        out[(half ? OFF_SG : OFF_CG) + g * DIM + d] = __fdiv_rn(tot, cnt);
    }
}

// ----------------------------------------------------------- classifier ----
__global__ __launch_bounds__(256) void classifier_kernel(
    const float* __restrict__ w1, const float* __restrict__ b1,
    const float* __restrict__ gamma, const float* __restrict__ beta,
    const float* __restrict__ rm, const float* __restrict__ rv,
    const float* __restrict__ w2, const float* __restrict__ b2,
    float* __restrict__ out)
{
    __shared__ float row[DIM];
    __shared__ float red[4];
    int g = blockIdx.x, t = threadIdx.x;
    if (t < DIM) row[t] = out[OFF_CG + g * DIM + t];
    __syncthreads();
    float h = 0.0f;
    #pragma unroll 8
    for (int k = 0; k < DIM; ++k) h = fmaf(row[k], w1[k * 256 + t], h);
    h = __fadd_rn(h, b1[t]);
    float inv = __frsqrt_rn(__fadd_rn(rv[t], 1e-5f));
    h = __fadd_rn(__fmul_rn(__fmul_rn(__fsub_rn(h, rm[t]), inv), gamma[t]), beta[t]);
    h = fmaxf(h, 0.0f);
    float p = __fmul_rn(h, w2[t]);
    #pragma unroll
    for (int off = 32; off; off >>= 1) p += __shfl_down(p, off, 64);
    if ((t & 63) == 0) red[t >> 6] = p;
    __syncthreads();
    if (t == 0) {
        float total = __fadd_rn(__fadd_rn(red[0], red[1]), __fadd_rn(red[2], red[3]));
        out[OFF_LOGIT + g] = __fadd_rn(total, b2[0]);
    }
}

extern "C" void kernel_launch(void* const* d_in, const int* in_sizes, int n_in,
                              void* d_out, int out_size, void* d_ws, size_t ws_size,
                              hipStream_t stream) {
    const float* node_feat = (const float*)d_in[0];
    const float* score     = (const float*)d_in[1];
    const int*   batch     = (const int*)d_in[2];
    const float* cb_c      = (const float*)d_in[3];
    const float* cb_s      = (const float*)d_in[4];
    const float* w1        = (const float*)d_in[5];
    const float* b1        = (const float*)d_in[6];
    const float* gamma     = (const float*)d_in[7];
    const float* beta      = (const float*)d_in[8];
    const float* rm        = (const float*)d_in[9];
    const float* rv        = (const float*)d_in[10];
    const float* w2        = (const float*)d_in[11];
    const float* b2        = (const float*)d_in[12];
    float* out = (float*)d_out;
    char*  ws  = (char*)d_ws;

    float*  cnorm    = (float*)(ws + WS_CNORM);
    int*    idx      = (int*)(ws + WS_IDX);
    int*    flagcnt  = (int*)(ws + WS_FLAGCNT);
    int*    starts   = (int*)(ws + WS_STARTS);
    int*    flaglist = (int*)(ws + WS_FLAGLIST);
    unsigned short* splits = (unsigned short*)d_out + SPLIT_U16;
    unsigned long long* halfres = (unsigned long long*)(out + HALF_F32);
    unsigned long long* cslot   = (unsigned long long*)(out + CSLOT_F32);
    double* partials = (double*)(out + OFF_CG);   // CG region scratch, pre-pool

    prep_kernel<<<2051, 256, 0, stream>>>(cb_c, cb_s, batch, cnorm, splits,
                                          starts, flagcnt);
    vq_main_kernel<<<dim3(256, 2), 256, 0, stream>>>(node_feat, score, splits, cnorm,
                                                     halfres);
    resolve_kernel<<<dim3(128, 2), 256, 0, stream>>>(halfres, cslot, idx,
                                                     flagcnt, flaglist);
    vq_cleanup_kernel<<<dim3(4096, 2), 256, 0, stream>>>(node_feat, score, cb_c, cb_s,
                                                         cnorm, flagcnt, flaglist, cslot);
    flag_writeback_kernel<<<256, 256, 0, stream>>>(flagcnt, flaglist, cslot, idx);
    gather_kernel<<<8192, 256, 0, stream>>>(node_feat, score, cb_c, cb_s, idx, out, partials);
    loss_reduce_kernel<<<2, 256, 0, stream>>>(partials, out);
    pool_kernel<<<dim3(512, 2), 512, 0, stream>>>(starts, out);
    classifier_kernel<<<512, 256, 0, stream>>>(w1, b1, gamma, beta, rm, rv, w2, b2, out);
}

// Round 8
// 315.523 us; speedup vs baseline: 4.3927x; 1.0263x over previous
//
#include <hip/hip_runtime.h>
#include <hip/hip_bf16.h>

#define NODES   32768
#define DIM     128
#define NCODES  4096
#define NGRAPHS 512
#define THR     0.0625f

// output layout (flat f32, concatenated in reference return order)
#define OFF_LOGIT 0
#define OFF_CG    512
#define OFF_SG    66048
#define OFF_LC    131584
#define OFF_LS    131585
#define OFF_CN    131586
#define OFF_SN    4325890

// scratch inside d_out (all rewritten by gather/pool later, in stream order):
//   fp16 codebook planes (FRAGMENT ORDER): u16 idx 263680.. (2 x 1 MB) [CN region]
//   half-results:  f32 idx 1180416.. u64[2][2][32768] 1 MB  [CN region]
//   cleanup slots: f32 idx 1442560.. u64[2][32768] 512 KB   [CN region]
//   loss partials: f32 idx 512..  double[2][8192]           [CG region]
#define SPLIT_U16   263680
#define PLANE_U16   524288
#define HALF_F32    1180416
#define CSLOT_F32   1442560

// workspace layout (bytes)
#define WS_CNORM    0        // float[2][4096]
#define WS_IDX      32768    // int[2][32768]
#define WS_FLAGCNT  294928   // int[2]
#define WS_STARTS   294936   // int[513]
#define WS_FLAGLIST 296988   // int[2][32767]
#define FLAG_CAP    32767

typedef __attribute__((ext_vector_type(8))) _Float16 f16x8_t;
typedef __attribute__((ext_vector_type(4))) float f32x4_t;

__device__ __forceinline__ float h_of(float x, float sc, int cb) {
    float omsc = __fsub_rn(1.0f, sc);
    float half_x = __fmul_rn(0.5f, x);
    if (cb == 0)
        return __fadd_rn(__fmul_rn(x, sc), __fmul_rn(half_x, omsc));
    else
        return __fadd_rn(__fmul_rn(x, omsc), __fmul_rn(half_x, sc));
}

__device__ __forceinline__ unsigned short f2h(float f) {
    return __builtin_bit_cast(unsigned short, (_Float16)f);
}

__device__ __forceinline__ void gload_lds16(const void* g, void* l) {
    __builtin_amdgcn_global_load_lds(
        (const __attribute__((address_space(1))) int*)g,
        (__attribute__((address_space(3))) int*)l, 16, 0, 0);
}

__device__ __forceinline__ unsigned sortkey(float f) {
    unsigned b = __float_as_uint(f);
    return (b & 0x80000000u) ? ~b : (b | 0x80000000u);
}
__device__ __forceinline__ float keyinv(unsigned k) {
    unsigned b = (k & 0x80000000u) ? (k & 0x7FFFFFFFu) : ~k;
    return __uint_as_float(b);
}

// ---------------------------------------------------------------- prep ----
// cnorm + fp16 codebook plane in MFMA-FRAGMENT ORDER + boundaries + zeroing.
// Fragment order (per half): u32 idx = ((t*16 + cs*4 + ch)*64 + lg*16 + l15)*4 + jw
//   where code = half*2048 + t*64 + cs*16 + l15, k = 2*lane: ch=k>>5,
//   lg=(k>>3)&3, jw=lane&3.
__global__ __launch_bounds__(256) void prep_kernel(
    const float* __restrict__ cb_c, const float* __restrict__ cb_s,
    const int* __restrict__ batch,
    float* __restrict__ cnorm, unsigned short* __restrict__ splits,
    int* __restrict__ starts, int* __restrict__ flagcnt)
{
    int gwave = (blockIdx.x * 256 + threadIdx.x) >> 6;
    int lane  = threadIdx.x & 63;

    if (gwave < 2 * NCODES) {                  // one wave per (cb,code)
        int cb = gwave >> 12, code = gwave & (NCODES - 1);
        const float* cp = (cb ? cb_s : cb_c) + (size_t)code * DIM;
        float2 v = ((const float2*)cp)[lane];  // elems 2l, 2l+1
        float p = __fadd_rn(__fmul_rn(v.x, v.x), __fmul_rn(v.y, v.y));
        #pragma unroll
        for (int off = 32; off; off >>= 1) p = __fadd_rn(p, __shfl_xor(p, off, 64));
        if (lane == 0) cnorm[cb * NCODES + code] = p;

        int hf = code >> 11, tt = (code >> 6) & 31, cs = (code >> 4) & 3, l15c = code & 15;
        int ch = lane >> 4, lg = (lane >> 2) & 3, jw = lane & 3;
        unsigned int* hp = (unsigned int*)(splits + (size_t)cb * PLANE_U16);
        int u32idx = hf * 131072 +
                     ((tt * 16 + cs * 4 + ch) * 64 + lg * 16 + l15c) * 4 + jw;
        hp[u32idx] = (unsigned)f2h(v.x) | ((unsigned)f2h(v.y) << 16);
    } else {
        int w1 = gwave - 2 * NCODES;
        int g = w1 * 64 + lane;
        if (g <= NGRAPHS) {
            int lo = 0, hi = NODES;
            while (lo < hi) { int mid = (lo + hi) >> 1; if (batch[mid] < g) lo = mid + 1; else hi = mid; }
            starts[g] = lo;
        }
        if (w1 == 0 && lane < 2) flagcnt[lane] = 0;
    }
}

// ----------------------------------------------------------- vq main ----
// 256 nodes x 2048 codes per block. Fragment-order B plane -> contiguous
// conflict-free ds_read_b128; 3-deep counted-vmcnt pipeline (never vmcnt(0)
// in steady state); -0.5*cnorm staged in LDS (no in-loop VMEM but gloads).
__global__ __launch_bounds__(256, 2) void vq_main_kernel(
    const float* __restrict__ node_feat, const float* __restrict__ score,
    const unsigned short* __restrict__ splits, const float* __restrict__ cnorm,
    unsigned long long* __restrict__ halfres)
{
    __shared__ __align__(16) char lds[65536];  // A stage 64KB -> 3x16KB B + 8KB cn
    const int nb    = blockIdx.x & 127;
    const int half  = blockIdx.x >> 7;
    const int cb    = blockIdx.y;
    const int nbase = nb * 256;
    const int tid  = threadIdx.x;
    const int w    = tid >> 6;
    const int lane = tid & 63;
    const int l15  = tid & 15;
    const int lg   = lane >> 4;
    const int swz  = (tid & 7) << 4;

    // ---- stage A (h values, fp16) into LDS, swizzled: 256 rows x 256 B ----
    #pragma unroll
    for (int i = 0; i < 32; ++i) {
        int idx = i * 1024 + tid * 4;
        int row = idx >> 7, k = idx & 127;
        float4 x = *(const float4*)&node_feat[(size_t)(nbase + row) * DIM + k];
        float sc = score[nbase + row];
        unsigned u0 = f2h(h_of(x.x, sc, cb)), u1 = f2h(h_of(x.y, sc, cb));
        unsigned u2 = f2h(h_of(x.z, sc, cb)), u3 = f2h(h_of(x.w, sc, cb));
        int abyte = row * 256 + ((2 * k) ^ ((row & 7) << 4));
        uint2 hw; hw.x = u0 | (u1 << 16); hw.y = u2 | (u3 << 16);
        *(uint2*)(lds + abyte) = hw;
    }
    __syncthreads();

    // ---- A fragments to registers: 4 rs x 4 ch ----
    f16x8_t ahi[4][4];
    int colbyte[4];
    #pragma unroll
    for (int ch = 0; ch < 4; ++ch) colbyte[ch] = (ch * 64 + lg * 16) ^ swz;
    #pragma unroll
    for (int rs = 0; rs < 4; ++rs)
        #pragma unroll
        for (int ch = 0; ch < 4; ++ch) {
            int row = 64 * w + 16 * rs + l15;
            ahi[rs][ch] = *(const f16x8_t*)(lds + row * 256 + colbyte[ch]);
        }
    __syncthreads();   // drains lgkm+vm; LDS reusable (bufs 0..48K, cn 48K..56K)

    // ---- -0.5*cnorm for this half into LDS[49152..57344) ----
    {
        const float* cnp = cnorm + cb * NCODES + half * 2048;
        float4 v0 = *(const float4*)&cnp[tid * 8];
        float4 v1 = *(const float4*)&cnp[tid * 8 + 4];
        float4 n0 = {__fmul_rn(-0.5f, v0.x), __fmul_rn(-0.5f, v0.y),
                     __fmul_rn(-0.5f, v0.z), __fmul_rn(-0.5f, v0.w)};
        float4 n1 = {__fmul_rn(-0.5f, v1.x), __fmul_rn(-0.5f, v1.y),
                     __fmul_rn(-0.5f, v1.z), __fmul_rn(-0.5f, v1.w)};
        *(float4*)(lds + 49152 + tid * 32) = n0;
        *(float4*)(lds + 49152 + tid * 32 + 16) = n1;
    }

    // ---- issue tiles 0 and 1 (linear fragment-order staging) ----
    const char* planeB = (const char*)(splits + (size_t)cb * PLANE_U16 + half * 262144);
    const char* gsrc = planeB + w * 4096 + lane * 16;
    #pragma unroll
    for (int i = 0; i < 4; ++i)
        gload_lds16(gsrc + i * 1024, lds + w * 4096 + i * 1024);
    #pragma unroll
    for (int i = 0; i < 4; ++i)
        gload_lds16(gsrc + 16384 + i * 1024, lds + 16384 + w * 4096 + i * 1024);
    asm volatile("s_waitcnt lgkmcnt(0)" ::: "memory");   // cn writes done pre-barrier

    const float NEG_INF = -3.4e38f;
    float b1v[4][4], b2v[4][4]; int b1i[4][4];
    #pragma unroll
    for (int rs = 0; rs < 4; ++rs)
        #pragma unroll
        for (int r = 0; r < 4; ++r) { b1v[rs][r] = NEG_INF; b2v[rs][r] = NEG_INF; b1i[rs][r] = 0; }

    for (int t = 0; t < 32; ++t) {
        if (t < 31) { asm volatile("s_waitcnt vmcnt(4)" ::: "memory"); }
        else        { asm volatile("s_waitcnt vmcnt(0)" ::: "memory"); }
        __builtin_amdgcn_s_barrier();
        __builtin_amdgcn_sched_barrier(0);

        if (t < 30) {   // issue tile t+2 (safe: this buffer's readers ended at t-1)
            int onx = ((t + 2) % 3) * 16384;
            const char* ts = planeB + (t + 2) * 16384 + w * 4096 + lane * 16;
            char* td = lds + onx + w * 4096;
            #pragma unroll
            for (int i = 0; i < 4; ++i)
                gload_lds16(ts + i * 1024, td + i * 1024);
        }

        const char* bufc = lds + (t % 3) * 16384;
        #pragma unroll
        for (int cs = 0; cs < 4; ++cs) {
            float cnc = *(const float*)(lds + 49152 + ((t * 64 + cs * 16 + l15) << 2));
            f32x4_t acc[4];
            #pragma unroll
            for (int rs = 0; rs < 4; ++rs) acc[rs] = (f32x4_t){cnc, cnc, cnc, cnc};

            #pragma unroll
            for (int ch = 0; ch < 4; ++ch) {
                f16x8_t bh = *(const f16x8_t*)(bufc + (cs * 4 + ch) * 1024 + lane * 16);
                #pragma unroll
                for (int rs = 0; rs < 4; ++rs)
                    acc[rs] = __builtin_amdgcn_mfma_f32_16x16x32_f16(ahi[rs][ch], bh, acc[rs], 0, 0, 0);
            }

            int code = half * 2048 + t * 64 + cs * 16 + l15;
            #pragma unroll
            for (int rs = 0; rs < 4; ++rs)
                #pragma unroll
                for (int r = 0; r < 4; ++r) {
                    float a = acc[rs][r];
                    bool gt = a > b1v[rs][r];
                    float nb2 = __builtin_amdgcn_fmed3f(a, b1v[rs][r], b2v[rs][r]);
                    if (gt) b1i[rs][r] = code;
                    b1v[rs][r] = fmaxf(a, b1v[rs][r]);
                    b2v[rs][r] = nb2;
                }
        }
    }

    // cross-lane merge over the 16 code-columns (lane bits 0..3)
    #pragma unroll
    for (int off = 1; off < 16; off <<= 1) {
        #pragma unroll
        for (int rs = 0; rs < 4; ++rs)
            #pragma unroll
            for (int r = 0; r < 4; ++r) {
                float ov1 = __shfl_xor(b1v[rs][r], off, 64);
                int   oi  = __shfl_xor(b1i[rs][r], off, 64);
                float ov2 = __shfl_xor(b2v[rs][r], off, 64);
                bool take = (ov1 > b1v[rs][r]) || (ov1 == b1v[rs][r] && oi < b1i[rs][r]);
                float loser = fminf(ov1, b1v[rs][r]);
                b1v[rs][r] = fmaxf(ov1, b1v[rs][r]);
                if (take) b1i[rs][r] = oi;
                b2v[rs][r] = fmaxf(loser, fmaxf(ov2, b2v[rs][r]));
            }
    }
    if (l15 == 0) {
        #pragma unroll
        for (int rs = 0; rs < 4; ++rs)
            #pragma unroll
            for (int r = 0; r < 4; ++r) {
                int node = nbase + 64 * w + 16 * rs + 4 * lg + r;
                unsigned key = sortkey(b1v[rs][r]);
                unsigned pay = (unsigned)b1i[rs][r] |
                               ((b1v[rs][r] - b2v[rs][r] < THR) ? 0x1000u : 0u);
                halfres[((size_t)(cb * 2 + half)) * NODES + node] =
                    ((unsigned long long)key << 32) | pay;
            }
    }
}

// -------------------------------------------------------------- resolve ----
__global__ __launch_bounds__(256) void resolve_kernel(
    const unsigned long long* __restrict__ hr, unsigned long long* __restrict__ cslot,
    int* __restrict__ idx_ws, int* __restrict__ flagcnt, int* __restrict__ flaglist)
{
    int cb = blockIdx.y;
    int node = blockIdx.x * 256 + threadIdx.x;
    unsigned long long A = hr[((size_t)(cb * 2 + 0)) * NODES + node];
    unsigned long long B = hr[((size_t)(cb * 2 + 1)) * NODES + node];
    unsigned ka = (unsigned)(A >> 32), kb = (unsigned)(B >> 32);
    bool awin = ka >= kb;
    unsigned long long W = awin ? A : B;
    float aw = keyinv(awin ? ka : kb);
    float al = keyinv(awin ? kb : ka);
    bool flag = ((W >> 12) & 1ull) || (__fsub_rn(aw, al) < THR);
    idx_ws[cb * NODES + node] = (int)(W & 0xFFFu);
    if (flag) cslot[(size_t)cb * NODES + node] = ~0ull;

    unsigned long long mask = __ballot(flag);
    if (mask) {
        int lane = threadIdx.x & 63;
        int leader = __ffsll((long long)mask) - 1;
        int base = 0;
        if (lane == leader) base = atomicAdd(flagcnt + cb, (int)__popcll(mask));
        base = __shfl(base, leader, 64);
        if (flag) {
            int pos = base + (int)__popcll(mask & ((1ull << lane) - 1ull));
            if (pos < FLAG_CAP) flaglist[cb * FLAG_CAP + pos] = node;
        }
    }
}

// --------------------------------------------------------- vq cleanup ----
__global__ __launch_bounds__(256) void vq_cleanup_kernel(
    const float* __restrict__ node_feat, const float* __restrict__ score,
    const float* __restrict__ cb_c, const float* __restrict__ cb_s,
    const float* __restrict__ cnorm, const int* __restrict__ flagcnt,
    const int* __restrict__ flaglist, unsigned long long* __restrict__ slots)
{
    __shared__ char cbS[32768];      // 64 codes x 512 B, XOR-swizzled 16B units
    __shared__ float hbuf[8][128];   // 8 nodes' h rows (2 per wave)
    const int cb  = blockIdx.y;
    const int seg = blockIdx.x & 63;    // 64-code segment
    const int ng  = blockIdx.x >> 6;    // node-group 0..63
    const float* cbp = cb ? cb_s : cb_c;
    const int* list = flaglist + cb * FLAG_CAP;
    int cnt = flagcnt[cb]; if (cnt > FLAG_CAP) cnt = FLAG_CAP;
    const int tid = threadIdx.x, w = tid >> 6, l = tid & 63;

    {   // stage this segment's 64 codes, swizzled, once
        int c = tid >> 2, ks = (tid & 3) * 32;
        const float* src = cbp + (size_t)(seg * 64 + c) * DIM + ks;
        char* dst = cbS + c * 512;
        int sw = (c & 7) << 4;
        #pragma unroll
        for (int j = 0; j < 8; ++j) {
            float4 v = *(const float4*)(src + j * 4);
            *(float4*)(dst + ((ks * 4 + j * 16) ^ sw)) = v;
        }
    }
    const int mycode = seg * 64 + l;
    const float cn = cnorm[cb * NCODES + mycode];
    const int swl = (l & 7) << 4;
    const char* crow = cbS + l * 512;
    __syncthreads();

    for (int base = ng * 8; base < cnt; base += 512) {
        int eA = base + 2 * w, eB = eA + 1;
        bool vA = eA < cnt, vB = eB < cnt;
        int nA = list[vA ? eA : 0], nB = list[vB ? eB : 0];
        float scA = score[nA], scB = score[nB];
        float a0 = h_of(node_feat[(size_t)nA * DIM + l],      scA, cb);
        float a1 = h_of(node_feat[(size_t)nA * DIM + 64 + l], scA, cb);
        float b0 = h_of(node_feat[(size_t)nB * DIM + l],      scB, cb);
        float b1 = h_of(node_feat[(size_t)nB * DIM + 64 + l], scB, cb);
        hbuf[2 * w][l] = a0;     hbuf[2 * w][64 + l] = a1;
        hbuf[2 * w + 1][l] = b0; hbuf[2 * w + 1][64 + l] = b1;
        float sxA = __fadd_rn(__fmul_rn(a0, a0), __fmul_rn(a1, a1));
        float sxB = __fadd_rn(__fmul_rn(b0, b0), __fmul_rn(b1, b1));
        #pragma unroll
        for (int off = 32; off; off >>= 1) {
            sxA = __fadd_rn(sxA, __shfl_xor(sxA, off, 64));
            sxB = __fadd_rn(sxB, __shfl_xor(sxB, off, 64));
        }
        asm volatile("s_waitcnt lgkmcnt(0)" ::: "memory");

        float pA0 = 0.f, pA1 = 0.f, pA2 = 0.f, pA3 = 0.f;
        float pB0 = 0.f, pB1 = 0.f, pB2 = 0.f, pB3 = 0.f;
        const float4* hA = (const float4*)hbuf[2 * w];
        const float4* hB = (const float4*)hbuf[2 * w + 1];
        #pragma unroll 8
        for (int m = 0; m < 32; ++m) {
            float4 c4 = *(const float4*)(crow + ((m * 16) ^ swl));
            float4 ha = hA[m], hb = hB[m];
            pA0 = fmaf(ha.x, c4.x, pA0); pA1 = fmaf(ha.y, c4.y, pA1);
            pA2 = fmaf(ha.z, c4.z, pA2); pA3 = fmaf(ha.w, c4.w, pA3);
            pB0 = fmaf(hb.x, c4.x, pB0); pB1 = fmaf(hb.y, c4.y, pB1);
            pB2 = fmaf(hb.z, c4.z, pB2); pB3 = fmaf(hb.w, c4.w, pB3);
        }
        float dotA = __fadd_rn(__fadd_rn(pA0, pA1), __fadd_rn(pA2, pA3));
        float dotB = __fadd_rn(__fadd_rn(pB0, pB1), __fadd_rn(pB2, pB3));
        float dA = __fadd_rn(__fsub_rn(sxA, __fmul_rn(2.0f, dotA)), cn);
        float dB = __fadd_rn(__fsub_rn(sxB, __fmul_rn(2.0f, dotB)), cn);

        unsigned long long pkA = ((unsigned long long)sortkey(dA) << 32) | (unsigned)mycode;
        unsigned long long pkB = ((unsigned long long)sortkey(dB) << 32) | (unsigned)mycode;
        #pragma unroll
        for (int off = 1; off < 64; off <<= 1) {
            unsigned long long oA = __shfl_xor(pkA, off, 64);
            unsigned long long oB = __shfl_xor(pkB, off, 64);
            pkA = (oA < pkA) ? oA : pkA;
            pkB = (oB < pkB) ? oB : pkB;
        }
        if (l == 0 && vA) atomicMin(&slots[(size_t)cb * NODES + nA], pkA);
        if (l == 0 && vB) atomicMin(&slots[(size_t)cb * NODES + nB], pkB);
        asm volatile("s_waitcnt lgkmcnt(0)" ::: "memory");
    }
}

// ------------------------------------------------------- flag writeback ----
__global__ __launch_bounds__(256) void flag_writeback_kernel(
    const int* __restrict__ flagcnt, const int* __restrict__ flaglist,
    const unsigned long long* __restrict__ slots, int* __restrict__ idx_ws)
{
    int gt = blockIdx.x * 256 + threadIdx.x;
    int c0 = flagcnt[0]; if (c0 > FLAG_CAP) c0 = FLAG_CAP;
    int c1 = flagcnt[1]; if (c1 > FLAG_CAP) c1 = FLAG_CAP;
    for (int e = gt; e < 2 * FLAG_CAP; e += 256 * 256) {
        int cb = (e >= FLAG_CAP) ? 1 : 0;
        int i = e - cb * FLAG_CAP;
        int cnt = cb ? c1 : c0;
        if (i < cnt) {
            int node = flaglist[cb * FLAG_CAP + i];
            idx_ws[cb * NODES + node] =
                (int)(slots[(size_t)cb * NODES + node] & 0xFFFFFFFFull);
        }
    }
}

// --------------------------------------------------------------- gather ----
__global__ __launch_bounds__(256) void gather_kernel(
    const float* __restrict__ node_feat, const float* __restrict__ score,
    const float* __restrict__ cb_c, const float* __restrict__ cb_s,
    const int* __restrict__ idx_all, float* __restrict__ out,
    double* __restrict__ partials)
{
    __shared__ float redc[4], reds[4];
    int wave = threadIdx.x >> 6, lane = threadIdx.x & 63;
    int node = blockIdx.x * 4 + wave;
    float sc = score[node];
    float2 x  = *(const float2*)&node_feat[(size_t)node * DIM + 2 * lane];
    int ic = idx_all[node], is_ = idx_all[NODES + node];
    float2 qc = *(const float2*)&cb_c[(size_t)ic * DIM + 2 * lane];
    float2 qs = *(const float2*)&cb_s[(size_t)is_ * DIM + 2 * lane];

    float omsc = __fsub_rn(1.0f, sc);
    float2 cn, sn;
    cn.x = __fadd_rn(__fmul_rn(x.x, sc), qc.x);
    cn.y = __fadd_rn(__fmul_rn(x.y, sc), qc.y);
    sn.x = __fadd_rn(__fmul_rn(x.x, omsc), qs.x);
    sn.y = __fadd_rn(__fmul_rn(x.y, omsc), qs.y);
    *(float2*)&out[OFF_CN + (size_t)node * DIM + 2 * lane] = cn;
    *(float2*)&out[OFF_SN + (size_t)node * DIM + 2 * lane] = sn;

    float hc1 = h_of(x.x, sc, 0), hc2 = h_of(x.y, sc, 0);
    float hs1 = h_of(x.x, sc, 1), hs2 = h_of(x.y, sc, 1);
    float d1 = qc.x - hc1, d2 = qc.y - hc2;
    float e1 = qs.x - hs1, e2 = qs.y - hs2;
    float lc = d1 * d1 + d2 * d2;
    float ls = e1 * e1 + e2 * e2;
    #pragma unroll
    for (int off = 32; off; off >>= 1) {
        lc += __shfl_down(lc, off, 64);
        ls += __shfl_down(ls, off, 64);
    }
    if (lane == 0) { redc[wave] = lc; reds[wave] = ls; }
    __syncthreads();
    if (threadIdx.x == 0) {
        partials[blockIdx.x]        = (double)redc[0] + redc[1] + redc[2] + redc[3];
        partials[8192 + blockIdx.x] = (double)reds[0] + reds[1] + reds[2] + reds[3];
    }
}

// ---------------------------------------------------------- loss reduce ----
__global__ __launch_bounds__(256) void loss_reduce_kernel(
    const double* __restrict__ partials, float* __restrict__ out)
{
    __shared__ double red[4];
    int b = blockIdx.x, t = threadIdx.x, w = t >> 6, l = t & 63;
    const double* p = partials + b * 8192;
    double s = 0.0;
    #pragma unroll 4
    for (int i = t; i < 8192; i += 256) s += p[i];
    #pragma unroll
    for (int off = 32; off; off >>= 1) s += __shfl_down(s, off, 64);
    if (l == 0) red[w] = s;
    __syncthreads();
    if (t == 0) {
        double tot = (red[0] + red[1]) + (red[2] + red[3]);
        out[OFF_LC + b] = (float)(tot * (1.0 / 4194304.0));   // / 2^22 exact
    }
}

// ----------------------------------------------------------------- pool ----
__global__ __launch_bounds__(512) void pool_kernel(
    const int* __restrict__ starts, float* __restrict__ out)
{
    __shared__ float part[4][128];
    int g = blockIdx.x, half = blockIdx.y;
    int d = threadIdx.x & 127, nl = threadIdx.x >> 7;
    int s = starts[g], e = starts[g + 1];
    const float* src = out + (half ? OFF_SN : OFF_CN);
    float sum = 0.0f;
    for (int n = s + nl; n < e; n += 4) sum = __fadd_rn(sum, src[(size_t)n * DIM + d]);
    part[nl][d] = sum;
    __syncthreads();
    if (nl == 0) {
        float tot = __fadd_rn(__fadd_rn(part[0][d], part[1][d]),
                              __fadd_rn(part[2][d], part[3][d]));
        float cnt = fmaxf((float)(e - s), 1.0f);
        out[(half ? OFF_SG : OFF_CG) + g * DIM + d] = __fdiv_rn(tot, cnt);
    }
}

// ----------------------------------------------------------- classifier ----
__global__ __launch_bounds__(256) void classifier_kernel(
    const float* __restrict__ w1, const float* __restrict__ b1,
    const float* __restrict__ gamma, const float* __restrict__ beta,
    const float* __restrict__ rm, const float* __restrict__ rv,
    const float* __restrict__ w2, const float* __restrict__ b2,
    float* __restrict__ out)
{
    __shared__ float row[DIM];
    __shared__ float red[4];
    int g = blockIdx.x, t = threadIdx.x;
    if (t < DIM) row[t] = out[OFF_CG + g * DIM + t];
    __syncthreads();
    float h = 0.0f;
    #pragma unroll 8
    for (int k = 0; k < DIM; ++k) h = fmaf(row[k], w1[k * 256 + t], h);
    h = __fadd_rn(h, b1[t]);
    float inv = __frsqrt_rn(__fadd_rn(rv[t], 1e-5f));
    h = __fadd_rn(__fmul_rn(__fmul_rn(__fsub_rn(h, rm[t]), inv), gamma[t]), beta[t]);
    h = fmaxf(h, 0.0f);
    float p = __fmul_rn(h, w2[t]);
    #pragma unroll
    for (int off = 32; off; off >>= 1) p += __shfl_down(p, off, 64);
    if ((t & 63) == 0) red[t >> 6] = p;
    __syncthreads();
    if (t == 0) {
        float total = __fadd_rn(__fadd_rn(red[0], red[1]), __fadd_rn(red[2], red[3]));
        out[OFF_LOGIT + g] = __fadd_rn(total, b2[0]);
    }
}

extern "C" void kernel_launch(void* const* d_in, const int* in_sizes, int n_in,
                              void* d_out, int out_size, void* d_ws, size_t ws_size,
                              hipStream_t stream) {
    const float* node_feat = (const float*)d_in[0];
    const float* score     = (const float*)d_in[1];
    const int*   batch     = (const int*)d_in[2];
    const float* cb_c      = (const float*)d_in[3];
    const float* cb_s      = (const float*)d_in[4];
    const float* w1        = (const float*)d_in[5];
    const float* b1        = (const float*)d_in[6];
    const float* gamma     = (const float*)d_in[7];
    const float* beta      = (const float*)d_in[8];
    const float* rm        = (const float*)d_in[9];
    const float* rv        = (const float*)d_in[10];
    const float* w2        = (const float*)d_in[11];
    const float* b2        = (const float*)d_in[12];
    float* out = (float*)d_out;
    char*  ws  = (char*)d_ws;

    float*  cnorm    = (float*)(ws + WS_CNORM);
    int*    idx      = (int*)(ws + WS_IDX);
    int*    flagcnt  = (int*)(ws + WS_FLAGCNT);
    int*    starts   = (int*)(ws + WS_STARTS);
    int*    flaglist = (int*)(ws + WS_FLAGLIST);
    unsigned short* splits = (unsigned short*)d_out + SPLIT_U16;
    unsigned long long* halfres = (unsigned long long*)(out + HALF_F32);
    unsigned long long* cslot   = (unsigned long long*)(out + CSLOT_F32);
    double* partials = (double*)(out + OFF_CG);   // CG region scratch, pre-pool

    prep_kernel<<<2051, 256, 0, stream>>>(cb_c, cb_s, batch, cnorm, splits,
                                          starts, flagcnt);
    vq_main_kernel<<<dim3(256, 2), 256, 0, stream>>>(node_feat, score, splits, cnorm,
                                                     halfres);
    resolve_kernel<<<dim3(128, 2), 256, 0, stream>>>(halfres, cslot, idx,
                                                     flagcnt, flaglist);
    vq_cleanup_kernel<<<dim3(4096, 2), 256, 0, stream>>>(node_feat, score, cb_c, cb_s,
                                                         cnorm, flagcnt, flaglist, cslot);
    flag_writeback_kernel<<<256, 256, 0, stream>>>(flagcnt, flaglist, cslot, idx);
    gather_kernel<<<8192, 256, 0, stream>>>(node_feat, score, cb_c, cb_s, idx, out, partials);
    loss_reduce_kernel<<<2, 256, 0, stream>>>(partials, out);
    pool_kernel<<<dim3(512, 2), 512, 0, stream>>>(starts, out);
    classifier_kernel<<<512, 256, 0, stream>>>(w1, b1, gamma, beta, rm, rv, w2, b2, out);
}